// Round 10
// baseline (324.516 us; speedup 1.0000x reference)
//
#include <hip/hip_runtime.h>
#include <hip/hip_bf16.h>
#include <math.h>

#define TWO_PI_D 6.283185307179586476925286766559
#define TWO_PI_F 6.28318530718f

typedef short bf16x8 __attribute__((ext_vector_type(8)));
typedef float f32x4 __attribute__((ext_vector_type(4)));

// ---------------------------------------------------------------------------
// Harmonic basis, bf16, TRANSPOSED + padded: Ct[n][k], n<1024 (1022 valid), k<512
// ---------------------------------------------------------------------------
__global__ __launch_bounds__(256) void basis_h_bf16_t(__hip_bfloat16* __restrict__ Ct)
{
    const int n = blockIdx.x;            // 0..1023
    for (int k = threadIdx.x; k < 512; k += 256) {
        float v = 0.0f;
        if (n < 1022) {
            float hann = 0.5f * (1.0f - cosf(TWO_PI_F * (float)n / 1022.0f));
            float w = hann * (1.0f / 1022.0f);
            if (k == 0) v = w;
            else if (k == 511) v = (n & 1) ? w : -w;
            else {
                int m = (k * n) % 1022;
                float c = cosf(TWO_PI_F * (float)m / 1022.0f);
                v = 2.0f * w * ((k & 1) ? -c : c);
            }
        }
        Ct[(size_t)n * 512 + k] = __float2bfloat16(v);
    }
}

// noise basis, fp32: C[k][n], k<80, n<158
template<int NMAG, int NIR>
__global__ __launch_bounds__(256) void basis_kernel(float* __restrict__ C)
{
    const int k = blockIdx.x;
    for (int n = threadIdx.x; n < NIR; n += blockDim.x) {
        double hann = 0.5 * (1.0 - cos(TWO_PI_D * (double)n / (double)NIR));
        double w = hann / (double)NIR;
        double v;
        if (k == 0) v = w;
        else if (k == NMAG - 1) v = (n & 1) ? w : -w;
        else {
            long m = ((long)k * (long)n) % NIR;
            double c = cos(TWO_PI_D * (double)m / (double)NIR);
            v = 2.0 * w * ((k & 1) ? -c : c);
        }
        C[(size_t)k * NIR + n] = (float)v;
    }
}

// ---------------------------------------------------------------------------
// fp32 tiled GEMM 64x64x16 — precision path (MLP hidden layers + noise IR).
// ---------------------------------------------------------------------------
__device__ inline float gelu_f(float x) {
    float x3 = x * x * x;
    float t = tanhf(0.7978845608028654f * (x + 0.044715f * x3));
    return 0.5f * x * (1.0f + t);
}

template<int MODE>
__global__ __launch_bounds__(256) void gemm_kernel(
    const float* __restrict__ A, const float* __restrict__ Bm,
    const float* __restrict__ bias, const float* __restrict__ resid,
    float* __restrict__ C, __hip_bfloat16* __restrict__ Cb, int M, int N, int K)
{
    __shared__ float As[16][68];
    __shared__ float Bs[16][68];
    const int tid = threadIdx.x;
    const int tx = tid & 15, ty = tid >> 4;
    const int m0 = blockIdx.x * 64;
    const int n0 = blockIdx.y * 64;
    const int ar  = tid >> 2;
    const int ac4 = (tid & 3) << 2;
    const int bk  = tid >> 4;
    const int bn4 = (tid & 15) << 2;
    float acc[4][4] = {};
    for (int k0 = 0; k0 < K; k0 += 16) {
        float4 av = *(const float4*)(A + (size_t)(m0 + ar) * K + k0 + ac4);
        As[ac4 + 0][ar] = av.x;
        As[ac4 + 1][ar] = av.y;
        As[ac4 + 2][ar] = av.z;
        As[ac4 + 3][ar] = av.w;
        const float* Bp = Bm + (size_t)(k0 + bk) * N + n0 + bn4;
        #pragma unroll
        for (int i = 0; i < 4; i++)
            Bs[bk][bn4 + i] = (n0 + bn4 + i < N) ? Bp[i] : 0.0f;
        __syncthreads();
        #pragma unroll
        for (int kk = 0; kk < 16; kk++) {
            float4 a4 = *(const float4*)&As[kk][ty << 2];
            float4 b4 = *(const float4*)&Bs[kk][tx << 2];
            float a[4] = {a4.x, a4.y, a4.z, a4.w};
            float b[4] = {b4.x, b4.y, b4.z, b4.w};
            #pragma unroll
            for (int i = 0; i < 4; i++)
                #pragma unroll
                for (int j = 0; j < 4; j++)
                    acc[i][j] = fmaf(a[i], b[j], acc[i][j]);
        }
        __syncthreads();
    }
    #pragma unroll
    for (int i = 0; i < 4; i++) {
        int m = m0 + (ty << 2) + i;
        #pragma unroll
        for (int j = 0; j < 4; j++) {
            int n = n0 + (tx << 2) + j;
            if (n < N) {
                float v = acc[i][j];
                if (bias) v += bias[n];
                if (MODE == 0) v = tanhf(v);
                else if (MODE == 1) v = resid[(size_t)m * N + n] + gelu_f(v);
                C[(size_t)m * N + n] = v;
                if (MODE == 1 && Cb) Cb[(size_t)m * N + n] = __float2bfloat16(v);
            }
        }
    }
}

// ---------------------------------------------------------------------------
// bf16 MFMA GEMM: A [M][K] bf16, Bt [NPAD][K] bf16, C [M][NSTRIDE] fp32
// ---------------------------------------------------------------------------
template<int K, int NSTRIDE>
__global__ __launch_bounds__(256) void mfma_gemm(
    const unsigned short* __restrict__ A, const unsigned short* __restrict__ Bt,
    float* __restrict__ C, int M)
{
    __shared__ __align__(16) unsigned short As[128][72];
    __shared__ __align__(16) unsigned short Bs[128][72];
    const int tid = threadIdx.x;
    const int m0 = blockIdx.x * 128;
    const int n0 = blockIdx.y * 128;
    const int wid = tid >> 6;
    const int lane = tid & 63;
    const int wm = (wid >> 1) << 6;
    const int wn = (wid & 1) << 6;

    f32x4 acc[4][4];
    #pragma unroll
    for (int i = 0; i < 4; i++)
        #pragma unroll
        for (int j = 0; j < 4; j++)
            acc[i][j] = (f32x4){0.f, 0.f, 0.f, 0.f};

    for (int k0 = 0; k0 < K; k0 += 64) {
        #pragma unroll
        for (int s = 0; s < 4; s++) {
            int g = tid + (s << 8);
            int row = g >> 3;
            int kc = (g & 7) << 3;
            int ra = m0 + row; if (ra > M - 1) ra = M - 1;
            *(uint4*)&As[row][kc] = *(const uint4*)&A[(size_t)ra * K + k0 + kc];
            *(uint4*)&Bs[row][kc] = *(const uint4*)&Bt[(size_t)(n0 + row) * K + k0 + kc];
        }
        __syncthreads();
        #pragma unroll
        for (int kk = 0; kk < 64; kk += 32) {
            bf16x8 av[4], bv[4];
            const int koff = kk + ((lane >> 4) << 3);
            #pragma unroll
            for (int mt = 0; mt < 4; mt++)
                av[mt] = *(const bf16x8*)&As[wm + (mt << 4) + (lane & 15)][koff];
            #pragma unroll
            for (int nt = 0; nt < 4; nt++)
                bv[nt] = *(const bf16x8*)&Bs[wn + (nt << 4) + (lane & 15)][koff];
            #pragma unroll
            for (int mt = 0; mt < 4; mt++)
                #pragma unroll
                for (int nt = 0; nt < 4; nt++)
                    acc[mt][nt] = __builtin_amdgcn_mfma_f32_16x16x32_bf16(
                        av[mt], bv[nt], acc[mt][nt], 0, 0, 0);
        }
        __syncthreads();
    }
    const int cr0 = m0 + wm + ((lane >> 4) << 2);
    const int cc0 = n0 + wn + (lane & 15);
    #pragma unroll
    for (int mt = 0; mt < 4; mt++)
        #pragma unroll
        for (int nt = 0; nt < 4; nt++)
            #pragma unroll
            for (int j = 0; j < 4; j++) {
                int r = cr0 + (mt << 4) + j;
                if (r < M) C[(size_t)r * NSTRIDE + cc0 + (nt << 4)] = acc[mt][nt][j];
            }
}

// ---------------------------------------------------------------------------
// W_out MFMA GEMM with FUSED exp_sigmoid epilogue: writes SPb (bf16, cols
// 1..512) and NP (fp32, cols 513..592) directly; no O materialization.
// A [M][256] bf16, Bt [640][256] bf16 (W_out^T padded).
// ---------------------------------------------------------------------------
__global__ __launch_bounds__(256) void mfma_gemm_sp(
    const unsigned short* __restrict__ A, const unsigned short* __restrict__ Bt,
    const float* __restrict__ b_out,
    __hip_bfloat16* __restrict__ SPb, float* __restrict__ NP, int M)
{
    constexpr int K = 256;
    __shared__ __align__(16) unsigned short As[128][72];
    __shared__ __align__(16) unsigned short Bs[128][72];
    const int tid = threadIdx.x;
    const int m0 = blockIdx.x * 128;
    const int n0 = blockIdx.y * 128;
    const int wid = tid >> 6;
    const int lane = tid & 63;
    const int wm = (wid >> 1) << 6;
    const int wn = (wid & 1) << 6;

    f32x4 acc[4][4];
    #pragma unroll
    for (int i = 0; i < 4; i++)
        #pragma unroll
        for (int j = 0; j < 4; j++)
            acc[i][j] = (f32x4){0.f, 0.f, 0.f, 0.f};

    for (int k0 = 0; k0 < K; k0 += 64) {
        #pragma unroll
        for (int s = 0; s < 4; s++) {
            int g = tid + (s << 8);
            int row = g >> 3;
            int kc = (g & 7) << 3;
            int ra = m0 + row; if (ra > M - 1) ra = M - 1;
            *(uint4*)&As[row][kc] = *(const uint4*)&A[(size_t)ra * K + k0 + kc];
            *(uint4*)&Bs[row][kc] = *(const uint4*)&Bt[(size_t)(n0 + row) * K + k0 + kc];
        }
        __syncthreads();
        #pragma unroll
        for (int kk = 0; kk < 64; kk += 32) {
            bf16x8 av[4], bv[4];
            const int koff = kk + ((lane >> 4) << 3);
            #pragma unroll
            for (int mt = 0; mt < 4; mt++)
                av[mt] = *(const bf16x8*)&As[wm + (mt << 4) + (lane & 15)][koff];
            #pragma unroll
            for (int nt = 0; nt < 4; nt++)
                bv[nt] = *(const bf16x8*)&Bs[wn + (nt << 4) + (lane & 15)][koff];
            #pragma unroll
            for (int mt = 0; mt < 4; mt++)
                #pragma unroll
                for (int nt = 0; nt < 4; nt++)
                    acc[mt][nt] = __builtin_amdgcn_mfma_f32_16x16x32_bf16(
                        av[mt], bv[nt], acc[mt][nt], 0, 0, 0);
        }
        __syncthreads();
    }
    const int cr0 = m0 + wm + ((lane >> 4) << 2);
    const int cc0 = n0 + wn + (lane & 15);
    #pragma unroll
    for (int mt = 0; mt < 4; mt++)
        #pragma unroll
        for (int nt = 0; nt < 4; nt++) {
            const int c = cc0 + (nt << 4);
            if (c < 1 || c >= 593) continue;
            const float bo = b_out[c];
            #pragma unroll
            for (int j = 0; j < 4; j++) {
                int r = cr0 + (mt << 4) + j;
                if (r < M) {
                    float v = acc[mt][nt][j] + bo;
                    float s = 1.0f / (1.0f + __expf(-v));
                    float p = 2.0f * __powf(s, 2.3025851f) + 1e-7f;
                    if (c < 513) SPb[(size_t)r * 512 + (c - 1)] = __float2bfloat16(p);
                    else         NP[(size_t)r * 80 + (c - 513)] = p;
                }
            }
        }
}

// ---------------------------------------------------------------------------
__global__ __launch_bounds__(256) void convert_wout(
    const float* __restrict__ W, __hip_bfloat16* __restrict__ WTb)
{
    const int n = blockIdx.x;           // 0..639
    const int k = threadIdx.x;          // 0..255
    float v = (n < 593) ? W[(size_t)k * 593 + n] : 0.0f;
    WTb[(size_t)n * 256 + k] = __float2bfloat16(v);
}

// exact-fp32 f0 logit + fused precise f0 transform
__global__ __launch_bounds__(256) void f0_gemv(
    const float* __restrict__ h3, const float* __restrict__ Wout,
    const float* __restrict__ b_out, float* __restrict__ f0w, float* __restrict__ f0out)
{
    const int row = blockIdx.x * 4 + (threadIdx.x >> 6);
    const int lane = threadIdx.x & 63;
    const float* a = h3 + (size_t)row * 256;
    float s = 0.0f;
    #pragma unroll
    for (int q = 0; q < 4; q++) {
        int k = lane + (q << 6);
        s = fmaf(a[k], Wout[(size_t)k * 593], s);
    }
    #pragma unroll
    for (int off = 32; off; off >>= 1) s += __shfl_down(s, off, 64);
    if (lane == 0) {
        float lg = s + b_out[0];
        float sg = 1.0f / (1.0f + expf(-lg));
        float f0 = 80.0f * powf(12.5f, sg);
        if (f0 < 80.0f) f0 = 0.0f;
        f0w[row] = f0;
        f0out[row] = f0;
    }
}

// ---------------------------------------------------------------------------
// Parallel fp64 frame-level pitch scan
// ---------------------------------------------------------------------------
__device__ inline double shfl_up_d(double x, int off) {
    long long l = __double_as_longlong(x);
    int lo = (int)(l & 0xffffffffLL);
    int hi = (int)(l >> 32);
    lo = __shfl_up(lo, off, 64);
    hi = __shfl_up(hi, off, 64);
    return __longlong_as_double(((long long)hi << 32) | (unsigned int)lo);
}

__global__ __launch_bounds__(256) void scan_par_kernel(
    const float* __restrict__ f0w, const float* __restrict__ iphase,
    double* __restrict__ base, float* __restrict__ fph)
{
    __shared__ double wsum[4];
    const int b = blockIdx.x;
    const int tid = threadIdx.x;
    const int lane = tid & 63;
    const float* f0 = f0w + b * 1000;
    double s[4];
    double loc = 0.0;
    #pragma unroll
    for (int q = 0; q < 4; q++) {
        int f = tid * 4 + q;
        s[q] = loc;
        if (f < 1000) {
            double c  = (double)f0[f];
            double nx = (double)f0[(f < 999) ? (f + 1) : 999];
            loc += 120.5 * c + 119.5 * nx;
        }
    }
    double v = loc;
    #pragma unroll
    for (int off = 1; off < 64; off <<= 1) {
        double o = shfl_up_d(v, off);
        if (lane >= off) v += o;
    }
    if (lane == 63) wsum[tid >> 6] = v;
    __syncthreads();
    double wpre = 0.0;
    const int w = tid >> 6;
    for (int i = 0; i < w; i++) wpre += wsum[i];
    const double excl = wpre + v - loc;
    #pragma unroll
    for (int q = 0; q < 4; q++) {
        int f = tid * 4 + q;
        if (f < 1000) base[b * 1000 + f] = excl + s[q];
    }
    if (tid == 255) {
        double total = excl + loc;
        double u  = total * (1.0 / 24000.0);
        double ph = TWO_PI_D * u + (double)iphase[b];
        fph[b] = (float)fmod(ph, TWO_PI_D);
    }
}

// ---------------------------------------------------------------------------
// Sawtooth (fp64 phase) + threefry2x32 noise (bit-exact)
// ---------------------------------------------------------------------------
__device__ inline unsigned rotl32(unsigned x, int d) { return (x << d) | (x >> (32 - d)); }

__global__ __launch_bounds__(256) void saw_noise_kernel(
    const float* __restrict__ f0w, const double* __restrict__ base,
    const float* __restrict__ iphase, float* __restrict__ saw, float* __restrict__ nz)
{
    int idx = blockIdx.x * 256 + threadIdx.x;
    if (idx >= 8 * 240000) return;
    int b = idx / 240000;
    int t = idx - b * 240000;
    int f = t / 240;
    int r = t - f * 240;
    double c  = (double)f0w[b * 1000 + f];
    double nx = (double)f0w[b * 1000 + ((f < 999) ? (f + 1) : 999)];
    double rr = (double)r;
    double Bc = rr * (rr + 1.0) * (1.0 / 480.0);
    double Ac = (rr + 1.0) - Bc;
    double cum = base[b * 1000 + f] + Ac * c + Bc * nx;
    double u  = cum * (1.0 / 24000.0) + (double)iphase[b] * (1.0 / TWO_PI_D);
    double fr = u - floor(u);
    saw[idx] = (float)(2.0 * fr - 1.0);

    const unsigned n2 = 960000u;
    unsigned mi = (unsigned)idx;
    unsigned i0 = (mi < n2) ? mi : (mi - n2);
    unsigned x0 = i0, x1 = i0 + n2;
    const unsigned ks0 = 0u, ks1 = 123u, ks2 = 0x1BD11BDAu ^ 0u ^ 123u;
    x0 += ks0; x1 += ks1;
#define TF_R(rot) { x0 += x1; x1 = rotl32(x1, rot); x1 ^= x0; }
    TF_R(13) TF_R(15) TF_R(26) TF_R(6)
    x0 += ks1; x1 += ks2 + 1u;
    TF_R(17) TF_R(29) TF_R(16) TF_R(24)
    x0 += ks2; x1 += ks0 + 2u;
    TF_R(13) TF_R(15) TF_R(26) TF_R(6)
    x0 += ks0; x1 += ks1 + 3u;
    TF_R(17) TF_R(29) TF_R(16) TF_R(24)
    x0 += ks1; x1 += ks2 + 4u;
    TF_R(13) TF_R(15) TF_R(26) TF_R(6)
    x0 += ks2; x1 += ks0 + 5u;
#undef TF_R
    unsigned bits = (mi < n2) ? x0 : x1;
    float uf = __uint_as_float((bits >> 9) | 0x3f800000u) - 1.0f;
    nz[idx] = uf * 2.0f - 1.0f;
}

// ---------------------------------------------------------------------------
// Per-frame conv, harmonic. One WAVE per frame, 2 frames/block (128 thr).
// Lane owns 20 outputs (64*20=1280). Per-lane w stride = 5 chunks (odd) ->
// 8 consecutive lanes tile all 32 banks exactly once. u-reads are wave-
// uniform broadcasts. Rolling 6-chunk circular window, period-6 unroll.
// LDS 14.2 KB/block -> up to 11 blocks/CU.
// ---------------------------------------------------------------------------
__global__ __launch_bounds__(128) void frameconv_h(
    const float* __restrict__ audio, const float* __restrict__ IR,
    float* __restrict__ Y)
{
    constexpr int WOFF = 244;            // left zero-pad words (chunk-aligned)
    constexpr int WSZ  = 1536;           // per-frame padded w words
    __shared__ float u_s[2][240];
    __shared__ __align__(16) float w_s[2][WSZ];
    const int fq  = blockIdx.x;          // frame pair 0..499
    const int b   = blockIdx.y;
    const int tid = threadIdx.x;
    const int wv  = tid >> 6;            // wave = frame within pair
    const int lane = tid & 63;

    // staging (coalesced; zero pads outside [0,1022))
    for (int i = tid; i < 2 * WSZ; i += 128) {
        int fr = i / WSZ, r = i - fr * WSZ;
        int d = r - WOFF;
        float v = 0.0f;
        if (d >= 0 && d < 1022)
            v = IR[((size_t)b * 1000 + fq * 2 + fr) * 1024 + d];
        w_s[fr][r] = v;
    }
    for (int i = tid; i < 2 * 240; i += 128) {
        int fr = i / 240, r = i - fr * 240;
        u_s[fr][r] = audio[(size_t)b * 240000 + (size_t)(fq * 2 + fr) * 240 + r];
    }
    __syncthreads();

    const float* wf = w_s[wv];
    const float* uf = u_s[wv];
    const int j0 = 20 * lane;
    float acc[20];
    #pragma unroll
    for (int q = 0; q < 20; q++) acc[q] = 0.0f;

    // window: 6 chunks covering padded words [wb(s), wb(s)+24)
    float C[24];
    const int wb0 = WOFF + j0 - 4;       // = 240 + 20*lane (>= 0, 16B-aligned)
    #pragma unroll
    for (int h = 0; h < 6; h++)
        *(float4*)&C[4 * h] = *(const float4*)&wf[wb0 + 4 * h];
    int ldw = wb0 - 4;                   // next incoming chunk word

    #pragma unroll 1
    for (int M = 0; M < 10; M++) {
        #pragma unroll
        for (int p = 0; p < 6; p++) {    // global step s = 6M+p, i0 = 4s
            const int i0 = 24 * M + 4 * p;
            float4 u4 = *(const float4*)&uf[i0];
            float uu[4] = {u4.x, u4.y, u4.z, u4.w};
            #pragma unroll
            for (int q = 0; q < 20; q++)
                #pragma unroll
                for (int k = 0; k < 4; k++) {
                    const int rel  = q - k + 4;              // 1..23
                    const int h    = rel >> 2;               // 0..5
                    const int slot = ((h - p) % 6 + 6) % 6;  // static
                    acc[q] = fmaf(uu[k], C[4 * slot + (rel & 3)], acc[q]);
                }
            const int lslot = ((-1 - p) % 6 + 6) % 6;        // 5,4,..,0
            *(float4*)&C[4 * lslot] = *(const float4*)&wf[ldw];
            ldw -= 4;
        }
    }

    float* yp = &Y[((size_t)b * 1000 + fq * 2 + wv) * 1280 + j0];
    #pragma unroll
    for (int cc = 0; cc < 5; cc++) {
        float4 r4 = {acc[4*cc], acc[4*cc+1], acc[4*cc+2], acc[4*cc+3]};
        *(float4*)&yp[4*cc] = r4;
    }
}

// ---------------------------------------------------------------------------
// Per-frame conv, noise: iterate IR, window over audio.
// ---------------------------------------------------------------------------
#define CONV_GROUP(u4) \
    a0 = fmaf(u4.x, Whi.x, a0); a1 = fmaf(u4.x, Whi.y, a1); a2 = fmaf(u4.x, Whi.z, a2); a3 = fmaf(u4.x, Whi.w, a3); \
    a0 = fmaf(u4.y, Wlo.w, a0); a1 = fmaf(u4.y, Whi.x, a1); a2 = fmaf(u4.y, Whi.y, a2); a3 = fmaf(u4.y, Whi.z, a3); \
    a0 = fmaf(u4.z, Wlo.z, a0); a1 = fmaf(u4.z, Wlo.w, a1); a2 = fmaf(u4.z, Whi.x, a2); a3 = fmaf(u4.z, Whi.y, a3); \
    a0 = fmaf(u4.w, Wlo.y, a0); a1 = fmaf(u4.w, Wlo.z, a1); a2 = fmaf(u4.w, Wlo.w, a2); a3 = fmaf(u4.w, Whi.x, a3);

__global__ __launch_bounds__(128) void frameconv_n(
    const float* __restrict__ audio, const float* __restrict__ IR,
    float* __restrict__ Y)
{
    __shared__ __align__(16) float u_s[160];
    __shared__ __align__(16) float w_s[560];
    const int f = blockIdx.x;
    const int b = blockIdx.y;
    const int tid = threadIdx.x;
    const float* irow = IR + ((size_t)b * 1000 + f) * 158;
    for (int i = tid; i < 160; i += 128) {
        u_s[i] = (i < 158) ? irow[i] : 0.0f;
        w_s[i] = 0.0f;
        w_s[400 + i] = 0.0f;
    }
    for (int i = tid; i < 240; i += 128)
        w_s[160 + i] = audio[(size_t)b * 240000 + (size_t)f * 240 + i];
    __syncthreads();

    const int j0 = tid << 2;
    if (j0 >= 400) return;
    int base = 160 + j0 - 4;
    float4 Wlo = *(const float4*)&w_s[base];
    float4 Whi = *(const float4*)&w_s[base + 4];
    float a0 = 0.f, a1 = 0.f, a2 = 0.f, a3 = 0.f;
    #pragma unroll 4
    for (int t = 0; t < 156; t += 4) {
        float4 u4 = *(const float4*)&u_s[t];
        CONV_GROUP(u4)
        Whi = Wlo;
        base -= 4;
        Wlo = *(const float4*)&w_s[base];
    }
    {
        float4 u4 = *(const float4*)&u_s[156];
        CONV_GROUP(u4)
    }
    float4 r; r.x = a0; r.y = a1; r.z = a2; r.w = a3;
    *(float4*)&Y[((size_t)b * 1000 + f) * 400 + j0] = r;
}

// ---------------------------------------------------------------------------
// Overlap-add + 'same' slice + outputs (full range, single launch)
// ---------------------------------------------------------------------------
__global__ __launch_bounds__(256) void combine_kernel(
    const float* __restrict__ Yh, const float* __restrict__ Yn,
    float* __restrict__ sig, float* __restrict__ harm, float* __restrict__ noise)
{
    int t = blockIdx.x * 256 + threadIdx.x;
    if (t >= 240000) return;
    const int b = blockIdx.y;
    float hsum = 0.0f;
    const int fhi = (t + 509) / 240;
    #pragma unroll
    for (int q = 0; q < 6; q++) {
        int f = fhi - q;
        int j = t + 509 - 240 * f;
        if (f >= 0 && f < 1000 && j < 1261)
            hsum += Yh[((size_t)b * 1000 + f) * 1280 + j];
    }
    float nsum = 0.0f;
    const int ghi = (t + 77) / 240;
    #pragma unroll
    for (int q = 0; q < 2; q++) {
        int f = ghi - q;
        int j = t + 77 - 240 * f;
        if (f >= 0 && f < 1000 && j < 397)
            nsum += Yn[((size_t)b * 1000 + f) * 400 + j];
    }
    size_t o = (size_t)b * 240000 + t;
    harm[o]  = hsum;
    noise[o] = nsum;
    sig[o]   = hsum + nsum;
}

// ---------------------------------------------------------------------------
extern "C" void kernel_launch(void* const* d_in, const int* in_sizes, int n_in,
                              void* d_out, int out_size, void* d_ws, size_t ws_size,
                              hipStream_t stream)
{
    (void)in_sizes; (void)n_in; (void)out_size; (void)ws_size;
    const float* mel    = (const float*)d_in[0];
    const float* iphase = (const float*)d_in[1];
    const float* W_in   = (const float*)d_in[2];
    const float* b_in   = (const float*)d_in[3];
    const float* W1     = (const float*)d_in[4];
    const float* b1     = (const float*)d_in[5];
    const float* W2     = (const float*)d_in[6];
    const float* b2     = (const float*)d_in[7];
    const float* W_out  = (const float*)d_in[8];
    const float* b_out  = (const float*)d_in[9];
    float* ws = (float*)d_ws;

    // workspace layout (float offsets)
    __hip_bfloat16* Chb = (__hip_bfloat16*)(ws + 0);        // [1024][512] bf16
    float*  Cn      = ws + 262144;                          // 12,640
    __hip_bfloat16* SPb = (__hip_bfloat16*)(ws + 274784);   // [8000][512] bf16
    float*  NP      = ws + 2322784;                         // 640,000
    float*  f0w     = ws + 3440640;                         // 8,000
    double* base    = (double*)(ws + 3448640);              // 8,000 dbl
    float*  saw     = ws + 3472640;                         // 1,920,000
    float*  nz      = ws + 5392640;                         // 1,920,000
    float*  BA      = ws + 7312640;                         // 2,048,000 (h1,h3)
    float*  BB      = ws + 9360640;                         // 2,048,000 (h2)
    __hip_bfloat16* BAb = (__hip_bfloat16*)(ws + 11408640); // [8000][256] bf16
    __hip_bfloat16* WTb = (__hip_bfloat16*)(ws + 12432640); // [640][256] bf16
    float*  IRh     = ws + 7312640;                         // [8000][1024] (aliases BA.., dead then)
    float*  IRn     = ws + 17634560;                        // 1,264,000
    float*  YhF     = ws + 18898560;                        // [8][1000][1280] = 10,240,000
    float*  YnF     = ws + 29138560;                        // [8][1000][400]  =  3,200,000

    float* out       = (float*)d_out;
    float* sig_out   = out;
    float* f0_out    = out + 1920000;
    float* fph_out   = out + 1928000;
    float* harm_out  = out + 1928008;
    float* noise_out = out + 3848008;

    basis_h_bf16_t<<<1024, 256, 0, stream>>>(Chb);
    basis_kernel<80, 158><<<80, 256, 0, stream>>>(Cn);

    // MLP hidden layers in fp32 (f0-precision path); 3rd layer mirrors bf16
    gemm_kernel<0><<<dim3(125, 4), 256, 0, stream>>>(mel, W_in, b_in, nullptr, BA, nullptr, 8000, 256, 80);
    gemm_kernel<1><<<dim3(125, 4), 256, 0, stream>>>(BA,  W1,   b1,   BA,      BB, nullptr, 8000, 256, 256);
    gemm_kernel<1><<<dim3(125, 4), 256, 0, stream>>>(BB,  W2,   b2,   BB,      BA, BAb,     8000, 256, 256);

    // W_out: bf16 MFMA with fused exp_sigmoid epilogue (SPb/NP direct)
    // + exact fp32 GEMV (fused f0) for col 0
    convert_wout<<<640, 256, 0, stream>>>(W_out, WTb);
    mfma_gemm_sp<<<dim3(63, 5), 256, 0, stream>>>(
        (const unsigned short*)BAb, (const unsigned short*)WTb, b_out, SPb, NP, 8000);
    f0_gemv<<<2000, 256, 0, stream>>>(BA, W_out, b_out, f0w, f0_out);

    scan_par_kernel<<<8, 256, 0, stream>>>(f0w, iphase, base, fph_out);
    saw_noise_kernel<<<(1920000 + 255) / 256, 256, 0, stream>>>(f0w, base, iphase, saw, nz);

    // IR_h = SPb @ Chb^T  (bf16 MFMA, fp32 out, stride 1024)
    mfma_gemm<512, 1024><<<dim3(63, 8), 256, 0, stream>>>(
        (const unsigned short*)SPb, (const unsigned short*)Chb, IRh, 8000);
    // IR_n fp32
    gemm_kernel<2><<<dim3(125, 3), 256, 0, stream>>>(NP, Cn, nullptr, nullptr, IRn, nullptr, 8000, 158, 80);

    // per-frame conv + overlap-add (single pass, no chunking)
    frameconv_h<<<dim3(500, 8), 128, 0, stream>>>(saw, IRh, YhF);
    frameconv_n<<<dim3(1000, 8), 128, 0, stream>>>(nz, IRn, YnF);
    combine_kernel<<<dim3(938, 8), 256, 0, stream>>>(YhF, YnF, sig_out, harm_out, noise_out);
}

// Round 11
// 313.767 us; speedup vs baseline: 1.0343x; 1.0343x over previous
//
#include <hip/hip_runtime.h>
#include <hip/hip_bf16.h>
#include <math.h>

#define TWO_PI_D 6.283185307179586476925286766559
#define TWO_PI_F 6.28318530718f

typedef short bf16x8 __attribute__((ext_vector_type(8)));
typedef float f32x4 __attribute__((ext_vector_type(4)));

// ---------------------------------------------------------------------------
// Harmonic basis, bf16, TRANSPOSED + padded: Ct[n][k], n<1024 (1022 valid), k<512
// ---------------------------------------------------------------------------
__global__ __launch_bounds__(256) void basis_h_bf16_t(__hip_bfloat16* __restrict__ Ct)
{
    const int n = blockIdx.x;            // 0..1023
    for (int k = threadIdx.x; k < 512; k += 256) {
        float v = 0.0f;
        if (n < 1022) {
            float hann = 0.5f * (1.0f - cosf(TWO_PI_F * (float)n / 1022.0f));
            float w = hann * (1.0f / 1022.0f);
            if (k == 0) v = w;
            else if (k == 511) v = (n & 1) ? w : -w;
            else {
                int m = (k * n) % 1022;
                float c = cosf(TWO_PI_F * (float)m / 1022.0f);
                v = 2.0f * w * ((k & 1) ? -c : c);
            }
        }
        Ct[(size_t)n * 512 + k] = __float2bfloat16(v);
    }
}

// noise basis, fp32: C[k][n], k<80, n<158
template<int NMAG, int NIR>
__global__ __launch_bounds__(256) void basis_kernel(float* __restrict__ C)
{
    const int k = blockIdx.x;
    for (int n = threadIdx.x; n < NIR; n += blockDim.x) {
        double hann = 0.5 * (1.0 - cos(TWO_PI_D * (double)n / (double)NIR));
        double w = hann / (double)NIR;
        double v;
        if (k == 0) v = w;
        else if (k == NMAG - 1) v = (n & 1) ? w : -w;
        else {
            long m = ((long)k * (long)n) % NIR;
            double c = cos(TWO_PI_D * (double)m / (double)NIR);
            v = 2.0 * w * ((k & 1) ? -c : c);
        }
        C[(size_t)k * NIR + n] = (float)v;
    }
}

// ---------------------------------------------------------------------------
// fp32 tiled GEMM 64x64x16 — precision path (MLP hidden layers + noise IR).
// ---------------------------------------------------------------------------
__device__ inline float gelu_f(float x) {
    float x3 = x * x * x;
    float t = tanhf(0.7978845608028654f * (x + 0.044715f * x3));
    return 0.5f * x * (1.0f + t);
}

template<int MODE>
__global__ __launch_bounds__(256) void gemm_kernel(
    const float* __restrict__ A, const float* __restrict__ Bm,
    const float* __restrict__ bias, const float* __restrict__ resid,
    float* __restrict__ C, __hip_bfloat16* __restrict__ Cb, int M, int N, int K)
{
    __shared__ float As[16][68];
    __shared__ float Bs[16][68];
    const int tid = threadIdx.x;
    const int tx = tid & 15, ty = tid >> 4;
    const int m0 = blockIdx.x * 64;
    const int n0 = blockIdx.y * 64;
    const int ar  = tid >> 2;
    const int ac4 = (tid & 3) << 2;
    const int bk  = tid >> 4;
    const int bn4 = (tid & 15) << 2;
    float acc[4][4] = {};
    for (int k0 = 0; k0 < K; k0 += 16) {
        float4 av = *(const float4*)(A + (size_t)(m0 + ar) * K + k0 + ac4);
        As[ac4 + 0][ar] = av.x;
        As[ac4 + 1][ar] = av.y;
        As[ac4 + 2][ar] = av.z;
        As[ac4 + 3][ar] = av.w;
        const float* Bp = Bm + (size_t)(k0 + bk) * N + n0 + bn4;
        #pragma unroll
        for (int i = 0; i < 4; i++)
            Bs[bk][bn4 + i] = (n0 + bn4 + i < N) ? Bp[i] : 0.0f;
        __syncthreads();
        #pragma unroll
        for (int kk = 0; kk < 16; kk++) {
            float4 a4 = *(const float4*)&As[kk][ty << 2];
            float4 b4 = *(const float4*)&Bs[kk][tx << 2];
            float a[4] = {a4.x, a4.y, a4.z, a4.w};
            float b[4] = {b4.x, b4.y, b4.z, b4.w};
            #pragma unroll
            for (int i = 0; i < 4; i++)
                #pragma unroll
                for (int j = 0; j < 4; j++)
                    acc[i][j] = fmaf(a[i], b[j], acc[i][j]);
        }
        __syncthreads();
    }
    #pragma unroll
    for (int i = 0; i < 4; i++) {
        int m = m0 + (ty << 2) + i;
        #pragma unroll
        for (int j = 0; j < 4; j++) {
            int n = n0 + (tx << 2) + j;
            if (n < N) {
                float v = acc[i][j];
                if (bias) v += bias[n];
                if (MODE == 0) v = tanhf(v);
                else if (MODE == 1) v = resid[(size_t)m * N + n] + gelu_f(v);
                C[(size_t)m * N + n] = v;
                if (MODE == 1 && Cb) Cb[(size_t)m * N + n] = __float2bfloat16(v);
            }
        }
    }
}

// ---------------------------------------------------------------------------
// bf16 MFMA GEMM: A [M][K] bf16, Bt [NPAD][K] bf16, C [M][NSTRIDE] fp32
// ---------------------------------------------------------------------------
template<int K, int NSTRIDE>
__global__ __launch_bounds__(256) void mfma_gemm(
    const unsigned short* __restrict__ A, const unsigned short* __restrict__ Bt,
    float* __restrict__ C, int M)
{
    __shared__ __align__(16) unsigned short As[128][72];
    __shared__ __align__(16) unsigned short Bs[128][72];
    const int tid = threadIdx.x;
    const int m0 = blockIdx.x * 128;
    const int n0 = blockIdx.y * 128;
    const int wid = tid >> 6;
    const int lane = tid & 63;
    const int wm = (wid >> 1) << 6;
    const int wn = (wid & 1) << 6;

    f32x4 acc[4][4];
    #pragma unroll
    for (int i = 0; i < 4; i++)
        #pragma unroll
        for (int j = 0; j < 4; j++)
            acc[i][j] = (f32x4){0.f, 0.f, 0.f, 0.f};

    for (int k0 = 0; k0 < K; k0 += 64) {
        #pragma unroll
        for (int s = 0; s < 4; s++) {
            int g = tid + (s << 8);
            int row = g >> 3;
            int kc = (g & 7) << 3;
            int ra = m0 + row; if (ra > M - 1) ra = M - 1;
            *(uint4*)&As[row][kc] = *(const uint4*)&A[(size_t)ra * K + k0 + kc];
            *(uint4*)&Bs[row][kc] = *(const uint4*)&Bt[(size_t)(n0 + row) * K + k0 + kc];
        }
        __syncthreads();
        #pragma unroll
        for (int kk = 0; kk < 64; kk += 32) {
            bf16x8 av[4], bv[4];
            const int koff = kk + ((lane >> 4) << 3);
            #pragma unroll
            for (int mt = 0; mt < 4; mt++)
                av[mt] = *(const bf16x8*)&As[wm + (mt << 4) + (lane & 15)][koff];
            #pragma unroll
            for (int nt = 0; nt < 4; nt++)
                bv[nt] = *(const bf16x8*)&Bs[wn + (nt << 4) + (lane & 15)][koff];
            #pragma unroll
            for (int mt = 0; mt < 4; mt++)
                #pragma unroll
                for (int nt = 0; nt < 4; nt++)
                    acc[mt][nt] = __builtin_amdgcn_mfma_f32_16x16x32_bf16(
                        av[mt], bv[nt], acc[mt][nt], 0, 0, 0);
        }
        __syncthreads();
    }
    const int cr0 = m0 + wm + ((lane >> 4) << 2);
    const int cc0 = n0 + wn + (lane & 15);
    #pragma unroll
    for (int mt = 0; mt < 4; mt++)
        #pragma unroll
        for (int nt = 0; nt < 4; nt++)
            #pragma unroll
            for (int j = 0; j < 4; j++) {
                int r = cr0 + (mt << 4) + j;
                if (r < M) C[(size_t)r * NSTRIDE + cc0 + (nt << 4)] = acc[mt][nt][j];
            }
}

// ---------------------------------------------------------------------------
// W_out MFMA GEMM with FUSED exp_sigmoid epilogue -> SPb (bf16) / NP (fp32)
// ---------------------------------------------------------------------------
__global__ __launch_bounds__(256) void mfma_gemm_sp(
    const unsigned short* __restrict__ A, const unsigned short* __restrict__ Bt,
    const float* __restrict__ b_out,
    __hip_bfloat16* __restrict__ SPb, float* __restrict__ NP, int M)
{
    constexpr int K = 256;
    __shared__ __align__(16) unsigned short As[128][72];
    __shared__ __align__(16) unsigned short Bs[128][72];
    const int tid = threadIdx.x;
    const int m0 = blockIdx.x * 128;
    const int n0 = blockIdx.y * 128;
    const int wid = tid >> 6;
    const int lane = tid & 63;
    const int wm = (wid >> 1) << 6;
    const int wn = (wid & 1) << 6;

    f32x4 acc[4][4];
    #pragma unroll
    for (int i = 0; i < 4; i++)
        #pragma unroll
        for (int j = 0; j < 4; j++)
            acc[i][j] = (f32x4){0.f, 0.f, 0.f, 0.f};

    for (int k0 = 0; k0 < K; k0 += 64) {
        #pragma unroll
        for (int s = 0; s < 4; s++) {
            int g = tid + (s << 8);
            int row = g >> 3;
            int kc = (g & 7) << 3;
            int ra = m0 + row; if (ra > M - 1) ra = M - 1;
            *(uint4*)&As[row][kc] = *(const uint4*)&A[(size_t)ra * K + k0 + kc];
            *(uint4*)&Bs[row][kc] = *(const uint4*)&Bt[(size_t)(n0 + row) * K + k0 + kc];
        }
        __syncthreads();
        #pragma unroll
        for (int kk = 0; kk < 64; kk += 32) {
            bf16x8 av[4], bv[4];
            const int koff = kk + ((lane >> 4) << 3);
            #pragma unroll
            for (int mt = 0; mt < 4; mt++)
                av[mt] = *(const bf16x8*)&As[wm + (mt << 4) + (lane & 15)][koff];
            #pragma unroll
            for (int nt = 0; nt < 4; nt++)
                bv[nt] = *(const bf16x8*)&Bs[wn + (nt << 4) + (lane & 15)][koff];
            #pragma unroll
            for (int mt = 0; mt < 4; mt++)
                #pragma unroll
                for (int nt = 0; nt < 4; nt++)
                    acc[mt][nt] = __builtin_amdgcn_mfma_f32_16x16x32_bf16(
                        av[mt], bv[nt], acc[mt][nt], 0, 0, 0);
        }
        __syncthreads();
    }
    const int cr0 = m0 + wm + ((lane >> 4) << 2);
    const int cc0 = n0 + wn + (lane & 15);
    #pragma unroll
    for (int mt = 0; mt < 4; mt++)
        #pragma unroll
        for (int nt = 0; nt < 4; nt++) {
            const int c = cc0 + (nt << 4);
            if (c < 1 || c >= 593) continue;
            const float bo = b_out[c];
            #pragma unroll
            for (int j = 0; j < 4; j++) {
                int r = cr0 + (mt << 4) + j;
                if (r < M) {
                    float v = acc[mt][nt][j] + bo;
                    float s = 1.0f / (1.0f + __expf(-v));
                    float p = 2.0f * __powf(s, 2.3025851f) + 1e-7f;
                    if (c < 513) SPb[(size_t)r * 512 + (c - 1)] = __float2bfloat16(p);
                    else         NP[(size_t)r * 80 + (c - 513)] = p;
                }
            }
        }
}

// ---------------------------------------------------------------------------
__global__ __launch_bounds__(256) void convert_wout(
    const float* __restrict__ W, __hip_bfloat16* __restrict__ WTb)
{
    const int n = blockIdx.x;           // 0..639
    const int k = threadIdx.x;          // 0..255
    float v = (n < 593) ? W[(size_t)k * 593 + n] : 0.0f;
    WTb[(size_t)n * 256 + k] = __float2bfloat16(v);
}

// exact-fp32 f0 logit + fused precise f0 transform
__global__ __launch_bounds__(256) void f0_gemv(
    const float* __restrict__ h3, const float* __restrict__ Wout,
    const float* __restrict__ b_out, float* __restrict__ f0w, float* __restrict__ f0out)
{
    const int row = blockIdx.x * 4 + (threadIdx.x >> 6);
    const int lane = threadIdx.x & 63;
    const float* a = h3 + (size_t)row * 256;
    float s = 0.0f;
    #pragma unroll
    for (int q = 0; q < 4; q++) {
        int k = lane + (q << 6);
        s = fmaf(a[k], Wout[(size_t)k * 593], s);
    }
    #pragma unroll
    for (int off = 32; off; off >>= 1) s += __shfl_down(s, off, 64);
    if (lane == 0) {
        float lg = s + b_out[0];
        float sg = 1.0f / (1.0f + expf(-lg));
        float f0 = 80.0f * powf(12.5f, sg);
        if (f0 < 80.0f) f0 = 0.0f;
        f0w[row] = f0;
        f0out[row] = f0;
    }
}

// ---------------------------------------------------------------------------
// Parallel fp64 frame-level pitch scan
// ---------------------------------------------------------------------------
__device__ inline double shfl_up_d(double x, int off) {
    long long l = __double_as_longlong(x);
    int lo = (int)(l & 0xffffffffLL);
    int hi = (int)(l >> 32);
    lo = __shfl_up(lo, off, 64);
    hi = __shfl_up(hi, off, 64);
    return __longlong_as_double(((long long)hi << 32) | (unsigned int)lo);
}

__global__ __launch_bounds__(256) void scan_par_kernel(
    const float* __restrict__ f0w, const float* __restrict__ iphase,
    double* __restrict__ base, float* __restrict__ fph)
{
    __shared__ double wsum[4];
    const int b = blockIdx.x;
    const int tid = threadIdx.x;
    const int lane = tid & 63;
    const float* f0 = f0w + b * 1000;
    double s[4];
    double loc = 0.0;
    #pragma unroll
    for (int q = 0; q < 4; q++) {
        int f = tid * 4 + q;
        s[q] = loc;
        if (f < 1000) {
            double c  = (double)f0[f];
            double nx = (double)f0[(f < 999) ? (f + 1) : 999];
            loc += 120.5 * c + 119.5 * nx;
        }
    }
    double v = loc;
    #pragma unroll
    for (int off = 1; off < 64; off <<= 1) {
        double o = shfl_up_d(v, off);
        if (lane >= off) v += o;
    }
    if (lane == 63) wsum[tid >> 6] = v;
    __syncthreads();
    double wpre = 0.0;
    const int w = tid >> 6;
    for (int i = 0; i < w; i++) wpre += wsum[i];
    const double excl = wpre + v - loc;
    #pragma unroll
    for (int q = 0; q < 4; q++) {
        int f = tid * 4 + q;
        if (f < 1000) base[b * 1000 + f] = excl + s[q];
    }
    if (tid == 255) {
        double total = excl + loc;
        double u  = total * (1.0 / 24000.0);
        double ph = TWO_PI_D * u + (double)iphase[b];
        fph[b] = (float)fmod(ph, TWO_PI_D);
    }
}

// ---------------------------------------------------------------------------
// threefry2x32 (bit-exact jax.random.uniform, key (0,123), N=1,920,000)
// ---------------------------------------------------------------------------
__device__ inline unsigned rotl32(unsigned x, int d) { return (x << d) | (x >> (32 - d)); }

__device__ inline float threefry_noise(unsigned mi)
{
    const unsigned n2 = 960000u;
    unsigned i0 = (mi < n2) ? mi : (mi - n2);
    unsigned x0 = i0, x1 = i0 + n2;
    const unsigned ks0 = 0u, ks1 = 123u, ks2 = 0x1BD11BDAu ^ 0u ^ 123u;
    x0 += ks0; x1 += ks1;
#define TF_R(rot) { x0 += x1; x1 = rotl32(x1, rot); x1 ^= x0; }
    TF_R(13) TF_R(15) TF_R(26) TF_R(6)
    x0 += ks1; x1 += ks2 + 1u;
    TF_R(17) TF_R(29) TF_R(16) TF_R(24)
    x0 += ks2; x1 += ks0 + 2u;
    TF_R(13) TF_R(15) TF_R(26) TF_R(6)
    x0 += ks0; x1 += ks1 + 3u;
    TF_R(17) TF_R(29) TF_R(16) TF_R(24)
    x0 += ks1; x1 += ks2 + 4u;
    TF_R(13) TF_R(15) TF_R(26) TF_R(6)
    x0 += ks2; x1 += ks0 + 5u;
#undef TF_R
    unsigned bits = (mi < n2) ? x0 : x1;
    float uf = __uint_as_float((bits >> 9) | 0x3f800000u) - 1.0f;
    return uf * 2.0f - 1.0f;
}

// fp64 sawtooth sample (exact same formula as the former saw_noise_kernel)
__device__ inline float saw_sample(const float* __restrict__ f0w,
                                   const double* __restrict__ base,
                                   const float* __restrict__ iphase,
                                   int b, int f, int r)
{
    double c  = (double)f0w[b * 1000 + f];
    double nx = (double)f0w[b * 1000 + ((f < 999) ? (f + 1) : 999)];
    double rr = (double)r;
    double Bc = rr * (rr + 1.0) * (1.0 / 480.0);
    double Ac = (rr + 1.0) - Bc;
    double cum = base[b * 1000 + f] + Ac * c + Bc * nx;
    double u  = cum * (1.0 / 24000.0) + (double)iphase[b] * (1.0 / TWO_PI_D);
    double fr = u - floor(u);
    return (float)(2.0 * fr - 1.0);
}

// ---------------------------------------------------------------------------
// Per-frame conv, harmonic. One WAVE per frame, 4 frames/block (256 thr) —
// R9-measured-best shape. Saw generation FUSED into u staging (fp64).
// Lane owns 20 outputs; per-lane w stride = 5 chunks (odd) -> conflict floor.
// ---------------------------------------------------------------------------
__global__ __launch_bounds__(256) void frameconv_h(
    const float* __restrict__ f0w, const double* __restrict__ base,
    const float* __restrict__ iphase, const float* __restrict__ IR,
    float* __restrict__ Y)
{
    constexpr int WOFF = 244;            // left zero-pad words (chunk-aligned)
    constexpr int WSZ  = 1536;           // per-frame padded w words
    __shared__ float u_s[4][240];
    __shared__ __align__(16) float w_s[4][WSZ];
    const int fq  = blockIdx.x;          // frame quad 0..249
    const int b   = blockIdx.y;
    const int tid = threadIdx.x;
    const int wv  = tid >> 6;            // wave = frame within quad
    const int lane = tid & 63;

    for (int i = tid; i < 4 * WSZ; i += 256) {
        int fr = i / WSZ, r = i - fr * WSZ;
        int d = r - WOFF;
        float v = 0.0f;
        if (d >= 0 && d < 1022)
            v = IR[((size_t)b * 1000 + fq * 4 + fr) * 1024 + d];
        w_s[fr][r] = v;
    }
    for (int i = tid; i < 4 * 240; i += 256) {
        int fr = i / 240, r = i - fr * 240;
        u_s[fr][r] = saw_sample(f0w, base, iphase, b, fq * 4 + fr, r);
    }
    __syncthreads();

    const float* wf = w_s[wv];
    const float* uf = u_s[wv];
    const int j0 = 20 * lane;
    float acc[20];
    #pragma unroll
    for (int q = 0; q < 20; q++) acc[q] = 0.0f;

    float C[24];
    const int wb0 = WOFF + j0 - 4;       // 16B-aligned
    #pragma unroll
    for (int h = 0; h < 6; h++)
        *(float4*)&C[4 * h] = *(const float4*)&wf[wb0 + 4 * h];
    int ldw = wb0 - 4;

    #pragma unroll 1
    for (int M = 0; M < 10; M++) {
        #pragma unroll
        for (int p = 0; p < 6; p++) {
            const int i0 = 24 * M + 4 * p;
            float4 u4 = *(const float4*)&uf[i0];
            float uu[4] = {u4.x, u4.y, u4.z, u4.w};
            #pragma unroll
            for (int q = 0; q < 20; q++)
                #pragma unroll
                for (int k = 0; k < 4; k++) {
                    const int rel  = q - k + 4;              // 1..23
                    const int h    = rel >> 2;               // 0..5
                    const int slot = ((h - p) % 6 + 6) % 6;  // static
                    acc[q] = fmaf(uu[k], C[4 * slot + (rel & 3)], acc[q]);
                }
            const int lslot = ((-1 - p) % 6 + 6) % 6;
            *(float4*)&C[4 * lslot] = *(const float4*)&wf[ldw];
            ldw -= 4;
        }
    }

    float* yp = &Y[((size_t)b * 1000 + fq * 4 + wv) * 1280 + j0];
    #pragma unroll
    for (int cc = 0; cc < 5; cc++) {
        float4 r4 = {acc[4*cc], acc[4*cc+1], acc[4*cc+2], acc[4*cc+3]};
        *(float4*)&yp[4*cc] = r4;
    }
}

// ---------------------------------------------------------------------------
// Per-frame conv, noise: iterate IR, window over audio. Noise generation
// (threefry) FUSED into the audio staging — nz never hits HBM.
// ---------------------------------------------------------------------------
#define CONV_GROUP(u4) \
    a0 = fmaf(u4.x, Whi.x, a0); a1 = fmaf(u4.x, Whi.y, a1); a2 = fmaf(u4.x, Whi.z, a2); a3 = fmaf(u4.x, Whi.w, a3); \
    a0 = fmaf(u4.y, Wlo.w, a0); a1 = fmaf(u4.y, Whi.x, a1); a2 = fmaf(u4.y, Whi.y, a2); a3 = fmaf(u4.y, Whi.z, a3); \
    a0 = fmaf(u4.z, Wlo.z, a0); a1 = fmaf(u4.z, Wlo.w, a1); a2 = fmaf(u4.z, Whi.x, a2); a3 = fmaf(u4.z, Whi.y, a3); \
    a0 = fmaf(u4.w, Wlo.y, a0); a1 = fmaf(u4.w, Wlo.z, a1); a2 = fmaf(u4.w, Wlo.w, a2); a3 = fmaf(u4.w, Whi.x, a3);

__global__ __launch_bounds__(128) void frameconv_n(
    const float* __restrict__ IR, float* __restrict__ Y)
{
    __shared__ __align__(16) float u_s[160];
    __shared__ __align__(16) float w_s[560];
    const int f = blockIdx.x;
    const int b = blockIdx.y;
    const int tid = threadIdx.x;
    const float* irow = IR + ((size_t)b * 1000 + f) * 158;
    for (int i = tid; i < 160; i += 128) {
        u_s[i] = (i < 158) ? irow[i] : 0.0f;
        w_s[i] = 0.0f;
        w_s[400 + i] = 0.0f;
    }
    for (int i = tid; i < 240; i += 128)
        w_s[160 + i] = threefry_noise((unsigned)(b * 240000 + f * 240 + i));
    __syncthreads();

    const int j0 = tid << 2;
    if (j0 >= 400) return;
    int base = 160 + j0 - 4;
    float4 Wlo = *(const float4*)&w_s[base];
    float4 Whi = *(const float4*)&w_s[base + 4];
    float a0 = 0.f, a1 = 0.f, a2 = 0.f, a3 = 0.f;
    #pragma unroll 4
    for (int t = 0; t < 156; t += 4) {
        float4 u4 = *(const float4*)&u_s[t];
        CONV_GROUP(u4)
        Whi = Wlo;
        base -= 4;
        Wlo = *(const float4*)&w_s[base];
    }
    {
        float4 u4 = *(const float4*)&u_s[156];
        CONV_GROUP(u4)
    }
    float4 r; r.x = a0; r.y = a1; r.z = a2; r.w = a3;
    *(float4*)&Y[((size_t)b * 1000 + f) * 400 + j0] = r;
}

// ---------------------------------------------------------------------------
// Overlap-add + 'same' slice + outputs (full range, single launch)
// ---------------------------------------------------------------------------
__global__ __launch_bounds__(256) void combine_kernel(
    const float* __restrict__ Yh, const float* __restrict__ Yn,
    float* __restrict__ sig, float* __restrict__ harm, float* __restrict__ noise)
{
    int t = blockIdx.x * 256 + threadIdx.x;
    if (t >= 240000) return;
    const int b = blockIdx.y;
    float hsum = 0.0f;
    const int fhi = (t + 509) / 240;
    #pragma unroll
    for (int q = 0; q < 6; q++) {
        int f = fhi - q;
        int j = t + 509 - 240 * f;
        if (f >= 0 && f < 1000 && j < 1261)
            hsum += Yh[((size_t)b * 1000 + f) * 1280 + j];
    }
    float nsum = 0.0f;
    const int ghi = (t + 77) / 240;
    #pragma unroll
    for (int q = 0; q < 2; q++) {
        int f = ghi - q;
        int j = t + 77 - 240 * f;
        if (f >= 0 && f < 1000 && j < 397)
            nsum += Yn[((size_t)b * 1000 + f) * 400 + j];
    }
    size_t o = (size_t)b * 240000 + t;
    harm[o]  = hsum;
    noise[o] = nsum;
    sig[o]   = hsum + nsum;
}

// ---------------------------------------------------------------------------
extern "C" void kernel_launch(void* const* d_in, const int* in_sizes, int n_in,
                              void* d_out, int out_size, void* d_ws, size_t ws_size,
                              hipStream_t stream)
{
    (void)in_sizes; (void)n_in; (void)out_size; (void)ws_size;
    const float* mel    = (const float*)d_in[0];
    const float* iphase = (const float*)d_in[1];
    const float* W_in   = (const float*)d_in[2];
    const float* b_in   = (const float*)d_in[3];
    const float* W1     = (const float*)d_in[4];
    const float* b1     = (const float*)d_in[5];
    const float* W2     = (const float*)d_in[6];
    const float* b2     = (const float*)d_in[7];
    const float* W_out  = (const float*)d_in[8];
    const float* b_out  = (const float*)d_in[9];
    float* ws = (float*)d_ws;

    // workspace layout (float offsets)
    __hip_bfloat16* Chb = (__hip_bfloat16*)(ws + 0);        // [1024][512] bf16
    float*  Cn      = ws + 262144;                          // 12,640
    __hip_bfloat16* SPb = (__hip_bfloat16*)(ws + 274784);   // [8000][512] bf16
    float*  NP      = ws + 2322784;                         // 640,000
    float*  f0w     = ws + 3440640;                         // 8,000
    double* base    = (double*)(ws + 3448640);              // 8,000 dbl
    float*  BA      = ws + 7312640;                         // 2,048,000 (h1,h3)
    float*  BB      = ws + 9360640;                         // 2,048,000 (h2)
    __hip_bfloat16* BAb = (__hip_bfloat16*)(ws + 11408640); // [8000][256] bf16
    __hip_bfloat16* WTb = (__hip_bfloat16*)(ws + 12432640); // [640][256] bf16
    float*  IRh     = ws + 7312640;                         // [8000][1024] (aliases BA.., dead then)
    float*  IRn     = ws + 17634560;                        // 1,264,000
    float*  YhF     = ws + 18898560;                        // [8][1000][1280] = 10,240,000
    float*  YnF     = ws + 29138560;                        // [8][1000][400]  =  3,200,000

    float* out       = (float*)d_out;
    float* sig_out   = out;
    float* f0_out    = out + 1920000;
    float* fph_out   = out + 1928000;
    float* harm_out  = out + 1928008;
    float* noise_out = out + 3848008;

    basis_h_bf16_t<<<1024, 256, 0, stream>>>(Chb);
    basis_kernel<80, 158><<<80, 256, 0, stream>>>(Cn);

    // MLP hidden layers in fp32 (f0-precision path); 3rd layer mirrors bf16
    gemm_kernel<0><<<dim3(125, 4), 256, 0, stream>>>(mel, W_in, b_in, nullptr, BA, nullptr, 8000, 256, 80);
    gemm_kernel<1><<<dim3(125, 4), 256, 0, stream>>>(BA,  W1,   b1,   BA,      BB, nullptr, 8000, 256, 256);
    gemm_kernel<1><<<dim3(125, 4), 256, 0, stream>>>(BB,  W2,   b2,   BB,      BA, BAb,     8000, 256, 256);

    // W_out: bf16 MFMA with fused exp_sigmoid epilogue + exact fp32 f0 GEMV
    convert_wout<<<640, 256, 0, stream>>>(W_out, WTb);
    mfma_gemm_sp<<<dim3(63, 5), 256, 0, stream>>>(
        (const unsigned short*)BAb, (const unsigned short*)WTb, b_out, SPb, NP, 8000);
    f0_gemv<<<2000, 256, 0, stream>>>(BA, W_out, b_out, f0w, f0_out);

    scan_par_kernel<<<8, 256, 0, stream>>>(f0w, iphase, base, fph_out);

    // IR_h = SPb @ Chb^T  (bf16 MFMA, fp32 out, stride 1024)
    mfma_gemm<512, 1024><<<dim3(63, 8), 256, 0, stream>>>(
        (const unsigned short*)SPb, (const unsigned short*)Chb, IRh, 8000);
    // IR_n fp32
    gemm_kernel<2><<<dim3(125, 3), 256, 0, stream>>>(NP, Cn, nullptr, nullptr, IRn, nullptr, 8000, 158, 80);

    // per-frame conv (saw / noise generated in-kernel) + overlap-add
    frameconv_h<<<dim3(250, 8), 256, 0, stream>>>(f0w, base, iphase, IRh, YhF);
    frameconv_n<<<dim3(1000, 8), 128, 0, stream>>>(IRn, YnF);
    combine_kernel<<<dim3(938, 8), 256, 0, stream>>>(YhF, YnF, sig_out, harm_out, noise_out);
}

// Round 12
// 293.147 us; speedup vs baseline: 1.1070x; 1.0703x over previous
//
#include <hip/hip_runtime.h>
#include <hip/hip_bf16.h>
#include <math.h>

#define TWO_PI_D 6.283185307179586476925286766559
#define TWO_PI_F 6.28318530718f

typedef short bf16x8 __attribute__((ext_vector_type(8)));
typedef float f32x4 __attribute__((ext_vector_type(4)));

// ---------------------------------------------------------------------------
// Harmonic basis, bf16, TRANSPOSED + padded: Ct[n][k], n<1024 (1022 valid), k<512
// ---------------------------------------------------------------------------
__global__ __launch_bounds__(256) void basis_h_bf16_t(__hip_bfloat16* __restrict__ Ct)
{
    const int n = blockIdx.x;            // 0..1023
    for (int k = threadIdx.x; k < 512; k += 256) {
        float v = 0.0f;
        if (n < 1022) {
            float hann = 0.5f * (1.0f - cosf(TWO_PI_F * (float)n / 1022.0f));
            float w = hann * (1.0f / 1022.0f);
            if (k == 0) v = w;
            else if (k == 511) v = (n & 1) ? w : -w;
            else {
                int m = (k * n) % 1022;
                float c = cosf(TWO_PI_F * (float)m / 1022.0f);
                v = 2.0f * w * ((k & 1) ? -c : c);
            }
        }
        Ct[(size_t)n * 512 + k] = __float2bfloat16(v);
    }
}

// noise basis, fp32: C[k][n], k<80, n<158
template<int NMAG, int NIR>
__global__ __launch_bounds__(256) void basis_kernel(float* __restrict__ C)
{
    const int k = blockIdx.x;
    for (int n = threadIdx.x; n < NIR; n += blockDim.x) {
        double hann = 0.5 * (1.0 - cos(TWO_PI_D * (double)n / (double)NIR));
        double w = hann / (double)NIR;
        double v;
        if (k == 0) v = w;
        else if (k == NMAG - 1) v = (n & 1) ? w : -w;
        else {
            long m = ((long)k * (long)n) % NIR;
            double c = cos(TWO_PI_D * (double)m / (double)NIR);
            v = 2.0 * w * ((k & 1) ? -c : c);
        }
        C[(size_t)k * NIR + n] = (float)v;
    }
}

// ---------------------------------------------------------------------------
// fp32 tiled GEMM 64x64x16 — precision path (MLP hidden layers + noise IR).
// ---------------------------------------------------------------------------
__device__ inline float gelu_f(float x) {
    float x3 = x * x * x;
    float t = tanhf(0.7978845608028654f * (x + 0.044715f * x3));
    return 0.5f * x * (1.0f + t);
}

template<int MODE>
__global__ __launch_bounds__(256) void gemm_kernel(
    const float* __restrict__ A, const float* __restrict__ Bm,
    const float* __restrict__ bias, const float* __restrict__ resid,
    float* __restrict__ C, __hip_bfloat16* __restrict__ Cb, int M, int N, int K)
{
    __shared__ float As[16][68];
    __shared__ float Bs[16][68];
    const int tid = threadIdx.x;
    const int tx = tid & 15, ty = tid >> 4;
    const int m0 = blockIdx.x * 64;
    const int n0 = blockIdx.y * 64;
    const int ar  = tid >> 2;
    const int ac4 = (tid & 3) << 2;
    const int bk  = tid >> 4;
    const int bn4 = (tid & 15) << 2;
    float acc[4][4] = {};
    for (int k0 = 0; k0 < K; k0 += 16) {
        float4 av = *(const float4*)(A + (size_t)(m0 + ar) * K + k0 + ac4);
        As[ac4 + 0][ar] = av.x;
        As[ac4 + 1][ar] = av.y;
        As[ac4 + 2][ar] = av.z;
        As[ac4 + 3][ar] = av.w;
        const float* Bp = Bm + (size_t)(k0 + bk) * N + n0 + bn4;
        #pragma unroll
        for (int i = 0; i < 4; i++)
            Bs[bk][bn4 + i] = (n0 + bn4 + i < N) ? Bp[i] : 0.0f;
        __syncthreads();
        #pragma unroll
        for (int kk = 0; kk < 16; kk++) {
            float4 a4 = *(const float4*)&As[kk][ty << 2];
            float4 b4 = *(const float4*)&Bs[kk][tx << 2];
            float a[4] = {a4.x, a4.y, a4.z, a4.w};
            float b[4] = {b4.x, b4.y, b4.z, b4.w};
            #pragma unroll
            for (int i = 0; i < 4; i++)
                #pragma unroll
                for (int j = 0; j < 4; j++)
                    acc[i][j] = fmaf(a[i], b[j], acc[i][j]);
        }
        __syncthreads();
    }
    #pragma unroll
    for (int i = 0; i < 4; i++) {
        int m = m0 + (ty << 2) + i;
        #pragma unroll
        for (int j = 0; j < 4; j++) {
            int n = n0 + (tx << 2) + j;
            if (n < N) {
                float v = acc[i][j];
                if (bias) v += bias[n];
                if (MODE == 0) v = tanhf(v);
                else if (MODE == 1) v = resid[(size_t)m * N + n] + gelu_f(v);
                C[(size_t)m * N + n] = v;
                if (MODE == 1 && Cb) Cb[(size_t)m * N + n] = __float2bfloat16(v);
            }
        }
    }
}

// ---------------------------------------------------------------------------
// bf16 MFMA GEMM: A [M][K] bf16, Bt [NPAD][K] bf16, C [M][NSTRIDE] fp32
// ---------------------------------------------------------------------------
template<int K, int NSTRIDE>
__global__ __launch_bounds__(256) void mfma_gemm(
    const unsigned short* __restrict__ A, const unsigned short* __restrict__ Bt,
    float* __restrict__ C, int M)
{
    __shared__ __align__(16) unsigned short As[128][72];
    __shared__ __align__(16) unsigned short Bs[128][72];
    const int tid = threadIdx.x;
    const int m0 = blockIdx.x * 128;
    const int n0 = blockIdx.y * 128;
    const int wid = tid >> 6;
    const int lane = tid & 63;
    const int wm = (wid >> 1) << 6;
    const int wn = (wid & 1) << 6;

    f32x4 acc[4][4];
    #pragma unroll
    for (int i = 0; i < 4; i++)
        #pragma unroll
        for (int j = 0; j < 4; j++)
            acc[i][j] = (f32x4){0.f, 0.f, 0.f, 0.f};

    for (int k0 = 0; k0 < K; k0 += 64) {
        #pragma unroll
        for (int s = 0; s < 4; s++) {
            int g = tid + (s << 8);
            int row = g >> 3;
            int kc = (g & 7) << 3;
            int ra = m0 + row; if (ra > M - 1) ra = M - 1;
            *(uint4*)&As[row][kc] = *(const uint4*)&A[(size_t)ra * K + k0 + kc];
            *(uint4*)&Bs[row][kc] = *(const uint4*)&Bt[(size_t)(n0 + row) * K + k0 + kc];
        }
        __syncthreads();
        #pragma unroll
        for (int kk = 0; kk < 64; kk += 32) {
            bf16x8 av[4], bv[4];
            const int koff = kk + ((lane >> 4) << 3);
            #pragma unroll
            for (int mt = 0; mt < 4; mt++)
                av[mt] = *(const bf16x8*)&As[wm + (mt << 4) + (lane & 15)][koff];
            #pragma unroll
            for (int nt = 0; nt < 4; nt++)
                bv[nt] = *(const bf16x8*)&Bs[wn + (nt << 4) + (lane & 15)][koff];
            #pragma unroll
            for (int mt = 0; mt < 4; mt++)
                #pragma unroll
                for (int nt = 0; nt < 4; nt++)
                    acc[mt][nt] = __builtin_amdgcn_mfma_f32_16x16x32_bf16(
                        av[mt], bv[nt], acc[mt][nt], 0, 0, 0);
        }
        __syncthreads();
    }
    const int cr0 = m0 + wm + ((lane >> 4) << 2);
    const int cc0 = n0 + wn + (lane & 15);
    #pragma unroll
    for (int mt = 0; mt < 4; mt++)
        #pragma unroll
        for (int nt = 0; nt < 4; nt++)
            #pragma unroll
            for (int j = 0; j < 4; j++) {
                int r = cr0 + (mt << 4) + j;
                if (r < M) C[(size_t)r * NSTRIDE + cc0 + (nt << 4)] = acc[mt][nt][j];
            }
}

// ---------------------------------------------------------------------------
__global__ __launch_bounds__(256) void convert_wout(
    const float* __restrict__ W, __hip_bfloat16* __restrict__ WTb)
{
    const int n = blockIdx.x;           // 0..639
    const int k = threadIdx.x;          // 0..255
    float v = (n < 593) ? W[(size_t)k * 593 + n] : 0.0f;
    WTb[(size_t)n * 256 + k] = __float2bfloat16(v);
}

// exact-fp32 f0 logit + fused precise f0 transform
__global__ __launch_bounds__(256) void f0_gemv(
    const float* __restrict__ h3, const float* __restrict__ Wout,
    const float* __restrict__ b_out, float* __restrict__ f0w, float* __restrict__ f0out)
{
    const int row = blockIdx.x * 4 + (threadIdx.x >> 6);
    const int lane = threadIdx.x & 63;
    const float* a = h3 + (size_t)row * 256;
    float s = 0.0f;
    #pragma unroll
    for (int q = 0; q < 4; q++) {
        int k = lane + (q << 6);
        s = fmaf(a[k], Wout[(size_t)k * 593], s);
    }
    #pragma unroll
    for (int off = 32; off; off >>= 1) s += __shfl_down(s, off, 64);
    if (lane == 0) {
        float lg = s + b_out[0];
        float sg = 1.0f / (1.0f + expf(-lg));
        float f0 = 80.0f * powf(12.5f, sg);
        if (f0 < 80.0f) f0 = 0.0f;
        f0w[row] = f0;
        f0out[row] = f0;
    }
}

// ---------------------------------------------------------------------------
// SP/NP from O[8000][640] cols 1..592 (+bias), fast-math exp_sigmoid
// ---------------------------------------------------------------------------
__global__ __launch_bounds__(256) void transform2_kernel(
    const float* __restrict__ O, const float* __restrict__ b_out,
    __hip_bfloat16* __restrict__ SPb, float* __restrict__ NP)
{
    int idx = blockIdx.x * 256 + threadIdx.x;
    if (idx >= 8000 * 592) return;
    int row = idx / 592;
    int c = idx - row * 592 + 1;
    float v = O[(size_t)row * 640 + c] + b_out[c];
    float s = 1.0f / (1.0f + __expf(-v));
    float p = 2.0f * __powf(s, 2.3025851f) + 1e-7f;
    if (c < 513) SPb[(size_t)row * 512 + (c - 1)] = __float2bfloat16(p);
    else         NP[(size_t)row * 80 + (c - 513)] = p;
}

// ---------------------------------------------------------------------------
// Parallel fp64 frame-level pitch scan
// ---------------------------------------------------------------------------
__device__ inline double shfl_up_d(double x, int off) {
    long long l = __double_as_longlong(x);
    int lo = (int)(l & 0xffffffffLL);
    int hi = (int)(l >> 32);
    lo = __shfl_up(lo, off, 64);
    hi = __shfl_up(hi, off, 64);
    return __longlong_as_double(((long long)hi << 32) | (unsigned int)lo);
}

__global__ __launch_bounds__(256) void scan_par_kernel(
    const float* __restrict__ f0w, const float* __restrict__ iphase,
    double* __restrict__ base, float* __restrict__ fph)
{
    __shared__ double wsum[4];
    const int b = blockIdx.x;
    const int tid = threadIdx.x;
    const int lane = tid & 63;
    const float* f0 = f0w + b * 1000;
    double s[4];
    double loc = 0.0;
    #pragma unroll
    for (int q = 0; q < 4; q++) {
        int f = tid * 4 + q;
        s[q] = loc;
        if (f < 1000) {
            double c  = (double)f0[f];
            double nx = (double)f0[(f < 999) ? (f + 1) : 999];
            loc += 120.5 * c + 119.5 * nx;
        }
    }
    double v = loc;
    #pragma unroll
    for (int off = 1; off < 64; off <<= 1) {
        double o = shfl_up_d(v, off);
        if (lane >= off) v += o;
    }
    if (lane == 63) wsum[tid >> 6] = v;
    __syncthreads();
    double wpre = 0.0;
    const int w = tid >> 6;
    for (int i = 0; i < w; i++) wpre += wsum[i];
    const double excl = wpre + v - loc;
    #pragma unroll
    for (int q = 0; q < 4; q++) {
        int f = tid * 4 + q;
        if (f < 1000) base[b * 1000 + f] = excl + s[q];
    }
    if (tid == 255) {
        double total = excl + loc;
        double u  = total * (1.0 / 24000.0);
        double ph = TWO_PI_D * u + (double)iphase[b];
        fph[b] = (float)fmod(ph, TWO_PI_D);
    }
}

// ---------------------------------------------------------------------------
// threefry2x32 (bit-exact jax.random.uniform, key (0,123), N=1,920,000)
// ---------------------------------------------------------------------------
__device__ inline unsigned rotl32(unsigned x, int d) { return (x << d) | (x >> (32 - d)); }

__device__ inline float threefry_noise(unsigned mi)
{
    const unsigned n2 = 960000u;
    unsigned i0 = (mi < n2) ? mi : (mi - n2);
    unsigned x0 = i0, x1 = i0 + n2;
    const unsigned ks0 = 0u, ks1 = 123u, ks2 = 0x1BD11BDAu ^ 0u ^ 123u;
    x0 += ks0; x1 += ks1;
#define TF_R(rot) { x0 += x1; x1 = rotl32(x1, rot); x1 ^= x0; }
    TF_R(13) TF_R(15) TF_R(26) TF_R(6)
    x0 += ks1; x1 += ks2 + 1u;
    TF_R(17) TF_R(29) TF_R(16) TF_R(24)
    x0 += ks2; x1 += ks0 + 2u;
    TF_R(13) TF_R(15) TF_R(26) TF_R(6)
    x0 += ks0; x1 += ks1 + 3u;
    TF_R(17) TF_R(29) TF_R(16) TF_R(24)
    x0 += ks1; x1 += ks2 + 4u;
    TF_R(13) TF_R(15) TF_R(26) TF_R(6)
    x0 += ks2; x1 += ks0 + 5u;
#undef TF_R
    unsigned bits = (mi < n2) ? x0 : x1;
    float uf = __uint_as_float((bits >> 9) | 0x3f800000u) - 1.0f;
    return uf * 2.0f - 1.0f;
}

// fp64 sawtooth sample (exact same formula as the original saw_noise_kernel)
__device__ inline float saw_sample(const float* __restrict__ f0w,
                                   const double* __restrict__ base,
                                   const float* __restrict__ iphase,
                                   int b, int f, int r)
{
    double c  = (double)f0w[b * 1000 + f];
    double nx = (double)f0w[b * 1000 + ((f < 999) ? (f + 1) : 999)];
    double rr = (double)r;
    double Bc = rr * (rr + 1.0) * (1.0 / 480.0);
    double Ac = (rr + 1.0) - Bc;
    double cum = base[b * 1000 + f] + Ac * c + Bc * nx;
    double u  = cum * (1.0 / 24000.0) + (double)iphase[b] * (1.0 / TWO_PI_D);
    double fr = u - floor(u);
    return (float)(2.0 * fr - 1.0);
}

// ---------------------------------------------------------------------------
// Per-frame conv, harmonic. One WAVE per frame, 4 frames/block (256 thr) —
// R9-measured-best shape. Saw generation FUSED into u staging (fp64).
// Lane owns 20 outputs; per-lane w stride = 5 chunks (odd) -> conflict floor.
// ---------------------------------------------------------------------------
__global__ __launch_bounds__(256) void frameconv_h(
    const float* __restrict__ f0w, const double* __restrict__ base,
    const float* __restrict__ iphase, const float* __restrict__ IR,
    float* __restrict__ Y)
{
    constexpr int WOFF = 244;            // left zero-pad words (chunk-aligned)
    constexpr int WSZ  = 1536;           // per-frame padded w words
    __shared__ float u_s[4][240];
    __shared__ __align__(16) float w_s[4][WSZ];
    const int fq  = blockIdx.x;          // frame quad 0..249
    const int b   = blockIdx.y;
    const int tid = threadIdx.x;
    const int wv  = tid >> 6;            // wave = frame within quad
    const int lane = tid & 63;

    for (int i = tid; i < 4 * WSZ; i += 256) {
        int fr = i / WSZ, r = i - fr * WSZ;
        int d = r - WOFF;
        float v = 0.0f;
        if (d >= 0 && d < 1022)
            v = IR[((size_t)b * 1000 + fq * 4 + fr) * 1024 + d];
        w_s[fr][r] = v;
    }
    for (int i = tid; i < 4 * 240; i += 256) {
        int fr = i / 240, r = i - fr * 240;
        u_s[fr][r] = saw_sample(f0w, base, iphase, b, fq * 4 + fr, r);
    }
    __syncthreads();

    const float* wf = w_s[wv];
    const float* uf = u_s[wv];
    const int j0 = 20 * lane;
    float acc[20];
    #pragma unroll
    for (int q = 0; q < 20; q++) acc[q] = 0.0f;

    float C[24];
    const int wb0 = WOFF + j0 - 4;       // 16B-aligned
    #pragma unroll
    for (int h = 0; h < 6; h++)
        *(float4*)&C[4 * h] = *(const float4*)&wf[wb0 + 4 * h];
    int ldw = wb0 - 4;

    #pragma unroll 1
    for (int M = 0; M < 10; M++) {
        #pragma unroll
        for (int p = 0; p < 6; p++) {
            const int i0 = 24 * M + 4 * p;
            float4 u4 = *(const float4*)&uf[i0];
            float uu[4] = {u4.x, u4.y, u4.z, u4.w};
            #pragma unroll
            for (int q = 0; q < 20; q++)
                #pragma unroll
                for (int k = 0; k < 4; k++) {
                    const int rel  = q - k + 4;              // 1..23
                    const int h    = rel >> 2;               // 0..5
                    const int slot = ((h - p) % 6 + 6) % 6;  // static
                    acc[q] = fmaf(uu[k], C[4 * slot + (rel & 3)], acc[q]);
                }
            const int lslot = ((-1 - p) % 6 + 6) % 6;
            *(float4*)&C[4 * lslot] = *(const float4*)&wf[ldw];
            ldw -= 4;
        }
    }

    float* yp = &Y[((size_t)b * 1000 + fq * 4 + wv) * 1280 + j0];
    #pragma unroll
    for (int cc = 0; cc < 5; cc++) {
        float4 r4 = {acc[4*cc], acc[4*cc+1], acc[4*cc+2], acc[4*cc+3]};
        *(float4*)&yp[4*cc] = r4;
    }
}

// ---------------------------------------------------------------------------
// Per-frame conv, noise: iterate IR, window over audio. Noise generation
// (threefry) FUSED into the audio staging — nz never hits HBM.
// ---------------------------------------------------------------------------
#define CONV_GROUP(u4) \
    a0 = fmaf(u4.x, Whi.x, a0); a1 = fmaf(u4.x, Whi.y, a1); a2 = fmaf(u4.x, Whi.z, a2); a3 = fmaf(u4.x, Whi.w, a3); \
    a0 = fmaf(u4.y, Wlo.w, a0); a1 = fmaf(u4.y, Whi.x, a1); a2 = fmaf(u4.y, Whi.y, a2); a3 = fmaf(u4.y, Whi.z, a3); \
    a0 = fmaf(u4.z, Wlo.z, a0); a1 = fmaf(u4.z, Wlo.w, a1); a2 = fmaf(u4.z, Whi.x, a2); a3 = fmaf(u4.z, Whi.y, a3); \
    a0 = fmaf(u4.w, Wlo.y, a0); a1 = fmaf(u4.w, Wlo.z, a1); a2 = fmaf(u4.w, Wlo.w, a2); a3 = fmaf(u4.w, Whi.x, a3);

__global__ __launch_bounds__(128) void frameconv_n(
    const float* __restrict__ IR, float* __restrict__ Y)
{
    __shared__ __align__(16) float u_s[160];
    __shared__ __align__(16) float w_s[560];
    const int f = blockIdx.x;
    const int b = blockIdx.y;
    const int tid = threadIdx.x;
    const float* irow = IR + ((size_t)b * 1000 + f) * 158;
    for (int i = tid; i < 160; i += 128) {
        u_s[i] = (i < 158) ? irow[i] : 0.0f;
        w_s[i] = 0.0f;
        w_s[400 + i] = 0.0f;
    }
    for (int i = tid; i < 240; i += 128)
        w_s[160 + i] = threefry_noise((unsigned)(b * 240000 + f * 240 + i));
    __syncthreads();

    const int j0 = tid << 2;
    if (j0 >= 400) return;
    int base = 160 + j0 - 4;
    float4 Wlo = *(const float4*)&w_s[base];
    float4 Whi = *(const float4*)&w_s[base + 4];
    float a0 = 0.f, a1 = 0.f, a2 = 0.f, a3 = 0.f;
    #pragma unroll 4
    for (int t = 0; t < 156; t += 4) {
        float4 u4 = *(const float4*)&u_s[t];
        CONV_GROUP(u4)
        Whi = Wlo;
        base -= 4;
        Wlo = *(const float4*)&w_s[base];
    }
    {
        float4 u4 = *(const float4*)&u_s[156];
        CONV_GROUP(u4)
    }
    float4 r; r.x = a0; r.y = a1; r.z = a2; r.w = a3;
    *(float4*)&Y[((size_t)b * 1000 + f) * 400 + j0] = r;
}

// ---------------------------------------------------------------------------
// Overlap-add + 'same' slice + outputs (full range, single launch)
// ---------------------------------------------------------------------------
__global__ __launch_bounds__(256) void combine_kernel(
    const float* __restrict__ Yh, const float* __restrict__ Yn,
    float* __restrict__ sig, float* __restrict__ harm, float* __restrict__ noise)
{
    int t = blockIdx.x * 256 + threadIdx.x;
    if (t >= 240000) return;
    const int b = blockIdx.y;
    float hsum = 0.0f;
    const int fhi = (t + 509) / 240;
    #pragma unroll
    for (int q = 0; q < 6; q++) {
        int f = fhi - q;
        int j = t + 509 - 240 * f;
        if (f >= 0 && f < 1000 && j < 1261)
            hsum += Yh[((size_t)b * 1000 + f) * 1280 + j];
    }
    float nsum = 0.0f;
    const int ghi = (t + 77) / 240;
    #pragma unroll
    for (int q = 0; q < 2; q++) {
        int f = ghi - q;
        int j = t + 77 - 240 * f;
        if (f >= 0 && f < 1000 && j < 397)
            nsum += Yn[((size_t)b * 1000 + f) * 400 + j];
    }
    size_t o = (size_t)b * 240000 + t;
    harm[o]  = hsum;
    noise[o] = nsum;
    sig[o]   = hsum + nsum;
}

// ---------------------------------------------------------------------------
extern "C" void kernel_launch(void* const* d_in, const int* in_sizes, int n_in,
                              void* d_out, int out_size, void* d_ws, size_t ws_size,
                              hipStream_t stream)
{
    (void)in_sizes; (void)n_in; (void)out_size; (void)ws_size;
    const float* mel    = (const float*)d_in[0];
    const float* iphase = (const float*)d_in[1];
    const float* W_in   = (const float*)d_in[2];
    const float* b_in   = (const float*)d_in[3];
    const float* W1     = (const float*)d_in[4];
    const float* b1     = (const float*)d_in[5];
    const float* W2     = (const float*)d_in[6];
    const float* b2     = (const float*)d_in[7];
    const float* W_out  = (const float*)d_in[8];
    const float* b_out  = (const float*)d_in[9];
    float* ws = (float*)d_ws;

    // workspace layout (float offsets), peak 32,338,560 floats = 129.4 MB
    __hip_bfloat16* Chb = (__hip_bfloat16*)(ws + 0);        // [1024][512] bf16
    float*  Cn      = ws + 262144;                          // 12,640
    __hip_bfloat16* SPb = (__hip_bfloat16*)(ws + 274784);   // [8000][512] bf16
    float*  NP      = ws + 2322784;                         // 640,000
    float*  f0w     = ws + 3440640;                         // 8,000
    double* base    = (double*)(ws + 3448640);              // 8,000 dbl
    float*  BA      = ws + 7312640;                         // 2,048,000 (h1,h3)
    float*  BB      = ws + 9360640;                         // 2,048,000 (h2)
    __hip_bfloat16* BAb = (__hip_bfloat16*)(ws + 11408640); // [8000][256] bf16
    __hip_bfloat16* WTb = (__hip_bfloat16*)(ws + 12432640); // [640][256] bf16
    float*  O       = ws + 12514560;                        // [8000][640] = 5,120,000
    float*  IRh     = ws + 7312640;                         // [8000][1024] (aliases BA..O, dead then)
    float*  IRn     = ws + 17634560;                        // 1,264,000
    float*  YhF     = ws + 18898560;                        // [8][1000][1280] = 10,240,000
    float*  YnF     = ws + 29138560;                        // [8][1000][400]  =  3,200,000

    float* out       = (float*)d_out;
    float* sig_out   = out;
    float* f0_out    = out + 1920000;
    float* fph_out   = out + 1928000;
    float* harm_out  = out + 1928008;
    float* noise_out = out + 3848008;

    basis_h_bf16_t<<<1024, 256, 0, stream>>>(Chb);
    basis_kernel<80, 158><<<80, 256, 0, stream>>>(Cn);

    // MLP hidden layers in fp32 (f0-precision path); 3rd layer mirrors bf16
    gemm_kernel<0><<<dim3(125, 4), 256, 0, stream>>>(mel, W_in, b_in, nullptr, BA, nullptr, 8000, 256, 80);
    gemm_kernel<1><<<dim3(125, 4), 256, 0, stream>>>(BA,  W1,   b1,   BA,      BB, nullptr, 8000, 256, 256);
    gemm_kernel<1><<<dim3(125, 4), 256, 0, stream>>>(BB,  W2,   b2,   BB,      BA, BAb,     8000, 256, 256);

    // W_out: bf16 MFMA -> O, then parallel transform2 (R9-proven path)
    // + exact fp32 GEMV (fused f0) for col 0
    convert_wout<<<640, 256, 0, stream>>>(W_out, WTb);
    mfma_gemm<256, 640><<<dim3(63, 5), 256, 0, stream>>>(
        (const unsigned short*)BAb, (const unsigned short*)WTb, O, 8000);
    f0_gemv<<<2000, 256, 0, stream>>>(BA, W_out, b_out, f0w, f0_out);

    transform2_kernel<<<(8000 * 592 + 255) / 256, 256, 0, stream>>>(O, b_out, SPb, NP);
    scan_par_kernel<<<8, 256, 0, stream>>>(f0w, iphase, base, fph_out);

    // IR_h = SPb @ Chb^T  (bf16 MFMA, fp32 out, stride 1024)
    mfma_gemm<512, 1024><<<dim3(63, 8), 256, 0, stream>>>(
        (const unsigned short*)SPb, (const unsigned short*)Chb, IRh, 8000);
    // IR_n fp32
    gemm_kernel<2><<<dim3(125, 3), 256, 0, stream>>>(NP, Cn, nullptr, nullptr, IRn, nullptr, 8000, 158, 80);

    // per-frame conv (saw / noise generated in-kernel) + overlap-add
    frameconv_h<<<dim3(250, 8), 256, 0, stream>>>(f0w, base, iphase, IRh, YhF);
    frameconv_n<<<dim3(1000, 8), 128, 0, stream>>>(IRn, YnF);
    combine_kernel<<<dim3(938, 8), 256, 0, stream>>>(YhF, YnF, sig_out, harm_out, noise_out);
}

// Round 13
// 254.166 us; speedup vs baseline: 1.2768x; 1.1534x over previous
//
#include <hip/hip_runtime.h>
#include <hip/hip_bf16.h>
#include <math.h>

#define TWO_PI_D 6.283185307179586476925286766559
#define TWO_PI_F 6.28318530718f

typedef short bf16x8 __attribute__((ext_vector_type(8)));
typedef float f32x4 __attribute__((ext_vector_type(4)));

static __device__ inline unsigned short f2bf(float v) {
    union { __hip_bfloat16 h; unsigned short u; } cv;
    cv.h = __float2bfloat16(v);
    return cv.u;
}

// ---------------------------------------------------------------------------
// Harmonic basis, bf16, TRANSPOSED + padded: Ct[n][k], n<1024 (1022 valid), k<512
// ---------------------------------------------------------------------------
__global__ __launch_bounds__(256) void basis_h_bf16_t(__hip_bfloat16* __restrict__ Ct)
{
    const int n = blockIdx.x;            // 0..1023
    for (int k = threadIdx.x; k < 512; k += 256) {
        float v = 0.0f;
        if (n < 1022) {
            float hann = 0.5f * (1.0f - cosf(TWO_PI_F * (float)n / 1022.0f));
            float w = hann * (1.0f / 1022.0f);
            if (k == 0) v = w;
            else if (k == 511) v = (n & 1) ? w : -w;
            else {
                int m = (k * n) % 1022;
                float c = cosf(TWO_PI_F * (float)m / 1022.0f);
                v = 2.0f * w * ((k & 1) ? -c : c);
            }
        }
        Ct[(size_t)n * 512 + k] = __float2bfloat16(v);
    }
}

// noise basis, fp32: C[k][n], k<80, n<158
template<int NMAG, int NIR>
__global__ __launch_bounds__(256) void basis_kernel(float* __restrict__ C)
{
    const int k = blockIdx.x;
    for (int n = threadIdx.x; n < NIR; n += blockDim.x) {
        double hann = 0.5 * (1.0 - cos(TWO_PI_D * (double)n / (double)NIR));
        double w = hann / (double)NIR;
        double v;
        if (k == 0) v = w;
        else if (k == NMAG - 1) v = (n & 1) ? w : -w;
        else {
            long m = ((long)k * (long)n) % NIR;
            double c = cos(TWO_PI_D * (double)m / (double)NIR);
            v = 2.0 * w * ((k & 1) ? -c : c);
        }
        C[(size_t)k * NIR + n] = (float)v;
    }
}

// ---------------------------------------------------------------------------
// fp32 tiled GEMM 64x64x16 — precision path (MLP hidden layers + noise IR).
// ---------------------------------------------------------------------------
__device__ inline float gelu_f(float x) {
    float x3 = x * x * x;
    float t = tanhf(0.7978845608028654f * (x + 0.044715f * x3));
    return 0.5f * x * (1.0f + t);
}

template<int MODE>
__global__ __launch_bounds__(256) void gemm_kernel(
    const float* __restrict__ A, const float* __restrict__ Bm,
    const float* __restrict__ bias, const float* __restrict__ resid,
    float* __restrict__ C, __hip_bfloat16* __restrict__ Cb, int M, int N, int K)
{
    __shared__ float As[16][68];
    __shared__ float Bs[16][68];
    const int tid = threadIdx.x;
    const int tx = tid & 15, ty = tid >> 4;
    const int m0 = blockIdx.x * 64;
    const int n0 = blockIdx.y * 64;
    const int ar  = tid >> 2;
    const int ac4 = (tid & 3) << 2;
    const int bk  = tid >> 4;
    const int bn4 = (tid & 15) << 2;
    float acc[4][4] = {};
    for (int k0 = 0; k0 < K; k0 += 16) {
        float4 av = *(const float4*)(A + (size_t)(m0 + ar) * K + k0 + ac4);
        As[ac4 + 0][ar] = av.x;
        As[ac4 + 1][ar] = av.y;
        As[ac4 + 2][ar] = av.z;
        As[ac4 + 3][ar] = av.w;
        const float* Bp = Bm + (size_t)(k0 + bk) * N + n0 + bn4;
        #pragma unroll
        for (int i = 0; i < 4; i++)
            Bs[bk][bn4 + i] = (n0 + bn4 + i < N) ? Bp[i] : 0.0f;
        __syncthreads();
        #pragma unroll
        for (int kk = 0; kk < 16; kk++) {
            float4 a4 = *(const float4*)&As[kk][ty << 2];
            float4 b4 = *(const float4*)&Bs[kk][tx << 2];
            float a[4] = {a4.x, a4.y, a4.z, a4.w};
            float b[4] = {b4.x, b4.y, b4.z, b4.w};
            #pragma unroll
            for (int i = 0; i < 4; i++)
                #pragma unroll
                for (int j = 0; j < 4; j++)
                    acc[i][j] = fmaf(a[i], b[j], acc[i][j]);
        }
        __syncthreads();
    }
    #pragma unroll
    for (int i = 0; i < 4; i++) {
        int m = m0 + (ty << 2) + i;
        #pragma unroll
        for (int j = 0; j < 4; j++) {
            int n = n0 + (tx << 2) + j;
            if (n < N) {
                float v = acc[i][j];
                if (bias) v += bias[n];
                if (MODE == 0) v = tanhf(v);
                else if (MODE == 1) v = resid[(size_t)m * N + n] + gelu_f(v);
                C[(size_t)m * N + n] = v;
                if (MODE == 1 && Cb) Cb[(size_t)m * N + n] = __float2bfloat16(v);
            }
        }
    }
}

// ---------------------------------------------------------------------------
// bf16 MFMA GEMM: A [M][K] bf16, Bt [NPAD][K] bf16, C [M][NSTRIDE] fp32
// ---------------------------------------------------------------------------
template<int K, int NSTRIDE>
__global__ __launch_bounds__(256) void mfma_gemm(
    const unsigned short* __restrict__ A, const unsigned short* __restrict__ Bt,
    float* __restrict__ C, int M)
{
    __shared__ __align__(16) unsigned short As[128][72];
    __shared__ __align__(16) unsigned short Bs[128][72];
    const int tid = threadIdx.x;
    const int m0 = blockIdx.x * 128;
    const int n0 = blockIdx.y * 128;
    const int wid = tid >> 6;
    const int lane = tid & 63;
    const int wm = (wid >> 1) << 6;
    const int wn = (wid & 1) << 6;

    f32x4 acc[4][4];
    #pragma unroll
    for (int i = 0; i < 4; i++)
        #pragma unroll
        for (int j = 0; j < 4; j++)
            acc[i][j] = (f32x4){0.f, 0.f, 0.f, 0.f};

    for (int k0 = 0; k0 < K; k0 += 64) {
        #pragma unroll
        for (int s = 0; s < 4; s++) {
            int g = tid + (s << 8);
            int row = g >> 3;
            int kc = (g & 7) << 3;
            int ra = m0 + row; if (ra > M - 1) ra = M - 1;
            *(uint4*)&As[row][kc] = *(const uint4*)&A[(size_t)ra * K + k0 + kc];
            *(uint4*)&Bs[row][kc] = *(const uint4*)&Bt[(size_t)(n0 + row) * K + k0 + kc];
        }
        __syncthreads();
        #pragma unroll
        for (int kk = 0; kk < 64; kk += 32) {
            bf16x8 av[4], bv[4];
            const int koff = kk + ((lane >> 4) << 3);
            #pragma unroll
            for (int mt = 0; mt < 4; mt++)
                av[mt] = *(const bf16x8*)&As[wm + (mt << 4) + (lane & 15)][koff];
            #pragma unroll
            for (int nt = 0; nt < 4; nt++)
                bv[nt] = *(const bf16x8*)&Bs[wn + (nt << 4) + (lane & 15)][koff];
            #pragma unroll
            for (int mt = 0; mt < 4; mt++)
                #pragma unroll
                for (int nt = 0; nt < 4; nt++)
                    acc[mt][nt] = __builtin_amdgcn_mfma_f32_16x16x32_bf16(
                        av[mt], bv[nt], acc[mt][nt], 0, 0, 0);
        }
        __syncthreads();
    }
    const int cr0 = m0 + wm + ((lane >> 4) << 2);
    const int cc0 = n0 + wn + (lane & 15);
    #pragma unroll
    for (int mt = 0; mt < 4; mt++)
        #pragma unroll
        for (int nt = 0; nt < 4; nt++)
            #pragma unroll
            for (int j = 0; j < 4; j++) {
                int r = cr0 + (mt << 4) + j;
                if (r < M) C[(size_t)r * NSTRIDE + cc0 + (nt << 4)] = acc[mt][nt][j];
            }
}

// same, but bf16 output (for IRh)
template<int K, int NSTRIDE>
__global__ __launch_bounds__(256) void mfma_gemm_bf16o(
    const unsigned short* __restrict__ A, const unsigned short* __restrict__ Bt,
    unsigned short* __restrict__ C, int M)
{
    __shared__ __align__(16) unsigned short As[128][72];
    __shared__ __align__(16) unsigned short Bs[128][72];
    const int tid = threadIdx.x;
    const int m0 = blockIdx.x * 128;
    const int n0 = blockIdx.y * 128;
    const int wid = tid >> 6;
    const int lane = tid & 63;
    const int wm = (wid >> 1) << 6;
    const int wn = (wid & 1) << 6;

    f32x4 acc[4][4];
    #pragma unroll
    for (int i = 0; i < 4; i++)
        #pragma unroll
        for (int j = 0; j < 4; j++)
            acc[i][j] = (f32x4){0.f, 0.f, 0.f, 0.f};

    for (int k0 = 0; k0 < K; k0 += 64) {
        #pragma unroll
        for (int s = 0; s < 4; s++) {
            int g = tid + (s << 8);
            int row = g >> 3;
            int kc = (g & 7) << 3;
            int ra = m0 + row; if (ra > M - 1) ra = M - 1;
            *(uint4*)&As[row][kc] = *(const uint4*)&A[(size_t)ra * K + k0 + kc];
            *(uint4*)&Bs[row][kc] = *(const uint4*)&Bt[(size_t)(n0 + row) * K + k0 + kc];
        }
        __syncthreads();
        #pragma unroll
        for (int kk = 0; kk < 64; kk += 32) {
            bf16x8 av[4], bv[4];
            const int koff = kk + ((lane >> 4) << 3);
            #pragma unroll
            for (int mt = 0; mt < 4; mt++)
                av[mt] = *(const bf16x8*)&As[wm + (mt << 4) + (lane & 15)][koff];
            #pragma unroll
            for (int nt = 0; nt < 4; nt++)
                bv[nt] = *(const bf16x8*)&Bs[wn + (nt << 4) + (lane & 15)][koff];
            #pragma unroll
            for (int mt = 0; mt < 4; mt++)
                #pragma unroll
                for (int nt = 0; nt < 4; nt++)
                    acc[mt][nt] = __builtin_amdgcn_mfma_f32_16x16x32_bf16(
                        av[mt], bv[nt], acc[mt][nt], 0, 0, 0);
        }
        __syncthreads();
    }
    const int cr0 = m0 + wm + ((lane >> 4) << 2);
    const int cc0 = n0 + wn + (lane & 15);
    #pragma unroll
    for (int mt = 0; mt < 4; mt++)
        #pragma unroll
        for (int nt = 0; nt < 4; nt++)
            #pragma unroll
            for (int j = 0; j < 4; j++) {
                int r = cr0 + (mt << 4) + j;
                if (r < M) C[(size_t)r * NSTRIDE + cc0 + (nt << 4)] = f2bf(acc[mt][nt][j]);
            }
}

// ---------------------------------------------------------------------------
__global__ __launch_bounds__(256) void convert_wout(
    const float* __restrict__ W, __hip_bfloat16* __restrict__ WTb)
{
    const int n = blockIdx.x;           // 0..639
    const int k = threadIdx.x;          // 0..255
    float v = (n < 593) ? W[(size_t)k * 593 + n] : 0.0f;
    WTb[(size_t)n * 256 + k] = __float2bfloat16(v);
}

// exact-fp32 f0 logit + fused precise f0 transform
__global__ __launch_bounds__(256) void f0_gemv(
    const float* __restrict__ h3, const float* __restrict__ Wout,
    const float* __restrict__ b_out, float* __restrict__ f0w, float* __restrict__ f0out)
{
    const int row = blockIdx.x * 4 + (threadIdx.x >> 6);
    const int lane = threadIdx.x & 63;
    const float* a = h3 + (size_t)row * 256;
    float s = 0.0f;
    #pragma unroll
    for (int q = 0; q < 4; q++) {
        int k = lane + (q << 6);
        s = fmaf(a[k], Wout[(size_t)k * 593], s);
    }
    #pragma unroll
    for (int off = 32; off; off >>= 1) s += __shfl_down(s, off, 64);
    if (lane == 0) {
        float lg = s + b_out[0];
        float sg = 1.0f / (1.0f + expf(-lg));
        float f0 = 80.0f * powf(12.5f, sg);
        if (f0 < 80.0f) f0 = 0.0f;
        f0w[row] = f0;
        f0out[row] = f0;
    }
}

// ---------------------------------------------------------------------------
// SP/NP from O[8000][640] cols 1..592 (+bias), fast-math exp_sigmoid
// ---------------------------------------------------------------------------
__global__ __launch_bounds__(256) void transform2_kernel(
    const float* __restrict__ O, const float* __restrict__ b_out,
    __hip_bfloat16* __restrict__ SPb, float* __restrict__ NP)
{
    int idx = blockIdx.x * 256 + threadIdx.x;
    if (idx >= 8000 * 592) return;
    int row = idx / 592;
    int c = idx - row * 592 + 1;
    float v = O[(size_t)row * 640 + c] + b_out[c];
    float s = 1.0f / (1.0f + __expf(-v));
    float p = 2.0f * __powf(s, 2.3025851f) + 1e-7f;
    if (c < 513) SPb[(size_t)row * 512 + (c - 1)] = __float2bfloat16(p);
    else         NP[(size_t)row * 80 + (c - 513)] = p;
}

// ---------------------------------------------------------------------------
// Parallel fp64 frame-level pitch scan
// ---------------------------------------------------------------------------
__device__ inline double shfl_up_d(double x, int off) {
    long long l = __double_as_longlong(x);
    int lo = (int)(l & 0xffffffffLL);
    int hi = (int)(l >> 32);
    lo = __shfl_up(lo, off, 64);
    hi = __shfl_up(hi, off, 64);
    return __longlong_as_double(((long long)hi << 32) | (unsigned int)lo);
}

__global__ __launch_bounds__(256) void scan_par_kernel(
    const float* __restrict__ f0w, const float* __restrict__ iphase,
    double* __restrict__ base, float* __restrict__ fph)
{
    __shared__ double wsum[4];
    const int b = blockIdx.x;
    const int tid = threadIdx.x;
    const int lane = tid & 63;
    const float* f0 = f0w + b * 1000;
    double s[4];
    double loc = 0.0;
    #pragma unroll
    for (int q = 0; q < 4; q++) {
        int f = tid * 4 + q;
        s[q] = loc;
        if (f < 1000) {
            double c  = (double)f0[f];
            double nx = (double)f0[(f < 999) ? (f + 1) : 999];
            loc += 120.5 * c + 119.5 * nx;
        }
    }
    double v = loc;
    #pragma unroll
    for (int off = 1; off < 64; off <<= 1) {
        double o = shfl_up_d(v, off);
        if (lane >= off) v += o;
    }
    if (lane == 63) wsum[tid >> 6] = v;
    __syncthreads();
    double wpre = 0.0;
    const int w = tid >> 6;
    for (int i = 0; i < w; i++) wpre += wsum[i];
    const double excl = wpre + v - loc;
    #pragma unroll
    for (int q = 0; q < 4; q++) {
        int f = tid * 4 + q;
        if (f < 1000) base[b * 1000 + f] = excl + s[q];
    }
    if (tid == 255) {
        double total = excl + loc;
        double u  = total * (1.0 / 24000.0);
        double ph = TWO_PI_D * u + (double)iphase[b];
        fph[b] = (float)fmod(ph, TWO_PI_D);
    }
}

// ---------------------------------------------------------------------------
// threefry2x32 (bit-exact jax.random.uniform, key (0,123), N=1,920,000)
// ---------------------------------------------------------------------------
__device__ inline unsigned rotl32(unsigned x, int d) { return (x << d) | (x >> (32 - d)); }

__device__ inline float threefry_noise(unsigned mi)
{
    const unsigned n2 = 960000u;
    unsigned i0 = (mi < n2) ? mi : (mi - n2);
    unsigned x0 = i0, x1 = i0 + n2;
    const unsigned ks0 = 0u, ks1 = 123u, ks2 = 0x1BD11BDAu ^ 0u ^ 123u;
    x0 += ks0; x1 += ks1;
#define TF_R(rot) { x0 += x1; x1 = rotl32(x1, rot); x1 ^= x0; }
    TF_R(13) TF_R(15) TF_R(26) TF_R(6)
    x0 += ks1; x1 += ks2 + 1u;
    TF_R(17) TF_R(29) TF_R(16) TF_R(24)
    x0 += ks2; x1 += ks0 + 2u;
    TF_R(13) TF_R(15) TF_R(26) TF_R(6)
    x0 += ks0; x1 += ks1 + 3u;
    TF_R(17) TF_R(29) TF_R(16) TF_R(24)
    x0 += ks1; x1 += ks2 + 4u;
    TF_R(13) TF_R(15) TF_R(26) TF_R(6)
    x0 += ks2; x1 += ks0 + 5u;
#undef TF_R
    unsigned bits = (mi < n2) ? x0 : x1;
    float uf = __uint_as_float((bits >> 9) | 0x3f800000u) - 1.0f;
    return uf * 2.0f - 1.0f;
}

// fp64 sawtooth sample
__device__ inline float saw_sample(const float* __restrict__ f0w,
                                   const double* __restrict__ base,
                                   const float* __restrict__ iphase,
                                   int b, int f, int r)
{
    double c  = (double)f0w[b * 1000 + f];
    double nx = (double)f0w[b * 1000 + ((f < 999) ? (f + 1) : 999)];
    double rr = (double)r;
    double Bc = rr * (rr + 1.0) * (1.0 / 480.0);
    double Ac = (rr + 1.0) - Bc;
    double cum = base[b * 1000 + f] + Ac * c + Bc * nx;
    double u  = cum * (1.0 / 24000.0) + (double)iphase[b] * (1.0 / TWO_PI_D);
    double fr = u - floor(u);
    return (float)(2.0 * fr - 1.0);
}

// ---------------------------------------------------------------------------
// Harmonic per-frame conv as MFMA: Y[jb+16m+n] = sum_k A[m][k] B[k][n]
//   A[m][k] = w[jb-240+k+16m]  (sliding window of IR, bf16, aligned b128)
//   B[k][n] = u[240+n-k]       (reversed saw; 4x b32 reads, parity twin)
// One wave per frame, 4 frames/block. 5 tiles of 256 outputs; 40 MFMA/frame.
// ---------------------------------------------------------------------------
__global__ __launch_bounds__(256) void frameconv_h_mfma(
    const float* __restrict__ f0w, const double* __restrict__ base,
    const float* __restrict__ iphase, const unsigned short* __restrict__ IRb,
    float* __restrict__ Y)
{
    __shared__ __align__(16) unsigned short we[4][1536];
    __shared__ __align__(16) unsigned short up0[4][288];
    __shared__ __align__(16) unsigned short up1[4][288];
    const int fq  = blockIdx.x;          // frame quad 0..249
    const int b   = blockIdx.y;
    const int tid = threadIdx.x;
    const int wv  = tid >> 6;
    const int lane = tid & 63;

    // stage w: we[fr][x] = IR[frame][x-240] for x in [240,1262), zeros elsewhere
    for (int i = tid; i < 4 * 1536; i += 256) {
        int fr = i / 1536, x = i - fr * 1536;
        unsigned short v = 0;
        if (x >= 240 && x < 1262)
            v = IRb[((size_t)b * 1000 + fq * 4 + fr) * 1024 + (x - 240)];
        we[fr][x] = v;
    }
    // reversed saw: up0[p] = bf16(u[256-p]) for p in [17,256], else 0; up1[p] = up0[p+1]
    for (int i = tid; i < 4 * 288; i += 256) {
        int fr = i / 288, p = i - fr * 288;
        float v = 0.0f;
        if (p >= 17 && p <= 256)
            v = saw_sample(f0w, base, iphase, b, fq * 4 + fr, 256 - p);
        unsigned short bv = f2bf(v);
        up0[fr][p] = bv;
        if (p >= 1) up1[fr][p - 1] = bv;
        if (p == 0) up1[fr][287] = 0;
    }
    __syncthreads();

    const unsigned short* wf = we[wv];
    const int n = lane & 15, hi = lane >> 4;

    // B-frags (u side), jb-independent: load once into registers
    const unsigned int* usrc = (const unsigned int*)((n & 1) ? up1[wv] : up0[wv]);
    bf16x8 bfrag[8];
    #pragma unroll
    for (int s = 0; s < 8; s++) {
        int e0 = 16 + 32 * s + 8 * hi - n - (n & 1);   // even element index
        int q = e0 >> 1;
        uint4 raw;
        raw.x = usrc[q]; raw.y = usrc[q + 1]; raw.z = usrc[q + 2]; raw.w = usrc[q + 3];
        bfrag[s] = __builtin_bit_cast(bf16x8, raw);
    }

    f32x4 acc[5];
    #pragma unroll
    for (int t = 0; t < 5; t++) acc[t] = (f32x4){0.f, 0.f, 0.f, 0.f};

    #pragma unroll
    for (int t = 0; t < 5; t++) {
        const int jb = t << 8;
        #pragma unroll
        for (int s = 0; s < 8; s++) {
            bf16x8 afrag = *(const bf16x8*)&wf[jb + 32 * s + 8 * hi + 16 * n];
            acc[t] = __builtin_amdgcn_mfma_f32_16x16x32_bf16(afrag, bfrag[s], acc[t], 0, 0, 0);
        }
    }

    float* yp = &Y[((size_t)b * 1000 + fq * 4 + wv) * 1280];
    #pragma unroll
    for (int t = 0; t < 5; t++)
        #pragma unroll
        for (int j = 0; j < 4; j++)
            yp[(t << 8) + 64 * hi + 16 * j + n] = acc[t][j];
}

// ---------------------------------------------------------------------------
// Per-frame conv, noise: iterate IR, window over audio (threefry fused).
// ---------------------------------------------------------------------------
#define CONV_GROUP(u4) \
    a0 = fmaf(u4.x, Whi.x, a0); a1 = fmaf(u4.x, Whi.y, a1); a2 = fmaf(u4.x, Whi.z, a2); a3 = fmaf(u4.x, Whi.w, a3); \
    a0 = fmaf(u4.y, Wlo.w, a0); a1 = fmaf(u4.y, Whi.x, a1); a2 = fmaf(u4.y, Whi.y, a2); a3 = fmaf(u4.y, Whi.z, a3); \
    a0 = fmaf(u4.z, Wlo.z, a0); a1 = fmaf(u4.z, Wlo.w, a1); a2 = fmaf(u4.z, Whi.x, a2); a3 = fmaf(u4.z, Whi.y, a3); \
    a0 = fmaf(u4.w, Wlo.y, a0); a1 = fmaf(u4.w, Wlo.z, a1); a2 = fmaf(u4.w, Wlo.w, a2); a3 = fmaf(u4.w, Whi.x, a3);

__global__ __launch_bounds__(128) void frameconv_n(
    const float* __restrict__ IR, float* __restrict__ Y)
{
    __shared__ __align__(16) float u_s[160];
    __shared__ __align__(16) float w_s[560];
    const int f = blockIdx.x;
    const int b = blockIdx.y;
    const int tid = threadIdx.x;
    const float* irow = IR + ((size_t)b * 1000 + f) * 158;
    for (int i = tid; i < 160; i += 128) {
        u_s[i] = (i < 158) ? irow[i] : 0.0f;
        w_s[i] = 0.0f;
        w_s[400 + i] = 0.0f;
    }
    for (int i = tid; i < 240; i += 128)
        w_s[160 + i] = threefry_noise((unsigned)(b * 240000 + f * 240 + i));
    __syncthreads();

    const int j0 = tid << 2;
    if (j0 >= 400) return;
    int base = 160 + j0 - 4;
    float4 Wlo = *(const float4*)&w_s[base];
    float4 Whi = *(const float4*)&w_s[base + 4];
    float a0 = 0.f, a1 = 0.f, a2 = 0.f, a3 = 0.f;
    #pragma unroll 4
    for (int t = 0; t < 156; t += 4) {
        float4 u4 = *(const float4*)&u_s[t];
        CONV_GROUP(u4)
        Whi = Wlo;
        base -= 4;
        Wlo = *(const float4*)&w_s[base];
    }
    {
        float4 u4 = *(const float4*)&u_s[156];
        CONV_GROUP(u4)
    }
    float4 r; r.x = a0; r.y = a1; r.z = a2; r.w = a3;
    *(float4*)&Y[((size_t)b * 1000 + f) * 400 + j0] = r;
}

// ---------------------------------------------------------------------------
// Overlap-add + 'same' slice + outputs
// ---------------------------------------------------------------------------
__global__ __launch_bounds__(256) void combine_kernel(
    const float* __restrict__ Yh, const float* __restrict__ Yn,
    float* __restrict__ sig, float* __restrict__ harm, float* __restrict__ noise)
{
    int t = blockIdx.x * 256 + threadIdx.x;
    if (t >= 240000) return;
    const int b = blockIdx.y;
    float hsum = 0.0f;
    const int fhi = (t + 509) / 240;
    #pragma unroll
    for (int q = 0; q < 6; q++) {
        int f = fhi - q;
        int j = t + 509 - 240 * f;
        if (f >= 0 && f < 1000 && j < 1261)
            hsum += Yh[((size_t)b * 1000 + f) * 1280 + j];
    }
    float nsum = 0.0f;
    const int ghi = (t + 77) / 240;
    #pragma unroll
    for (int q = 0; q < 2; q++) {
        int f = ghi - q;
        int j = t + 77 - 240 * f;
        if (f >= 0 && f < 1000 && j < 397)
            nsum += Yn[((size_t)b * 1000 + f) * 400 + j];
    }
    size_t o = (size_t)b * 240000 + t;
    harm[o]  = hsum;
    noise[o] = nsum;
    sig[o]   = hsum + nsum;
}

// ---------------------------------------------------------------------------
extern "C" void kernel_launch(void* const* d_in, const int* in_sizes, int n_in,
                              void* d_out, int out_size, void* d_ws, size_t ws_size,
                              hipStream_t stream)
{
    (void)in_sizes; (void)n_in; (void)out_size; (void)ws_size;
    const float* mel    = (const float*)d_in[0];
    const float* iphase = (const float*)d_in[1];
    const float* W_in   = (const float*)d_in[2];
    const float* b_in   = (const float*)d_in[3];
    const float* W1     = (const float*)d_in[4];
    const float* b1     = (const float*)d_in[5];
    const float* W2     = (const float*)d_in[6];
    const float* b2     = (const float*)d_in[7];
    const float* W_out  = (const float*)d_in[8];
    const float* b_out  = (const float*)d_in[9];
    float* ws = (float*)d_ws;

    // workspace layout (float offsets)
    __hip_bfloat16* Chb = (__hip_bfloat16*)(ws + 0);        // [1024][512] bf16
    float*  Cn      = ws + 262144;                          // 12,640
    __hip_bfloat16* SPb = (__hip_bfloat16*)(ws + 274784);   // [8000][512] bf16
    float*  NP      = ws + 2322784;                         // 640,000
    float*  f0w     = ws + 3440640;                         // 8,000
    double* base    = (double*)(ws + 3448640);              // 8,000 dbl
    float*  BA      = ws + 7312640;                         // 2,048,000 (h1,h3)
    float*  BB      = ws + 9360640;                         // 2,048,000 (h2)
    __hip_bfloat16* BAb = (__hip_bfloat16*)(ws + 11408640); // [8000][256] bf16
    __hip_bfloat16* WTb = (__hip_bfloat16*)(ws + 12432640); // [640][256] bf16
    float*  O       = ws + 12514560;                        // [8000][640]
    unsigned short* IRhb = (unsigned short*)(ws + 7312640); // [8000][1024] bf16 (aliases BA+BB, dead then)
    float*  IRn     = ws + 17634560;                        // 1,264,000
    float*  YhF     = ws + 18898560;                        // [8][1000][1280]
    float*  YnF     = ws + 29138560;                        // [8][1000][400]

    float* out       = (float*)d_out;
    float* sig_out   = out;
    float* f0_out    = out + 1920000;
    float* fph_out   = out + 1928000;
    float* harm_out  = out + 1928008;
    float* noise_out = out + 3848008;

    basis_h_bf16_t<<<1024, 256, 0, stream>>>(Chb);
    basis_kernel<80, 158><<<80, 256, 0, stream>>>(Cn);

    // MLP hidden layers in fp32 (f0-precision path); 3rd layer mirrors bf16
    gemm_kernel<0><<<dim3(125, 4), 256, 0, stream>>>(mel, W_in, b_in, nullptr, BA, nullptr, 8000, 256, 80);
    gemm_kernel<1><<<dim3(125, 4), 256, 0, stream>>>(BA,  W1,   b1,   BA,      BB, nullptr, 8000, 256, 256);
    gemm_kernel<1><<<dim3(125, 4), 256, 0, stream>>>(BB,  W2,   b2,   BB,      BA, BAb,     8000, 256, 256);

    // W_out: bf16 MFMA -> O, then parallel transform2; exact fp32 f0 GEMV
    convert_wout<<<640, 256, 0, stream>>>(W_out, WTb);
    mfma_gemm<256, 640><<<dim3(63, 5), 256, 0, stream>>>(
        (const unsigned short*)BAb, (const unsigned short*)WTb, O, 8000);
    f0_gemv<<<2000, 256, 0, stream>>>(BA, W_out, b_out, f0w, f0_out);

    transform2_kernel<<<(8000 * 592 + 255) / 256, 256, 0, stream>>>(O, b_out, SPb, NP);
    scan_par_kernel<<<8, 256, 0, stream>>>(f0w, iphase, base, fph_out);

    // IR_h = SPb @ Chb^T  (bf16 MFMA, BF16 out, stride 1024)
    mfma_gemm_bf16o<512, 1024><<<dim3(63, 8), 256, 0, stream>>>(
        (const unsigned short*)SPb, (const unsigned short*)Chb, IRhb, 8000);
    // IR_n fp32
    gemm_kernel<2><<<dim3(125, 3), 256, 0, stream>>>(NP, Cn, nullptr, nullptr, IRn, nullptr, 8000, 158, 80);

    // per-frame conv (saw / noise generated in-kernel) + overlap-add
    frameconv_h_mfma<<<dim3(250, 8), 256, 0, stream>>>(f0w, base, iphase, IRhb, YhF);
    frameconv_n<<<dim3(1000, 8), 128, 0, stream>>>(IRn, YnF);
    combine_kernel<<<dim3(938, 8), 256, 0, stream>>>(YhF, YnF, sig_out, harm_out, noise_out);
}

// Round 16
// 225.369 us; speedup vs baseline: 1.4399x; 1.1278x over previous
//
#include <hip/hip_runtime.h>
#include <hip/hip_bf16.h>
#include <math.h>

#define TWO_PI_D 6.283185307179586476925286766559
#define TWO_PI_F 6.28318530718f

typedef short bf16x8 __attribute__((ext_vector_type(8)));
typedef float f32x4 __attribute__((ext_vector_type(4)));

static __device__ inline unsigned short f2bf(float v) {
    union { __hip_bfloat16 h; unsigned short u; } cv;
    cv.h = __float2bfloat16(v);
    return cv.u;
}

// ---------------------------------------------------------------------------
// Harmonic basis, bf16, TRANSPOSED + padded: Ct[n][k], n<1024 (1022 valid), k<512
// ---------------------------------------------------------------------------
__global__ __launch_bounds__(256) void basis_h_bf16_t(__hip_bfloat16* __restrict__ Ct)
{
    const int n = blockIdx.x;            // 0..1023
    for (int k = threadIdx.x; k < 512; k += 256) {
        float v = 0.0f;
        if (n < 1022) {
            float hann = 0.5f * (1.0f - cosf(TWO_PI_F * (float)n / 1022.0f));
            float w = hann * (1.0f / 1022.0f);
            if (k == 0) v = w;
            else if (k == 511) v = (n & 1) ? w : -w;
            else {
                int m = (k * n) % 1022;
                float c = cosf(TWO_PI_F * (float)m / 1022.0f);
                v = 2.0f * w * ((k & 1) ? -c : c);
            }
        }
        Ct[(size_t)n * 512 + k] = __float2bfloat16(v);
    }
}

// noise basis, fp32: C[k][n], k<80, n<158
template<int NMAG, int NIR>
__global__ __launch_bounds__(256) void basis_kernel(float* __restrict__ C)
{
    const int k = blockIdx.x;
    for (int n = threadIdx.x; n < NIR; n += blockDim.x) {
        double hann = 0.5 * (1.0 - cos(TWO_PI_D * (double)n / (double)NIR));
        double w = hann / (double)NIR;
        double v;
        if (k == 0) v = w;
        else if (k == NMAG - 1) v = (n & 1) ? w : -w;
        else {
            long m = ((long)k * (long)n) % NIR;
            double c = cos(TWO_PI_D * (double)m / (double)NIR);
            v = 2.0 * w * ((k & 1) ? -c : c);
        }
        C[(size_t)k * NIR + n] = (float)v;
    }
}

// ---------------------------------------------------------------------------
// fp32 tiled GEMM 64x64x16 — precision path (MLP hidden layers + noise IR).
// ---------------------------------------------------------------------------
__device__ inline float gelu_f(float x) {
    float x3 = x * x * x;
    float t = tanhf(0.7978845608028654f * (x + 0.044715f * x3));
    return 0.5f * x * (1.0f + t);
}

template<int MODE>
__global__ __launch_bounds__(256) void gemm_kernel(
    const float* __restrict__ A, const float* __restrict__ Bm,
    const float* __restrict__ bias, const float* __restrict__ resid,
    float* __restrict__ C, __hip_bfloat16* __restrict__ Cb, int M, int N, int K)
{
    __shared__ float As[16][68];
    __shared__ float Bs[16][68];
    const int tid = threadIdx.x;
    const int tx = tid & 15, ty = tid >> 4;
    const int m0 = blockIdx.x * 64;
    const int n0 = blockIdx.y * 64;
    const int ar  = tid >> 2;
    const int ac4 = (tid & 3) << 2;
    const int bk  = tid >> 4;
    const int bn4 = (tid & 15) << 2;
    float acc[4][4] = {};
    for (int k0 = 0; k0 < K; k0 += 16) {
        float4 av = *(const float4*)(A + (size_t)(m0 + ar) * K + k0 + ac4);
        As[ac4 + 0][ar] = av.x;
        As[ac4 + 1][ar] = av.y;
        As[ac4 + 2][ar] = av.z;
        As[ac4 + 3][ar] = av.w;
        const float* Bp = Bm + (size_t)(k0 + bk) * N + n0 + bn4;
        #pragma unroll
        for (int i = 0; i < 4; i++)
            Bs[bk][bn4 + i] = (n0 + bn4 + i < N) ? Bp[i] : 0.0f;
        __syncthreads();
        #pragma unroll
        for (int kk = 0; kk < 16; kk++) {
            float4 a4 = *(const float4*)&As[kk][ty << 2];
            float4 b4 = *(const float4*)&Bs[kk][tx << 2];
            float a[4] = {a4.x, a4.y, a4.z, a4.w};
            float b[4] = {b4.x, b4.y, b4.z, b4.w};
            #pragma unroll
            for (int i = 0; i < 4; i++)
                #pragma unroll
                for (int j = 0; j < 4; j++)
                    acc[i][j] = fmaf(a[i], b[j], acc[i][j]);
        }
        __syncthreads();
    }
    #pragma unroll
    for (int i = 0; i < 4; i++) {
        int m = m0 + (ty << 2) + i;
        #pragma unroll
        for (int j = 0; j < 4; j++) {
            int n = n0 + (tx << 2) + j;
            if (n < N) {
                float v = acc[i][j];
                if (bias) v += bias[n];
                if (MODE == 0) v = tanhf(v);
                else if (MODE == 1) v = resid[(size_t)m * N + n] + gelu_f(v);
                C[(size_t)m * N + n] = v;
                if (MODE == 1 && Cb) Cb[(size_t)m * N + n] = __float2bfloat16(v);
            }
        }
    }
}

// ---------------------------------------------------------------------------
// bf16 MFMA GEMM: A [M][K] bf16, Bt [NPAD][K] bf16, C [M][NSTRIDE] fp32
// ---------------------------------------------------------------------------
template<int K, int NSTRIDE>
__global__ __launch_bounds__(256) void mfma_gemm(
    const unsigned short* __restrict__ A, const unsigned short* __restrict__ Bt,
    float* __restrict__ C, int M)
{
    __shared__ __align__(16) unsigned short As[128][72];
    __shared__ __align__(16) unsigned short Bs[128][72];
    const int tid = threadIdx.x;
    const int m0 = blockIdx.x * 128;
    const int n0 = blockIdx.y * 128;
    const int wid = tid >> 6;
    const int lane = tid & 63;
    const int wm = (wid >> 1) << 6;
    const int wn = (wid & 1) << 6;

    f32x4 acc[4][4];
    #pragma unroll
    for (int i = 0; i < 4; i++)
        #pragma unroll
        for (int j = 0; j < 4; j++)
            acc[i][j] = (f32x4){0.f, 0.f, 0.f, 0.f};

    for (int k0 = 0; k0 < K; k0 += 64) {
        #pragma unroll
        for (int s = 0; s < 4; s++) {
            int g = tid + (s << 8);
            int row = g >> 3;
            int kc = (g & 7) << 3;
            int ra = m0 + row; if (ra > M - 1) ra = M - 1;
            *(uint4*)&As[row][kc] = *(const uint4*)&A[(size_t)ra * K + k0 + kc];
            *(uint4*)&Bs[row][kc] = *(const uint4*)&Bt[(size_t)(n0 + row) * K + k0 + kc];
        }
        __syncthreads();
        #pragma unroll
        for (int kk = 0; kk < 64; kk += 32) {
            bf16x8 av[4], bv[4];
            const int koff = kk + ((lane >> 4) << 3);
            #pragma unroll
            for (int mt = 0; mt < 4; mt++)
                av[mt] = *(const bf16x8*)&As[wm + (mt << 4) + (lane & 15)][koff];
            #pragma unroll
            for (int nt = 0; nt < 4; nt++)
                bv[nt] = *(const bf16x8*)&Bs[wn + (nt << 4) + (lane & 15)][koff];
            #pragma unroll
            for (int mt = 0; mt < 4; mt++)
                #pragma unroll
                for (int nt = 0; nt < 4; nt++)
                    acc[mt][nt] = __builtin_amdgcn_mfma_f32_16x16x32_bf16(
                        av[mt], bv[nt], acc[mt][nt], 0, 0, 0);
        }
        __syncthreads();
    }
    const int cr0 = m0 + wm + ((lane >> 4) << 2);
    const int cc0 = n0 + wn + (lane & 15);
    #pragma unroll
    for (int mt = 0; mt < 4; mt++)
        #pragma unroll
        for (int nt = 0; nt < 4; nt++)
            #pragma unroll
            for (int j = 0; j < 4; j++) {
                int r = cr0 + (mt << 4) + j;
                if (r < M) C[(size_t)r * NSTRIDE + cc0 + (nt << 4)] = acc[mt][nt][j];
            }
}

// same, but bf16 output (for IRh)
template<int K, int NSTRIDE>
__global__ __launch_bounds__(256) void mfma_gemm_bf16o(
    const unsigned short* __restrict__ A, const unsigned short* __restrict__ Bt,
    unsigned short* __restrict__ C, int M)
{
    __shared__ __align__(16) unsigned short As[128][72];
    __shared__ __align__(16) unsigned short Bs[128][72];
    const int tid = threadIdx.x;
    const int m0 = blockIdx.x * 128;
    const int n0 = blockIdx.y * 128;
    const int wid = tid >> 6;
    const int lane = tid & 63;
    const int wm = (wid >> 1) << 6;
    const int wn = (wid & 1) << 6;

    f32x4 acc[4][4];
    #pragma unroll
    for (int i = 0; i < 4; i++)
        #pragma unroll
        for (int j = 0; j < 4; j++)
            acc[i][j] = (f32x4){0.f, 0.f, 0.f, 0.f};

    for (int k0 = 0; k0 < K; k0 += 64) {
        #pragma unroll
        for (int s = 0; s < 4; s++) {
            int g = tid + (s << 8);
            int row = g >> 3;
            int kc = (g & 7) << 3;
            int ra = m0 + row; if (ra > M - 1) ra = M - 1;
            *(uint4*)&As[row][kc] = *(const uint4*)&A[(size_t)ra * K + k0 + kc];
            *(uint4*)&Bs[row][kc] = *(const uint4*)&Bt[(size_t)(n0 + row) * K + k0 + kc];
        }
        __syncthreads();
        #pragma unroll
        for (int kk = 0; kk < 64; kk += 32) {
            bf16x8 av[4], bv[4];
            const int koff = kk + ((lane >> 4) << 3);
            #pragma unroll
            for (int mt = 0; mt < 4; mt++)
                av[mt] = *(const bf16x8*)&As[wm + (mt << 4) + (lane & 15)][koff];
            #pragma unroll
            for (int nt = 0; nt < 4; nt++)
                bv[nt] = *(const bf16x8*)&Bs[wn + (nt << 4) + (lane & 15)][koff];
            #pragma unroll
            for (int mt = 0; mt < 4; mt++)
                #pragma unroll
                for (int nt = 0; nt < 4; nt++)
                    acc[mt][nt] = __builtin_amdgcn_mfma_f32_16x16x32_bf16(
                        av[mt], bv[nt], acc[mt][nt], 0, 0, 0);
        }
        __syncthreads();
    }
    const int cr0 = m0 + wm + ((lane >> 4) << 2);
    const int cc0 = n0 + wn + (lane & 15);
    #pragma unroll
    for (int mt = 0; mt < 4; mt++)
        #pragma unroll
        for (int nt = 0; nt < 4; nt++)
            #pragma unroll
            for (int j = 0; j < 4; j++) {
                int r = cr0 + (mt << 4) + j;
                if (r < M) C[(size_t)r * NSTRIDE + cc0 + (nt << 4)] = f2bf(acc[mt][nt][j]);
            }
}

// ---------------------------------------------------------------------------
__global__ __launch_bounds__(256) void convert_wout(
    const float* __restrict__ W, __hip_bfloat16* __restrict__ WTb)
{
    const int n = blockIdx.x;           // 0..639
    const int k = threadIdx.x;          // 0..255
    float v = (n < 593) ? W[(size_t)k * 593 + n] : 0.0f;
    WTb[(size_t)n * 256 + k] = __float2bfloat16(v);
}

// exact-fp32 f0 logit + fused precise f0 transform
__global__ __launch_bounds__(256) void f0_gemv(
    const float* __restrict__ h3, const float* __restrict__ Wout,
    const float* __restrict__ b_out, float* __restrict__ f0w, float* __restrict__ f0out)
{
    const int row = blockIdx.x * 4 + (threadIdx.x >> 6);
    const int lane = threadIdx.x & 63;
    const float* a = h3 + (size_t)row * 256;
    float s = 0.0f;
    #pragma unroll
    for (int q = 0; q < 4; q++) {
        int k = lane + (q << 6);
        s = fmaf(a[k], Wout[(size_t)k * 593], s);
    }
    #pragma unroll
    for (int off = 32; off; off >>= 1) s += __shfl_down(s, off, 64);
    if (lane == 0) {
        float lg = s + b_out[0];
        float sg = 1.0f / (1.0f + expf(-lg));
        float f0 = 80.0f * powf(12.5f, sg);
        if (f0 < 80.0f) f0 = 0.0f;
        f0w[row] = f0;
        f0out[row] = f0;
    }
}

// ---------------------------------------------------------------------------
// SP/NP from O[8000][640] cols 1..592 (+bias), fast-math exp_sigmoid
// ---------------------------------------------------------------------------
__global__ __launch_bounds__(256) void transform2_kernel(
    const float* __restrict__ O, const float* __restrict__ b_out,
    __hip_bfloat16* __restrict__ SPb, float* __restrict__ NP)
{
    int idx = blockIdx.x * 256 + threadIdx.x;
    if (idx >= 8000 * 592) return;
    int row = idx / 592;
    int c = idx - row * 592 + 1;
    float v = O[(size_t)row * 640 + c] + b_out[c];
    float s = 1.0f / (1.0f + __expf(-v));
    float p = 2.0f * __powf(s, 2.3025851f) + 1e-7f;
    if (c < 513) SPb[(size_t)row * 512 + (c - 1)] = __float2bfloat16(p);
    else         NP[(size_t)row * 80 + (c - 513)] = p;
}

// ---------------------------------------------------------------------------
// Parallel fp64 frame-level pitch scan
// ---------------------------------------------------------------------------
__device__ inline double shfl_up_d(double x, int off) {
    long long l = __double_as_longlong(x);
    int lo = (int)(l & 0xffffffffLL);
    int hi = (int)(l >> 32);
    lo = __shfl_up(lo, off, 64);
    hi = __shfl_up(hi, off, 64);
    return __longlong_as_double(((long long)hi << 32) | (unsigned int)lo);
}

__global__ __launch_bounds__(256) void scan_par_kernel(
    const float* __restrict__ f0w, const float* __restrict__ iphase,
    double* __restrict__ base, float* __restrict__ fph)
{
    __shared__ double wsum[4];
    const int b = blockIdx.x;
    const int tid = threadIdx.x;
    const int lane = tid & 63;
    const float* f0 = f0w + b * 1000;
    double s[4];
    double loc = 0.0;
    #pragma unroll
    for (int q = 0; q < 4; q++) {
        int f = tid * 4 + q;
        s[q] = loc;
        if (f < 1000) {
            double c  = (double)f0[f];
            double nx = (double)f0[(f < 999) ? (f + 1) : 999];
            loc += 120.5 * c + 119.5 * nx;
        }
    }
    double v = loc;
    #pragma unroll
    for (int off = 1; off < 64; off <<= 1) {
        double o = shfl_up_d(v, off);
        if (lane >= off) v += o;
    }
    if (lane == 63) wsum[tid >> 6] = v;
    __syncthreads();
    double wpre = 0.0;
    const int w = tid >> 6;
    for (int i = 0; i < w; i++) wpre += wsum[i];
    const double excl = wpre + v - loc;
    #pragma unroll
    for (int q = 0; q < 4; q++) {
        int f = tid * 4 + q;
        if (f < 1000) base[b * 1000 + f] = excl + s[q];
    }
    if (tid == 255) {
        double total = excl + loc;
        double u  = total * (1.0 / 24000.0);
        double ph = TWO_PI_D * u + (double)iphase[b];
        fph[b] = (float)fmod(ph, TWO_PI_D);
    }
}

// ---------------------------------------------------------------------------
// threefry2x32 (bit-exact jax.random.uniform, key (0,123), N=1,920,000)
// ---------------------------------------------------------------------------
__device__ inline unsigned rotl32(unsigned x, int d) { return (x << d) | (x >> (32 - d)); }

__device__ inline float threefry_noise(unsigned mi)
{
    const unsigned n2 = 960000u;
    unsigned i0 = (mi < n2) ? mi : (mi - n2);
    unsigned x0 = i0, x1 = i0 + n2;
    const unsigned ks0 = 0u, ks1 = 123u, ks2 = 0x1BD11BDAu ^ 0u ^ 123u;
    x0 += ks0; x1 += ks1;
#define TF_R(rot) { x0 += x1; x1 = rotl32(x1, rot); x1 ^= x0; }
    TF_R(13) TF_R(15) TF_R(26) TF_R(6)
    x0 += ks1; x1 += ks2 + 1u;
    TF_R(17) TF_R(29) TF_R(16) TF_R(24)
    x0 += ks2; x1 += ks0 + 2u;
    TF_R(13) TF_R(15) TF_R(26) TF_R(6)
    x0 += ks0; x1 += ks1 + 3u;
    TF_R(17) TF_R(29) TF_R(16) TF_R(24)
    x0 += ks1; x1 += ks2 + 4u;
    TF_R(13) TF_R(15) TF_R(26) TF_R(6)
    x0 += ks2; x1 += ks0 + 5u;
#undef TF_R
    unsigned bits = (mi < n2) ? x0 : x1;
    float uf = __uint_as_float((bits >> 9) | 0x3f800000u) - 1.0f;
    return uf * 2.0f - 1.0f;
}

// fp64 sawtooth sample
__device__ inline float saw_sample(const float* __restrict__ f0w,
                                   const double* __restrict__ base,
                                   const float* __restrict__ iphase,
                                   int b, int f, int r)
{
    double c  = (double)f0w[b * 1000 + f];
    double nx = (double)f0w[b * 1000 + ((f < 999) ? (f + 1) : 999)];
    double rr = (double)r;
    double Bc = rr * (rr + 1.0) * (1.0 / 480.0);
    double Ac = (rr + 1.0) - Bc;
    double cum = base[b * 1000 + f] + Ac * c + Bc * nx;
    double u  = cum * (1.0 / 24000.0) + (double)iphase[b] * (1.0 / TWO_PI_D);
    double fr = u - floor(u);
    return (float)(2.0 * fr - 1.0);
}

// ---------------------------------------------------------------------------
// Harmonic per-frame conv as MFMA (R13-proven): Y[jb+16m+n] = sum_k A B
// ---------------------------------------------------------------------------
__global__ __launch_bounds__(256) void frameconv_h_mfma(
    const float* __restrict__ f0w, const double* __restrict__ base,
    const float* __restrict__ iphase, const unsigned short* __restrict__ IRb,
    float* __restrict__ Y)
{
    __shared__ __align__(16) unsigned short we[4][1536];
    __shared__ __align__(16) unsigned short up0[4][288];
    __shared__ __align__(16) unsigned short up1[4][288];
    const int fq  = blockIdx.x;          // frame quad 0..249
    const int b   = blockIdx.y;
    const int tid = threadIdx.x;
    const int wv  = tid >> 6;
    const int lane = tid & 63;

    for (int i = tid; i < 4 * 1536; i += 256) {
        int fr = i / 1536, x = i - fr * 1536;
        unsigned short v = 0;
        if (x >= 240 && x < 1262)
            v = IRb[((size_t)b * 1000 + fq * 4 + fr) * 1024 + (x - 240)];
        we[fr][x] = v;
    }
    for (int i = tid; i < 4 * 288; i += 256) {
        int fr = i / 288, p = i - fr * 288;
        float v = 0.0f;
        if (p >= 17 && p <= 256)
            v = saw_sample(f0w, base, iphase, b, fq * 4 + fr, 256 - p);
        unsigned short bv = f2bf(v);
        up0[fr][p] = bv;
        if (p >= 1) up1[fr][p - 1] = bv;
        if (p == 0) up1[fr][287] = 0;
    }
    __syncthreads();

    const unsigned short* wf = we[wv];
    const int n = lane & 15, hi = lane >> 4;

    const unsigned int* usrc = (const unsigned int*)((n & 1) ? up1[wv] : up0[wv]);
    bf16x8 bfrag[8];
    #pragma unroll
    for (int s = 0; s < 8; s++) {
        int e0 = 16 + 32 * s + 8 * hi - n - (n & 1);
        int q = e0 >> 1;
        uint4 raw;
        raw.x = usrc[q]; raw.y = usrc[q + 1]; raw.z = usrc[q + 2]; raw.w = usrc[q + 3];
        bfrag[s] = __builtin_bit_cast(bf16x8, raw);
    }

    f32x4 acc[5];
    #pragma unroll
    for (int t = 0; t < 5; t++) acc[t] = (f32x4){0.f, 0.f, 0.f, 0.f};

    #pragma unroll
    for (int t = 0; t < 5; t++) {
        const int jb = t << 8;
        #pragma unroll
        for (int s = 0; s < 8; s++) {
            bf16x8 afrag = *(const bf16x8*)&wf[jb + 32 * s + 8 * hi + 16 * n];
            acc[t] = __builtin_amdgcn_mfma_f32_16x16x32_bf16(afrag, bfrag[s], acc[t], 0, 0, 0);
        }
    }

    float* yp = &Y[((size_t)b * 1000 + fq * 4 + wv) * 1280];
    #pragma unroll
    for (int t = 0; t < 5; t++)
        #pragma unroll
        for (int j = 0; j < 4; j++)
            yp[(t << 8) + 64 * hi + 16 * j + n] = acc[t][j];
}

// ---------------------------------------------------------------------------
// Noise per-frame conv as MFMA (isomorphic, K=192, taps 158, outputs 397):
//   Y[jb+16m+n] = sum_k A[m][k] B[k][n]
//   A[m][k] = nza[jb+16m+k], nza[x] = nz[x-160] (x in [160,400)), else 0
//   B[k][n] = ir[n+160-k] = irrev[16+k-n], irrev[p] = ir[176-p] (p in [19,176])
// One wave per frame, 4 frames/block; 2 tiles x 6 MFMA = 12 MFMA/frame.
// ---------------------------------------------------------------------------
__global__ __launch_bounds__(256) void frameconv_n_mfma(
    const float* __restrict__ IRn, float* __restrict__ Y)
{
    __shared__ __align__(16) unsigned short nza[4][704];
    __shared__ __align__(16) unsigned short ip0[4][224];
    __shared__ __align__(16) unsigned short ip1[4][224];
    const int fq  = blockIdx.x;          // frame quad 0..249
    const int b   = blockIdx.y;
    const int tid = threadIdx.x;
    const int wv  = tid >> 6;
    const int lane = tid & 63;

    for (int i = tid; i < 4 * 704; i += 256) {
        int fr = i / 704, x = i - fr * 704;
        unsigned short v = 0;
        if (x >= 160 && x < 400)
            v = f2bf(threefry_noise((unsigned)(b * 240000 + (fq * 4 + fr) * 240 + (x - 160))));
        nza[fr][x] = v;
    }
    for (int i = tid; i < 4 * 224; i += 256) {
        int fr = i / 224, p = i - fr * 224;
        float v = 0.0f;
        if (p >= 19 && p <= 176)
            v = IRn[((size_t)b * 1000 + fq * 4 + fr) * 158 + (176 - p)];
        unsigned short bv = f2bf(v);
        ip0[fr][p] = bv;
        if (p >= 1) ip1[fr][p - 1] = bv;
        if (p == 0) ip1[fr][223] = 0;
    }
    __syncthreads();

    const unsigned short* af = nza[wv];
    const int n = lane & 15, hi = lane >> 4;

    const unsigned int* usrc = (const unsigned int*)((n & 1) ? ip1[wv] : ip0[wv]);
    bf16x8 bfrag[6];
    #pragma unroll
    for (int s = 0; s < 6; s++) {
        int e0 = 16 + 32 * s + 8 * hi - n - (n & 1);
        int q = e0 >> 1;
        uint4 raw;
        raw.x = usrc[q]; raw.y = usrc[q + 1]; raw.z = usrc[q + 2]; raw.w = usrc[q + 3];
        bfrag[s] = __builtin_bit_cast(bf16x8, raw);
    }

    f32x4 acc[2];
    acc[0] = (f32x4){0.f, 0.f, 0.f, 0.f};
    acc[1] = (f32x4){0.f, 0.f, 0.f, 0.f};

    #pragma unroll
    for (int t = 0; t < 2; t++) {
        const int jb = t << 8;
        #pragma unroll
        for (int s = 0; s < 6; s++) {
            bf16x8 afrag = *(const bf16x8*)&af[jb + 32 * s + 8 * hi + 16 * n];
            acc[t] = __builtin_amdgcn_mfma_f32_16x16x32_bf16(afrag, bfrag[s], acc[t], 0, 0, 0);
        }
    }

    float* yp = &Y[((size_t)b * 1000 + fq * 4 + wv) * 400];
    #pragma unroll
    for (int t = 0; t < 2; t++)
        #pragma unroll
        for (int j = 0; j < 4; j++) {
            int idx = (t << 8) + 64 * hi + 16 * j + n;
            if (idx < 400) yp[idx] = acc[t][j];
        }
}

// ---------------------------------------------------------------------------
// Overlap-add + 'same' slice + outputs
// ---------------------------------------------------------------------------
__global__ __launch_bounds__(256) void combine_kernel(
    const float* __restrict__ Yh, const float* __restrict__ Yn,
    float* __restrict__ sig, float* __restrict__ harm, float* __restrict__ noise)
{
    int t = blockIdx.x * 256 + threadIdx.x;
    if (t >= 240000) return;
    const int b = blockIdx.y;
    float hsum = 0.0f;
    const int fhi = (t + 509) / 240;
    #pragma unroll
    for (int q = 0; q < 6; q++) {
        int f = fhi - q;
        int j = t + 509 - 240 * f;
        if (f >= 0 && f < 1000 && j < 1261)
            hsum += Yh[((size_t)b * 1000 + f) * 1280 + j];
    }
    float nsum = 0.0f;
    const int ghi = (t + 77) / 240;
    #pragma unroll
    for (int q = 0; q < 2; q++) {
        int f = ghi - q;
        int j = t + 77 - 240 * f;
        if (f >= 0 && f < 1000 && j < 397)
            nsum += Yn[((size_t)b * 1000 + f) * 400 + j];
    }
    size_t o = (size_t)b * 240000 + t;
    harm[o]  = hsum;
    noise[o] = nsum;
    sig[o]   = hsum + nsum;
}

// ---------------------------------------------------------------------------
extern "C" void kernel_launch(void* const* d_in, const int* in_sizes, int n_in,
                              void* d_out, int out_size, void* d_ws, size_t ws_size,
                              hipStream_t stream)
{
    (void)in_sizes; (void)n_in; (void)out_size; (void)ws_size;
    const float* mel    = (const float*)d_in[0];
    const float* iphase = (const float*)d_in[1];
    const float* W_in   = (const float*)d_in[2];
    const float* b_in   = (const float*)d_in[3];
    const float* W1     = (const float*)d_in[4];
    const float* b1     = (const float*)d_in[5];
    const float* W2     = (const float*)d_in[6];
    const float* b2     = (const float*)d_in[7];
    const float* W_out  = (const float*)d_in[8];
    const float* b_out  = (const float*)d_in[9];
    float* ws = (float*)d_ws;

    // workspace layout (float offsets)
    __hip_bfloat16* Chb = (__hip_bfloat16*)(ws + 0);        // [1024][512] bf16
    float*  Cn      = ws + 262144;                          // 12,640
    __hip_bfloat16* SPb = (__hip_bfloat16*)(ws + 274784);   // [8000][512] bf16
    float*  NP      = ws + 2322784;                         // 640,000
    float*  f0w     = ws + 3440640;                         // 8,000
    double* base    = (double*)(ws + 3448640);              // 8,000 dbl
    float*  BA      = ws + 7312640;                         // 2,048,000 (h1,h3)
    float*  BB      = ws + 9360640;                         // 2,048,000 (h2)
    __hip_bfloat16* BAb = (__hip_bfloat16*)(ws + 11408640); // [8000][256] bf16
    __hip_bfloat16* WTb = (__hip_bfloat16*)(ws + 12432640); // [640][256] bf16
    float*  O       = ws + 12514560;                        // [8000][640]
    unsigned short* IRhb = (unsigned short*)(ws + 7312640); // [8000][1024] bf16 (aliases BA+BB, dead then)
    float*  IRn     = ws + 17634560;                        // 1,264,000
    float*  YhF     = ws + 18898560;                        // [8][1000][1280]
    float*  YnF     = ws + 29138560;                        // [8][1000][400]

    float* out       = (float*)d_out;
    float* sig_out   = out;
    float* f0_out    = out + 1920000;
    float* fph_out   = out + 1928000;
    float* harm_out  = out + 1928008;
    float* noise_out = out + 3848008;

    basis_h_bf16_t<<<1024, 256, 0, stream>>>(Chb);
    basis_kernel<80, 158><<<80, 256, 0, stream>>>(Cn);

    // MLP hidden layers in fp32 (f0-precision path); 3rd layer mirrors bf16
    gemm_kernel<0><<<dim3(125, 4), 256, 0, stream>>>(mel, W_in, b_in, nullptr, BA, nullptr, 8000, 256, 80);
    gemm_kernel<1><<<dim3(125, 4), 256, 0, stream>>>(BA,  W1,   b1,   BA,      BB, nullptr, 8000, 256, 256);
    gemm_kernel<1><<<dim3(125, 4), 256, 0, stream>>>(BB,  W2,   b2,   BB,      BA, BAb,     8000, 256, 256);

    // W_out: bf16 MFMA -> O, then parallel transform2; exact fp32 f0 GEMV
    convert_wout<<<640, 256, 0, stream>>>(W_out, WTb);
    mfma_gemm<256, 640><<<dim3(63, 5), 256, 0, stream>>>(
        (const unsigned short*)BAb, (const unsigned short*)WTb, O, 8000);
    f0_gemv<<<2000, 256, 0, stream>>>(BA, W_out, b_out, f0w, f0_out);

    transform2_kernel<<<(8000 * 592 + 255) / 256, 256, 0, stream>>>(O, b_out, SPb, NP);
    scan_par_kernel<<<8, 256, 0, stream>>>(f0w, iphase, base, fph_out);

    // IR_h = SPb @ Chb^T  (bf16 MFMA, BF16 out, stride 1024)
    mfma_gemm_bf16o<512, 1024><<<dim3(63, 8), 256, 0, stream>>>(
        (const unsigned short*)SPb, (const unsigned short*)Chb, IRhb, 8000);
    // IR_n fp32
    gemm_kernel<2><<<dim3(125, 3), 256, 0, stream>>>(NP, Cn, nullptr, nullptr, IRn, nullptr, 8000, 158, 80);

    // per-frame conv (saw / noise generated in-kernel, MFMA) + overlap-add
    frameconv_h_mfma<<<dim3(250, 8), 256, 0, stream>>>(f0w, base, iphase, IRhb, YhF);
    frameconv_n_mfma<<<dim3(250, 8), 256, 0, stream>>>(IRn, YnF);
    combine_kernel<<<dim3(938, 8), 256, 0, stream>>>(YhF, YnF, sig_out, harm_out, noise_out);
}

// Round 17
// 222.707 us; speedup vs baseline: 1.4571x; 1.0120x over previous
//
#include <hip/hip_runtime.h>
#include <hip/hip_bf16.h>
#include <math.h>

#define TWO_PI_D 6.283185307179586476925286766559
#define TWO_PI_F 6.28318530718f

typedef short bf16x8 __attribute__((ext_vector_type(8)));
typedef float f32x4 __attribute__((ext_vector_type(4)));

static __device__ inline unsigned short f2bf(float v) {
    union { __hip_bfloat16 h; unsigned short u; } cv;
    cv.h = __float2bfloat16(v);
    return cv.u;
}
static __device__ inline float bf2f(unsigned short u) {
    union { unsigned short u; __hip_bfloat16 h; } cv;
    cv.u = u;
    return __bfloat162float(cv.h);
}

// ---------------------------------------------------------------------------
// Harmonic basis, bf16, TRANSPOSED + padded: Ct[n][k], n<1024 (1022 valid), k<512
// __cosf: 2^-21 abs err << bf16 target precision; 4x faster transcendental.
// ---------------------------------------------------------------------------
__global__ __launch_bounds__(256) void basis_h_bf16_t(__hip_bfloat16* __restrict__ Ct)
{
    const int n = blockIdx.x;            // 0..1023
    for (int k = threadIdx.x; k < 512; k += 256) {
        float v = 0.0f;
        if (n < 1022) {
            float hann = 0.5f * (1.0f - __cosf(TWO_PI_F * (float)n / 1022.0f));
            float w = hann * (1.0f / 1022.0f);
            if (k == 0) v = w;
            else if (k == 511) v = (n & 1) ? w : -w;
            else {
                int m = (k * n) % 1022;
                float c = __cosf(TWO_PI_F * (float)m / 1022.0f);
                v = 2.0f * w * ((k & 1) ? -c : c);
            }
        }
        Ct[(size_t)n * 512 + k] = __float2bfloat16(v);
    }
}

// noise basis, fp32: C[k][n], k<80, n<158
template<int NMAG, int NIR>
__global__ __launch_bounds__(256) void basis_kernel(float* __restrict__ C)
{
    const int k = blockIdx.x;
    for (int n = threadIdx.x; n < NIR; n += blockDim.x) {
        double hann = 0.5 * (1.0 - cos(TWO_PI_D * (double)n / (double)NIR));
        double w = hann / (double)NIR;
        double v;
        if (k == 0) v = w;
        else if (k == NMAG - 1) v = (n & 1) ? w : -w;
        else {
            long m = ((long)k * (long)n) % NIR;
            double c = cos(TWO_PI_D * (double)m / (double)NIR);
            v = 2.0 * w * ((k & 1) ? -c : c);
        }
        C[(size_t)k * NIR + n] = (float)v;
    }
}

// ---------------------------------------------------------------------------
// fp32 tiled GEMM 64x64x16 — precision path (MLP hidden layers + noise IR).
// ---------------------------------------------------------------------------
__device__ inline float gelu_f(float x) {
    float x3 = x * x * x;
    float t = tanhf(0.7978845608028654f * (x + 0.044715f * x3));
    return 0.5f * x * (1.0f + t);
}

template<int MODE>
__global__ __launch_bounds__(256) void gemm_kernel(
    const float* __restrict__ A, const float* __restrict__ Bm,
    const float* __restrict__ bias, const float* __restrict__ resid,
    float* __restrict__ C, __hip_bfloat16* __restrict__ Cb, int M, int N, int K)
{
    __shared__ float As[16][68];
    __shared__ float Bs[16][68];
    const int tid = threadIdx.x;
    const int tx = tid & 15, ty = tid >> 4;
    const int m0 = blockIdx.x * 64;
    const int n0 = blockIdx.y * 64;
    const int ar  = tid >> 2;
    const int ac4 = (tid & 3) << 2;
    const int bk  = tid >> 4;
    const int bn4 = (tid & 15) << 2;
    float acc[4][4] = {};
    for (int k0 = 0; k0 < K; k0 += 16) {
        float4 av = *(const float4*)(A + (size_t)(m0 + ar) * K + k0 + ac4);
        As[ac4 + 0][ar] = av.x;
        As[ac4 + 1][ar] = av.y;
        As[ac4 + 2][ar] = av.z;
        As[ac4 + 3][ar] = av.w;
        const float* Bp = Bm + (size_t)(k0 + bk) * N + n0 + bn4;
        #pragma unroll
        for (int i = 0; i < 4; i++)
            Bs[bk][bn4 + i] = (n0 + bn4 + i < N) ? Bp[i] : 0.0f;
        __syncthreads();
        #pragma unroll
        for (int kk = 0; kk < 16; kk++) {
            float4 a4 = *(const float4*)&As[kk][ty << 2];
            float4 b4 = *(const float4*)&Bs[kk][tx << 2];
            float a[4] = {a4.x, a4.y, a4.z, a4.w};
            float b[4] = {b4.x, b4.y, b4.z, b4.w};
            #pragma unroll
            for (int i = 0; i < 4; i++)
                #pragma unroll
                for (int j = 0; j < 4; j++)
                    acc[i][j] = fmaf(a[i], b[j], acc[i][j]);
        }
        __syncthreads();
    }
    #pragma unroll
    for (int i = 0; i < 4; i++) {
        int m = m0 + (ty << 2) + i;
        #pragma unroll
        for (int j = 0; j < 4; j++) {
            int n = n0 + (tx << 2) + j;
            if (n < N) {
                float v = acc[i][j];
                if (bias) v += bias[n];
                if (MODE == 0) v = tanhf(v);
                else if (MODE == 1) v = resid[(size_t)m * N + n] + gelu_f(v);
                C[(size_t)m * N + n] = v;
                if (MODE == 1 && Cb) Cb[(size_t)m * N + n] = __float2bfloat16(v);
            }
        }
    }
}

// ---------------------------------------------------------------------------
// bf16 MFMA GEMM: A [M][K] bf16, Bt [NPAD][K] bf16, C [M][NSTRIDE] fp32
// ---------------------------------------------------------------------------
template<int K, int NSTRIDE>
__global__ __launch_bounds__(256) void mfma_gemm(
    const unsigned short* __restrict__ A, const unsigned short* __restrict__ Bt,
    float* __restrict__ C, int M)
{
    __shared__ __align__(16) unsigned short As[128][72];
    __shared__ __align__(16) unsigned short Bs[128][72];
    const int tid = threadIdx.x;
    const int m0 = blockIdx.x * 128;
    const int n0 = blockIdx.y * 128;
    const int wid = tid >> 6;
    const int lane = tid & 63;
    const int wm = (wid >> 1) << 6;
    const int wn = (wid & 1) << 6;

    f32x4 acc[4][4];
    #pragma unroll
    for (int i = 0; i < 4; i++)
        #pragma unroll
        for (int j = 0; j < 4; j++)
            acc[i][j] = (f32x4){0.f, 0.f, 0.f, 0.f};

    for (int k0 = 0; k0 < K; k0 += 64) {
        #pragma unroll
        for (int s = 0; s < 4; s++) {
            int g = tid + (s << 8);
            int row = g >> 3;
            int kc = (g & 7) << 3;
            int ra = m0 + row; if (ra > M - 1) ra = M - 1;
            *(uint4*)&As[row][kc] = *(const uint4*)&A[(size_t)ra * K + k0 + kc];
            *(uint4*)&Bs[row][kc] = *(const uint4*)&Bt[(size_t)(n0 + row) * K + k0 + kc];
        }
        __syncthreads();
        #pragma unroll
        for (int kk = 0; kk < 64; kk += 32) {
            bf16x8 av[4], bv[4];
            const int koff = kk + ((lane >> 4) << 3);
            #pragma unroll
            for (int mt = 0; mt < 4; mt++)
                av[mt] = *(const bf16x8*)&As[wm + (mt << 4) + (lane & 15)][koff];
            #pragma unroll
            for (int nt = 0; nt < 4; nt++)
                bv[nt] = *(const bf16x8*)&Bs[wn + (nt << 4) + (lane & 15)][koff];
            #pragma unroll
            for (int mt = 0; mt < 4; mt++)
                #pragma unroll
                for (int nt = 0; nt < 4; nt++)
                    acc[mt][nt] = __builtin_amdgcn_mfma_f32_16x16x32_bf16(
                        av[mt], bv[nt], acc[mt][nt], 0, 0, 0);
        }
        __syncthreads();
    }
    const int cr0 = m0 + wm + ((lane >> 4) << 2);
    const int cc0 = n0 + wn + (lane & 15);
    #pragma unroll
    for (int mt = 0; mt < 4; mt++)
        #pragma unroll
        for (int nt = 0; nt < 4; nt++)
            #pragma unroll
            for (int j = 0; j < 4; j++) {
                int r = cr0 + (mt << 4) + j;
                if (r < M) C[(size_t)r * NSTRIDE + cc0 + (nt << 4)] = acc[mt][nt][j];
            }
}

// same, but bf16 output (for IRh)
template<int K, int NSTRIDE>
__global__ __launch_bounds__(256) void mfma_gemm_bf16o(
    const unsigned short* __restrict__ A, const unsigned short* __restrict__ Bt,
    unsigned short* __restrict__ C, int M)
{
    __shared__ __align__(16) unsigned short As[128][72];
    __shared__ __align__(16) unsigned short Bs[128][72];
    const int tid = threadIdx.x;
    const int m0 = blockIdx.x * 128;
    const int n0 = blockIdx.y * 128;
    const int wid = tid >> 6;
    const int lane = tid & 63;
    const int wm = (wid >> 1) << 6;
    const int wn = (wid & 1) << 6;

    f32x4 acc[4][4];
    #pragma unroll
    for (int i = 0; i < 4; i++)
        #pragma unroll
        for (int j = 0; j < 4; j++)
            acc[i][j] = (f32x4){0.f, 0.f, 0.f, 0.f};

    for (int k0 = 0; k0 < K; k0 += 64) {
        #pragma unroll
        for (int s = 0; s < 4; s++) {
            int g = tid + (s << 8);
            int row = g >> 3;
            int kc = (g & 7) << 3;
            int ra = m0 + row; if (ra > M - 1) ra = M - 1;
            *(uint4*)&As[row][kc] = *(const uint4*)&A[(size_t)ra * K + k0 + kc];
            *(uint4*)&Bs[row][kc] = *(const uint4*)&Bt[(size_t)(n0 + row) * K + k0 + kc];
        }
        __syncthreads();
        #pragma unroll
        for (int kk = 0; kk < 64; kk += 32) {
            bf16x8 av[4], bv[4];
            const int koff = kk + ((lane >> 4) << 3);
            #pragma unroll
            for (int mt = 0; mt < 4; mt++)
                av[mt] = *(const bf16x8*)&As[wm + (mt << 4) + (lane & 15)][koff];
            #pragma unroll
            for (int nt = 0; nt < 4; nt++)
                bv[nt] = *(const bf16x8*)&Bs[wn + (nt << 4) + (lane & 15)][koff];
            #pragma unroll
            for (int mt = 0; mt < 4; mt++)
                #pragma unroll
                for (int nt = 0; nt < 4; nt++)
                    acc[mt][nt] = __builtin_amdgcn_mfma_f32_16x16x32_bf16(
                        av[mt], bv[nt], acc[mt][nt], 0, 0, 0);
        }
        __syncthreads();
    }
    const int cr0 = m0 + wm + ((lane >> 4) << 2);
    const int cc0 = n0 + wn + (lane & 15);
    #pragma unroll
    for (int mt = 0; mt < 4; mt++)
        #pragma unroll
        for (int nt = 0; nt < 4; nt++)
            #pragma unroll
            for (int j = 0; j < 4; j++) {
                int r = cr0 + (mt << 4) + j;
                if (r < M) C[(size_t)r * NSTRIDE + cc0 + (nt << 4)] = f2bf(acc[mt][nt][j]);
            }
}

// ---------------------------------------------------------------------------
__global__ __launch_bounds__(256) void convert_wout(
    const float* __restrict__ W, __hip_bfloat16* __restrict__ WTb)
{
    const int n = blockIdx.x;           // 0..639
    const int k = threadIdx.x;          // 0..255
    float v = (n < 593) ? W[(size_t)k * 593 + n] : 0.0f;
    WTb[(size_t)n * 256 + k] = __float2bfloat16(v);
}

// exact-fp32 f0 logit + fused precise f0 transform
__global__ __launch_bounds__(256) void f0_gemv(
    const float* __restrict__ h3, const float* __restrict__ Wout,
    const float* __restrict__ b_out, float* __restrict__ f0w, float* __restrict__ f0out)
{
    const int row = blockIdx.x * 4 + (threadIdx.x >> 6);
    const int lane = threadIdx.x & 63;
    const float* a = h3 + (size_t)row * 256;
    float s = 0.0f;
    #pragma unroll
    for (int q = 0; q < 4; q++) {
        int k = lane + (q << 6);
        s = fmaf(a[k], Wout[(size_t)k * 593], s);
    }
    #pragma unroll
    for (int off = 32; off; off >>= 1) s += __shfl_down(s, off, 64);
    if (lane == 0) {
        float lg = s + b_out[0];
        float sg = 1.0f / (1.0f + expf(-lg));
        float f0 = 80.0f * powf(12.5f, sg);
        if (f0 < 80.0f) f0 = 0.0f;
        f0w[row] = f0;
        f0out[row] = f0;
    }
}

// ---------------------------------------------------------------------------
// SP/NP from O[8000][640] cols 1..592 (+bias), fast-math exp_sigmoid
// ---------------------------------------------------------------------------
__global__ __launch_bounds__(256) void transform2_kernel(
    const float* __restrict__ O, const float* __restrict__ b_out,
    __hip_bfloat16* __restrict__ SPb, float* __restrict__ NP)
{
    int idx = blockIdx.x * 256 + threadIdx.x;
    if (idx >= 8000 * 592) return;
    int row = idx / 592;
    int c = idx - row * 592 + 1;
    float v = O[(size_t)row * 640 + c] + b_out[c];
    float s = 1.0f / (1.0f + __expf(-v));
    float p = 2.0f * __powf(s, 2.3025851f) + 1e-7f;
    if (c < 513) SPb[(size_t)row * 512 + (c - 1)] = __float2bfloat16(p);
    else         NP[(size_t)row * 80 + (c - 513)] = p;
}

// ---------------------------------------------------------------------------
// Parallel fp64 frame-level pitch scan
// ---------------------------------------------------------------------------
__device__ inline double shfl_up_d(double x, int off) {
    long long l = __double_as_longlong(x);
    int lo = (int)(l & 0xffffffffLL);
    int hi = (int)(l >> 32);
    lo = __shfl_up(lo, off, 64);
    hi = __shfl_up(hi, off, 64);
    return __longlong_as_double(((long long)hi << 32) | (unsigned int)lo);
}

__global__ __launch_bounds__(256) void scan_par_kernel(
    const float* __restrict__ f0w, const float* __restrict__ iphase,
    double* __restrict__ base, float* __restrict__ fph)
{
    __shared__ double wsum[4];
    const int b = blockIdx.x;
    const int tid = threadIdx.x;
    const int lane = tid & 63;
    const float* f0 = f0w + b * 1000;
    double s[4];
    double loc = 0.0;
    #pragma unroll
    for (int q = 0; q < 4; q++) {
        int f = tid * 4 + q;
        s[q] = loc;
        if (f < 1000) {
            double c  = (double)f0[f];
            double nx = (double)f0[(f < 999) ? (f + 1) : 999];
            loc += 120.5 * c + 119.5 * nx;
        }
    }
    double v = loc;
    #pragma unroll
    for (int off = 1; off < 64; off <<= 1) {
        double o = shfl_up_d(v, off);
        if (lane >= off) v += o;
    }
    if (lane == 63) wsum[tid >> 6] = v;
    __syncthreads();
    double wpre = 0.0;
    const int w = tid >> 6;
    for (int i = 0; i < w; i++) wpre += wsum[i];
    const double excl = wpre + v - loc;
    #pragma unroll
    for (int q = 0; q < 4; q++) {
        int f = tid * 4 + q;
        if (f < 1000) base[b * 1000 + f] = excl + s[q];
    }
    if (tid == 255) {
        double total = excl + loc;
        double u  = total * (1.0 / 24000.0);
        double ph = TWO_PI_D * u + (double)iphase[b];
        fph[b] = (float)fmod(ph, TWO_PI_D);
    }
}

// ---------------------------------------------------------------------------
// threefry2x32 (bit-exact jax.random.uniform, key (0,123), N=1,920,000)
// ---------------------------------------------------------------------------
__device__ inline unsigned rotl32(unsigned x, int d) { return (x << d) | (x >> (32 - d)); }

__device__ inline float threefry_noise(unsigned mi)
{
    const unsigned n2 = 960000u;
    unsigned i0 = (mi < n2) ? mi : (mi - n2);
    unsigned x0 = i0, x1 = i0 + n2;
    const unsigned ks0 = 0u, ks1 = 123u, ks2 = 0x1BD11BDAu ^ 0u ^ 123u;
    x0 += ks0; x1 += ks1;
#define TF_R(rot) { x0 += x1; x1 = rotl32(x1, rot); x1 ^= x0; }
    TF_R(13) TF_R(15) TF_R(26) TF_R(6)
    x0 += ks1; x1 += ks2 + 1u;
    TF_R(17) TF_R(29) TF_R(16) TF_R(24)
    x0 += ks2; x1 += ks0 + 2u;
    TF_R(13) TF_R(15) TF_R(26) TF_R(6)
    x0 += ks0; x1 += ks1 + 3u;
    TF_R(17) TF_R(29) TF_R(16) TF_R(24)
    x0 += ks1; x1 += ks2 + 4u;
    TF_R(13) TF_R(15) TF_R(26) TF_R(6)
    x0 += ks2; x1 += ks0 + 5u;
#undef TF_R
    unsigned bits = (mi < n2) ? x0 : x1;
    float uf = __uint_as_float((bits >> 9) | 0x3f800000u) - 1.0f;
    return uf * 2.0f - 1.0f;
}

// fp64 sawtooth sample
__device__ inline float saw_sample(const float* __restrict__ f0w,
                                   const double* __restrict__ base,
                                   const float* __restrict__ iphase,
                                   int b, int f, int r)
{
    double c  = (double)f0w[b * 1000 + f];
    double nx = (double)f0w[b * 1000 + ((f < 999) ? (f + 1) : 999)];
    double rr = (double)r;
    double Bc = rr * (rr + 1.0) * (1.0 / 480.0);
    double Ac = (rr + 1.0) - Bc;
    double cum = base[b * 1000 + f] + Ac * c + Bc * nx;
    double u  = cum * (1.0 / 24000.0) + (double)iphase[b] * (1.0 / TWO_PI_D);
    double fr = u - floor(u);
    return (float)(2.0 * fr - 1.0);
}

// ---------------------------------------------------------------------------
// Harmonic per-frame conv as MFMA (R13-proven): Y[jb+16m+n] = sum_k A B
// Output Y in bf16 (halves conv-write + combine-read HBM traffic).
// ---------------------------------------------------------------------------
__global__ __launch_bounds__(256) void frameconv_h_mfma(
    const float* __restrict__ f0w, const double* __restrict__ base,
    const float* __restrict__ iphase, const unsigned short* __restrict__ IRb,
    unsigned short* __restrict__ Y)
{
    __shared__ __align__(16) unsigned short we[4][1536];
    __shared__ __align__(16) unsigned short up0[4][288];
    __shared__ __align__(16) unsigned short up1[4][288];
    const int fq  = blockIdx.x;          // frame quad 0..249
    const int b   = blockIdx.y;
    const int tid = threadIdx.x;
    const int wv  = tid >> 6;
    const int lane = tid & 63;

    for (int i = tid; i < 4 * 1536; i += 256) {
        int fr = i / 1536, x = i - fr * 1536;
        unsigned short v = 0;
        if (x >= 240 && x < 1262)
            v = IRb[((size_t)b * 1000 + fq * 4 + fr) * 1024 + (x - 240)];
        we[fr][x] = v;
    }
    for (int i = tid; i < 4 * 288; i += 256) {
        int fr = i / 288, p = i - fr * 288;
        float v = 0.0f;
        if (p >= 17 && p <= 256)
            v = saw_sample(f0w, base, iphase, b, fq * 4 + fr, 256 - p);
        unsigned short bv = f2bf(v);
        up0[fr][p] = bv;
        if (p >= 1) up1[fr][p - 1] = bv;
        if (p == 0) up1[fr][287] = 0;
    }
    __syncthreads();

    const unsigned short* wf = we[wv];
    const int n = lane & 15, hi = lane >> 4;

    const unsigned int* usrc = (const unsigned int*)((n & 1) ? up1[wv] : up0[wv]);
    bf16x8 bfrag[8];
    #pragma unroll
    for (int s = 0; s < 8; s++) {
        int e0 = 16 + 32 * s + 8 * hi - n - (n & 1);
        int q = e0 >> 1;
        uint4 raw;
        raw.x = usrc[q]; raw.y = usrc[q + 1]; raw.z = usrc[q + 2]; raw.w = usrc[q + 3];
        bfrag[s] = __builtin_bit_cast(bf16x8, raw);
    }

    f32x4 acc[5];
    #pragma unroll
    for (int t = 0; t < 5; t++) acc[t] = (f32x4){0.f, 0.f, 0.f, 0.f};

    #pragma unroll
    for (int t = 0; t < 5; t++) {
        const int jb = t << 8;
        #pragma unroll
        for (int s = 0; s < 8; s++) {
            bf16x8 afrag = *(const bf16x8*)&wf[jb + 32 * s + 8 * hi + 16 * n];
            acc[t] = __builtin_amdgcn_mfma_f32_16x16x32_bf16(afrag, bfrag[s], acc[t], 0, 0, 0);
        }
    }

    unsigned short* yp = &Y[((size_t)b * 1000 + fq * 4 + wv) * 1280];
    #pragma unroll
    for (int t = 0; t < 5; t++)
        #pragma unroll
        for (int j = 0; j < 4; j++)
            yp[(t << 8) + 64 * hi + 16 * j + n] = f2bf(acc[t][j]);
}

// ---------------------------------------------------------------------------
// Noise per-frame conv as MFMA (isomorphic, K=192, taps 158, outputs 397).
// Output Y in bf16.
// ---------------------------------------------------------------------------
__global__ __launch_bounds__(256) void frameconv_n_mfma(
    const float* __restrict__ IRn, unsigned short* __restrict__ Y)
{
    __shared__ __align__(16) unsigned short nza[4][704];
    __shared__ __align__(16) unsigned short ip0[4][224];
    __shared__ __align__(16) unsigned short ip1[4][224];
    const int fq  = blockIdx.x;          // frame quad 0..249
    const int b   = blockIdx.y;
    const int tid = threadIdx.x;
    const int wv  = tid >> 6;
    const int lane = tid & 63;

    for (int i = tid; i < 4 * 704; i += 256) {
        int fr = i / 704, x = i - fr * 704;
        unsigned short v = 0;
        if (x >= 160 && x < 400)
            v = f2bf(threefry_noise((unsigned)(b * 240000 + (fq * 4 + fr) * 240 + (x - 160))));
        nza[fr][x] = v;
    }
    for (int i = tid; i < 4 * 224; i += 256) {
        int fr = i / 224, p = i - fr * 224;
        float v = 0.0f;
        if (p >= 19 && p <= 176)
            v = IRn[((size_t)b * 1000 + fq * 4 + fr) * 158 + (176 - p)];
        unsigned short bv = f2bf(v);
        ip0[fr][p] = bv;
        if (p >= 1) ip1[fr][p - 1] = bv;
        if (p == 0) ip1[fr][223] = 0;
    }
    __syncthreads();

    const unsigned short* af = nza[wv];
    const int n = lane & 15, hi = lane >> 4;

    const unsigned int* usrc = (const unsigned int*)((n & 1) ? ip1[wv] : ip0[wv]);
    bf16x8 bfrag[6];
    #pragma unroll
    for (int s = 0; s < 6; s++) {
        int e0 = 16 + 32 * s + 8 * hi - n - (n & 1);
        int q = e0 >> 1;
        uint4 raw;
        raw.x = usrc[q]; raw.y = usrc[q + 1]; raw.z = usrc[q + 2]; raw.w = usrc[q + 3];
        bfrag[s] = __builtin_bit_cast(bf16x8, raw);
    }

    f32x4 acc[2];
    acc[0] = (f32x4){0.f, 0.f, 0.f, 0.f};
    acc[1] = (f32x4){0.f, 0.f, 0.f, 0.f};

    #pragma unroll
    for (int t = 0; t < 2; t++) {
        const int jb = t << 8;
        #pragma unroll
        for (int s = 0; s < 6; s++) {
            bf16x8 afrag = *(const bf16x8*)&af[jb + 32 * s + 8 * hi + 16 * n];
            acc[t] = __builtin_amdgcn_mfma_f32_16x16x32_bf16(afrag, bfrag[s], acc[t], 0, 0, 0);
        }
    }

    unsigned short* yp = &Y[((size_t)b * 1000 + fq * 4 + wv) * 400];
    #pragma unroll
    for (int t = 0; t < 2; t++)
        #pragma unroll
        for (int j = 0; j < 4; j++) {
            int idx = (t << 8) + 64 * hi + 16 * j + n;
            if (idx < 400) yp[idx] = f2bf(acc[t][j]);
        }
}

// ---------------------------------------------------------------------------
// Overlap-add + 'same' slice + outputs (bf16 Y inputs)
// ---------------------------------------------------------------------------
__global__ __launch_bounds__(256) void combine_kernel(
    const unsigned short* __restrict__ Yh, const unsigned short* __restrict__ Yn,
    float* __restrict__ sig, float* __restrict__ harm, float* __restrict__ noise)
{
    int t = blockIdx.x * 256 + threadIdx.x;
    if (t >= 240000) return;
    const int b = blockIdx.y;
    float hsum = 0.0f;
    const int fhi = (t + 509) / 240;
    #pragma unroll
    for (int q = 0; q < 6; q++) {
        int f = fhi - q;
        int j = t + 509 - 240 * f;
        if (f >= 0 && f < 1000 && j < 1261)
            hsum += bf2f(Yh[((size_t)b * 1000 + f) * 1280 + j]);
    }
    float nsum = 0.0f;
    const int ghi = (t + 77) / 240;
    #pragma unroll
    for (int q = 0; q < 2; q++) {
        int f = ghi - q;
        int j = t + 77 - 240 * f;
        if (f >= 0 && f < 1000 && j < 397)
            nsum += bf2f(Yn[((size_t)b * 1000 + f) * 400 + j]);
    }
    size_t o = (size_t)b * 240000 + t;
    harm[o]  = hsum;
    noise[o] = nsum;
    sig[o]   = hsum + nsum;
}

// ---------------------------------------------------------------------------
extern "C" void kernel_launch(void* const* d_in, const int* in_sizes, int n_in,
                              void* d_out, int out_size, void* d_ws, size_t ws_size,
                              hipStream_t stream)
{
    (void)in_sizes; (void)n_in; (void)out_size; (void)ws_size;
    const float* mel    = (const float*)d_in[0];
    const float* iphase = (const float*)d_in[1];
    const float* W_in   = (const float*)d_in[2];
    const float* b_in   = (const float*)d_in[3];
    const float* W1     = (const float*)d_in[4];
    const float* b1     = (const float*)d_in[5];
    const float* W2     = (const float*)d_in[6];
    const float* b2     = (const float*)d_in[7];
    const float* W_out  = (const float*)d_in[8];
    const float* b_out  = (const float*)d_in[9];
    float* ws = (float*)d_ws;

    // workspace layout (float offsets)
    __hip_bfloat16* Chb = (__hip_bfloat16*)(ws + 0);        // [1024][512] bf16
    float*  Cn      = ws + 262144;                          // 12,640
    __hip_bfloat16* SPb = (__hip_bfloat16*)(ws + 274784);   // [8000][512] bf16
    float*  NP      = ws + 2322784;                         // 640,000
    float*  f0w     = ws + 3440640;                         // 8,000
    double* base    = (double*)(ws + 3448640);              // 8,000 dbl
    float*  BA      = ws + 7312640;                         // 2,048,000 (h1,h3)
    float*  BB      = ws + 9360640;                         // 2,048,000 (h2)
    __hip_bfloat16* BAb = (__hip_bfloat16*)(ws + 11408640); // [8000][256] bf16
    __hip_bfloat16* WTb = (__hip_bfloat16*)(ws + 12432640); // [640][256] bf16
    float*  O       = ws + 12514560;                        // [8000][640]
    unsigned short* IRhb = (unsigned short*)(ws + 7312640); // [8000][1024] bf16 (aliases BA+BB, dead then)
    float*  IRn     = ws + 17634560;                        // 1,264,000
    unsigned short* YhFb = (unsigned short*)(ws + 18898560);// [8][1000][1280] bf16 = 5,120,000 floats
    unsigned short* YnFb = (unsigned short*)(ws + 24018560);// [8][1000][400]  bf16 = 1,600,000 floats

    float* out       = (float*)d_out;
    float* sig_out   = out;
    float* f0_out    = out + 1920000;
    float* fph_out   = out + 1928000;
    float* harm_out  = out + 1928008;
    float* noise_out = out + 3848008;

    basis_h_bf16_t<<<1024, 256, 0, stream>>>(Chb);
    basis_kernel<80, 158><<<80, 256, 0, stream>>>(Cn);

    // MLP hidden layers in fp32 (f0-precision path); 3rd layer mirrors bf16
    gemm_kernel<0><<<dim3(125, 4), 256, 0, stream>>>(mel, W_in, b_in, nullptr, BA, nullptr, 8000, 256, 80);
    gemm_kernel<1><<<dim3(125, 4), 256, 0, stream>>>(BA,  W1,   b1,   BA,      BB, nullptr, 8000, 256, 256);
    gemm_kernel<1><<<dim3(125, 4), 256, 0, stream>>>(BB,  W2,   b2,   BB,      BA, BAb,     8000, 256, 256);

    // W_out: bf16 MFMA -> O, then parallel transform2; exact fp32 f0 GEMV
    convert_wout<<<640, 256, 0, stream>>>(W_out, WTb);
    mfma_gemm<256, 640><<<dim3(63, 5), 256, 0, stream>>>(
        (const unsigned short*)BAb, (const unsigned short*)WTb, O, 8000);
    f0_gemv<<<2000, 256, 0, stream>>>(BA, W_out, b_out, f0w, f0_out);

    transform2_kernel<<<(8000 * 592 + 255) / 256, 256, 0, stream>>>(O, b_out, SPb, NP);
    scan_par_kernel<<<8, 256, 0, stream>>>(f0w, iphase, base, fph_out);

    // IR_h = SPb @ Chb^T  (bf16 MFMA, BF16 out, stride 1024)
    mfma_gemm_bf16o<512, 1024><<<dim3(63, 8), 256, 0, stream>>>(
        (const unsigned short*)SPb, (const unsigned short*)Chb, IRhb, 8000);
    // IR_n fp32
    gemm_kernel<2><<<dim3(125, 3), 256, 0, stream>>>(NP, Cn, nullptr, nullptr, IRn, nullptr, 8000, 158, 80);

    // per-frame conv (saw / noise generated in-kernel, MFMA) + overlap-add
    frameconv_h_mfma<<<dim3(250, 8), 256, 0, stream>>>(f0w, base, iphase, IRhb, YhFb);
    frameconv_n_mfma<<<dim3(250, 8), 256, 0, stream>>>(IRn, YnFb);
    combine_kernel<<<dim3(938, 8), 256, 0, stream>>>(YhFb, YnFb, sig_out, harm_out, noise_out);
}

// Round 18
// 210.921 us; speedup vs baseline: 1.5386x; 1.0559x over previous
//
#include <hip/hip_runtime.h>
#include <hip/hip_bf16.h>
#include <math.h>

#define TWO_PI_D 6.283185307179586476925286766559
#define TWO_PI_F 6.28318530718f

typedef short bf16x8 __attribute__((ext_vector_type(8)));
typedef float f32x4 __attribute__((ext_vector_type(4)));

static __device__ inline unsigned short f2bf(float v) {
    union { __hip_bfloat16 h; unsigned short u; } cv;
    cv.h = __float2bfloat16(v);
    return cv.u;
}
static __device__ inline float bf2f(unsigned short u) {
    union { unsigned short u; __hip_bfloat16 h; } cv;
    cv.u = u;
    return __bfloat162float(cv.h);
}

// ---------------------------------------------------------------------------
// Merged basis builder: blocks [0,1024) harmonic bf16-T table; [1024,1104)
// noise fp32 table.
// ---------------------------------------------------------------------------
__global__ __launch_bounds__(256) void basis_both(
    __hip_bfloat16* __restrict__ Ct, float* __restrict__ Cn)
{
    if (blockIdx.x < 1024) {
        const int n = blockIdx.x;
        for (int k = threadIdx.x; k < 512; k += 256) {
            float v = 0.0f;
            if (n < 1022) {
                float hann = 0.5f * (1.0f - __cosf(TWO_PI_F * (float)n / 1022.0f));
                float w = hann * (1.0f / 1022.0f);
                if (k == 0) v = w;
                else if (k == 511) v = (n & 1) ? w : -w;
                else {
                    int m = (k * n) % 1022;
                    float c = __cosf(TWO_PI_F * (float)m / 1022.0f);
                    v = 2.0f * w * ((k & 1) ? -c : c);
                }
            }
            Ct[(size_t)n * 512 + k] = __float2bfloat16(v);
        }
    } else {
        const int k = blockIdx.x - 1024;     // 0..79
        for (int n = threadIdx.x; n < 158; n += 256) {
            double hann = 0.5 * (1.0 - cos(TWO_PI_D * (double)n / 158.0));
            double w = hann / 158.0;
            double v;
            if (k == 0) v = w;
            else if (k == 79) v = (n & 1) ? w : -w;
            else {
                long m = ((long)k * (long)n) % 158;
                double c = cos(TWO_PI_D * (double)m / 158.0);
                v = 2.0 * w * ((k & 1) ? -c : c);
            }
            Cn[(size_t)k * 158 + n] = (float)v;
        }
    }
}

// ---------------------------------------------------------------------------
// fp32 tiled GEMM 64x64x16 — precision path (MLP hidden layers + noise IR).
// ---------------------------------------------------------------------------
__device__ inline float gelu_f(float x) {
    float x3 = x * x * x;
    float t = tanhf(0.7978845608028654f * (x + 0.044715f * x3));
    return 0.5f * x * (1.0f + t);
}

template<int MODE>
__global__ __launch_bounds__(256) void gemm_kernel(
    const float* __restrict__ A, const float* __restrict__ Bm,
    const float* __restrict__ bias, const float* __restrict__ resid,
    float* __restrict__ C, __hip_bfloat16* __restrict__ Cb, int M, int N, int K)
{
    __shared__ float As[16][68];
    __shared__ float Bs[16][68];
    const int tid = threadIdx.x;
    const int tx = tid & 15, ty = tid >> 4;
    const int m0 = blockIdx.x * 64;
    const int n0 = blockIdx.y * 64;
    const int ar  = tid >> 2;
    const int ac4 = (tid & 3) << 2;
    const int bk  = tid >> 4;
    const int bn4 = (tid & 15) << 2;
    float acc[4][4] = {};
    for (int k0 = 0; k0 < K; k0 += 16) {
        float4 av = *(const float4*)(A + (size_t)(m0 + ar) * K + k0 + ac4);
        As[ac4 + 0][ar] = av.x;
        As[ac4 + 1][ar] = av.y;
        As[ac4 + 2][ar] = av.z;
        As[ac4 + 3][ar] = av.w;
        const float* Bp = Bm + (size_t)(k0 + bk) * N + n0 + bn4;
        #pragma unroll
        for (int i = 0; i < 4; i++)
            Bs[bk][bn4 + i] = (n0 + bn4 + i < N) ? Bp[i] : 0.0f;
        __syncthreads();
        #pragma unroll
        for (int kk = 0; kk < 16; kk++) {
            float4 a4 = *(const float4*)&As[kk][ty << 2];
            float4 b4 = *(const float4*)&Bs[kk][tx << 2];
            float a[4] = {a4.x, a4.y, a4.z, a4.w};
            float b[4] = {b4.x, b4.y, b4.z, b4.w};
            #pragma unroll
            for (int i = 0; i < 4; i++)
                #pragma unroll
                for (int j = 0; j < 4; j++)
                    acc[i][j] = fmaf(a[i], b[j], acc[i][j]);
        }
        __syncthreads();
    }
    #pragma unroll
    for (int i = 0; i < 4; i++) {
        int m = m0 + (ty << 2) + i;
        #pragma unroll
        for (int j = 0; j < 4; j++) {
            int n = n0 + (tx << 2) + j;
            if (n < N) {
                float v = acc[i][j];
                if (bias) v += bias[n];
                if (MODE == 0) v = tanhf(v);
                else if (MODE == 1) v = resid[(size_t)m * N + n] + gelu_f(v);
                C[(size_t)m * N + n] = v;
                if (MODE == 1 && Cb) Cb[(size_t)m * N + n] = __float2bfloat16(v);
            }
        }
    }
}

// ---------------------------------------------------------------------------
// bf16 MFMA GEMM, bf16 output (O and IRh): A [M][K], Bt [NPAD][K], C [M][NSTRIDE]
// ---------------------------------------------------------------------------
template<int K, int NSTRIDE>
__global__ __launch_bounds__(256) void mfma_gemm_bf16o(
    const unsigned short* __restrict__ A, const unsigned short* __restrict__ Bt,
    unsigned short* __restrict__ C, int M)
{
    __shared__ __align__(16) unsigned short As[128][72];
    __shared__ __align__(16) unsigned short Bs[128][72];
    const int tid = threadIdx.x;
    const int m0 = blockIdx.x * 128;
    const int n0 = blockIdx.y * 128;
    const int wid = tid >> 6;
    const int lane = tid & 63;
    const int wm = (wid >> 1) << 6;
    const int wn = (wid & 1) << 6;

    f32x4 acc[4][4];
    #pragma unroll
    for (int i = 0; i < 4; i++)
        #pragma unroll
        for (int j = 0; j < 4; j++)
            acc[i][j] = (f32x4){0.f, 0.f, 0.f, 0.f};

    for (int k0 = 0; k0 < K; k0 += 64) {
        #pragma unroll
        for (int s = 0; s < 4; s++) {
            int g = tid + (s << 8);
            int row = g >> 3;
            int kc = (g & 7) << 3;
            int ra = m0 + row; if (ra > M - 1) ra = M - 1;
            *(uint4*)&As[row][kc] = *(const uint4*)&A[(size_t)ra * K + k0 + kc];
            *(uint4*)&Bs[row][kc] = *(const uint4*)&Bt[(size_t)(n0 + row) * K + k0 + kc];
        }
        __syncthreads();
        #pragma unroll
        for (int kk = 0; kk < 64; kk += 32) {
            bf16x8 av[4], bv[4];
            const int koff = kk + ((lane >> 4) << 3);
            #pragma unroll
            for (int mt = 0; mt < 4; mt++)
                av[mt] = *(const bf16x8*)&As[wm + (mt << 4) + (lane & 15)][koff];
            #pragma unroll
            for (int nt = 0; nt < 4; nt++)
                bv[nt] = *(const bf16x8*)&Bs[wn + (nt << 4) + (lane & 15)][koff];
            #pragma unroll
            for (int mt = 0; mt < 4; mt++)
                #pragma unroll
                for (int nt = 0; nt < 4; nt++)
                    acc[mt][nt] = __builtin_amdgcn_mfma_f32_16x16x32_bf16(
                        av[mt], bv[nt], acc[mt][nt], 0, 0, 0);
        }
        __syncthreads();
    }
    const int cr0 = m0 + wm + ((lane >> 4) << 2);
    const int cc0 = n0 + wn + (lane & 15);
    #pragma unroll
    for (int mt = 0; mt < 4; mt++)
        #pragma unroll
        for (int nt = 0; nt < 4; nt++)
            #pragma unroll
            for (int j = 0; j < 4; j++) {
                int r = cr0 + (mt << 4) + j;
                if (r < M) C[(size_t)r * NSTRIDE + cc0 + (nt << 4)] = f2bf(acc[mt][nt][j]);
            }
}

// ---------------------------------------------------------------------------
__global__ __launch_bounds__(256) void convert_wout(
    const float* __restrict__ W, __hip_bfloat16* __restrict__ WTb)
{
    const int n = blockIdx.x;           // 0..639
    const int k = threadIdx.x;          // 0..255
    float v = (n < 593) ? W[(size_t)k * 593 + n] : 0.0f;
    WTb[(size_t)n * 256 + k] = __float2bfloat16(v);
}

// exact-fp32 f0 logit + fused precise f0 transform
__global__ __launch_bounds__(256) void f0_gemv(
    const float* __restrict__ h3, const float* __restrict__ Wout,
    const float* __restrict__ b_out, float* __restrict__ f0w, float* __restrict__ f0out)
{
    const int row = blockIdx.x * 4 + (threadIdx.x >> 6);
    const int lane = threadIdx.x & 63;
    const float* a = h3 + (size_t)row * 256;
    float s = 0.0f;
    #pragma unroll
    for (int q = 0; q < 4; q++) {
        int k = lane + (q << 6);
        s = fmaf(a[k], Wout[(size_t)k * 593], s);
    }
    #pragma unroll
    for (int off = 32; off; off >>= 1) s += __shfl_down(s, off, 64);
    if (lane == 0) {
        float lg = s + b_out[0];
        float sg = 1.0f / (1.0f + expf(-lg));
        float f0 = 80.0f * powf(12.5f, sg);
        if (f0 < 80.0f) f0 = 0.0f;
        f0w[row] = f0;
        f0out[row] = f0;
    }
}

// ---------------------------------------------------------------------------
// SP/NP from bf16 O[8000][640] cols 1..592 (+bias), fast-math exp_sigmoid
// ---------------------------------------------------------------------------
__global__ __launch_bounds__(256) void transform2_kernel(
    const unsigned short* __restrict__ Ob, const float* __restrict__ b_out,
    __hip_bfloat16* __restrict__ SPb, float* __restrict__ NP)
{
    int idx = blockIdx.x * 256 + threadIdx.x;
    if (idx >= 8000 * 592) return;
    int row = idx / 592;
    int c = idx - row * 592 + 1;
    float v = bf2f(Ob[(size_t)row * 640 + c]) + b_out[c];
    float s = 1.0f / (1.0f + __expf(-v));
    float p = 2.0f * __powf(s, 2.3025851f) + 1e-7f;
    if (c < 513) SPb[(size_t)row * 512 + (c - 1)] = __float2bfloat16(p);
    else         NP[(size_t)row * 80 + (c - 513)] = p;
}

// ---------------------------------------------------------------------------
// Parallel fp64 frame-level pitch scan
// ---------------------------------------------------------------------------
__device__ inline double shfl_up_d(double x, int off) {
    long long l = __double_as_longlong(x);
    int lo = (int)(l & 0xffffffffLL);
    int hi = (int)(l >> 32);
    lo = __shfl_up(lo, off, 64);
    hi = __shfl_up(hi, off, 64);
    return __longlong_as_double(((long long)hi << 32) | (unsigned int)lo);
}

__global__ __launch_bounds__(256) void scan_par_kernel(
    const float* __restrict__ f0w, const float* __restrict__ iphase,
    double* __restrict__ base, float* __restrict__ fph)
{
    __shared__ double wsum[4];
    const int b = blockIdx.x;
    const int tid = threadIdx.x;
    const int lane = tid & 63;
    const float* f0 = f0w + b * 1000;
    double s[4];
    double loc = 0.0;
    #pragma unroll
    for (int q = 0; q < 4; q++) {
        int f = tid * 4 + q;
        s[q] = loc;
        if (f < 1000) {
            double c  = (double)f0[f];
            double nx = (double)f0[(f < 999) ? (f + 1) : 999];
            loc += 120.5 * c + 119.5 * nx;
        }
    }
    double v = loc;
    #pragma unroll
    for (int off = 1; off < 64; off <<= 1) {
        double o = shfl_up_d(v, off);
        if (lane >= off) v += o;
    }
    if (lane == 63) wsum[tid >> 6] = v;
    __syncthreads();
    double wpre = 0.0;
    const int w = tid >> 6;
    for (int i = 0; i < w; i++) wpre += wsum[i];
    const double excl = wpre + v - loc;
    #pragma unroll
    for (int q = 0; q < 4; q++) {
        int f = tid * 4 + q;
        if (f < 1000) base[b * 1000 + f] = excl + s[q];
    }
    if (tid == 255) {
        double total = excl + loc;
        double u  = total * (1.0 / 24000.0);
        double ph = TWO_PI_D * u + (double)iphase[b];
        fph[b] = (float)fmod(ph, TWO_PI_D);
    }
}

// ---------------------------------------------------------------------------
// threefry2x32 (bit-exact jax.random.uniform, key (0,123), N=1,920,000)
// ---------------------------------------------------------------------------
__device__ inline unsigned rotl32(unsigned x, int d) { return (x << d) | (x >> (32 - d)); }

__device__ inline float threefry_noise(unsigned mi)
{
    const unsigned n2 = 960000u;
    unsigned i0 = (mi < n2) ? mi : (mi - n2);
    unsigned x0 = i0, x1 = i0 + n2;
    const unsigned ks0 = 0u, ks1 = 123u, ks2 = 0x1BD11BDAu ^ 0u ^ 123u;
    x0 += ks0; x1 += ks1;
#define TF_R(rot) { x0 += x1; x1 = rotl32(x1, rot); x1 ^= x0; }
    TF_R(13) TF_R(15) TF_R(26) TF_R(6)
    x0 += ks1; x1 += ks2 + 1u;
    TF_R(17) TF_R(29) TF_R(16) TF_R(24)
    x0 += ks2; x1 += ks0 + 2u;
    TF_R(13) TF_R(15) TF_R(26) TF_R(6)
    x0 += ks0; x1 += ks1 + 3u;
    TF_R(17) TF_R(29) TF_R(16) TF_R(24)
    x0 += ks1; x1 += ks2 + 4u;
    TF_R(13) TF_R(15) TF_R(26) TF_R(6)
    x0 += ks2; x1 += ks0 + 5u;
#undef TF_R
    unsigned bits = (mi < n2) ? x0 : x1;
    float uf = __uint_as_float((bits >> 9) | 0x3f800000u) - 1.0f;
    return uf * 2.0f - 1.0f;
}

// fp64 sawtooth sample
__device__ inline float saw_sample(const float* __restrict__ f0w,
                                   const double* __restrict__ base,
                                   const float* __restrict__ iphase,
                                   int b, int f, int r)
{
    double c  = (double)f0w[b * 1000 + f];
    double nx = (double)f0w[b * 1000 + ((f < 999) ? (f + 1) : 999)];
    double rr = (double)r;
    double Bc = rr * (rr + 1.0) * (1.0 / 480.0);
    double Ac = (rr + 1.0) - Bc;
    double cum = base[b * 1000 + f] + Ac * c + Bc * nx;
    double u  = cum * (1.0 / 24000.0) + (double)iphase[b] * (1.0 / TWO_PI_D);
    double fr = u - floor(u);
    return (float)(2.0 * fr - 1.0);
}

// ---------------------------------------------------------------------------
// MERGED per-frame convs as MFMA. blockIdx.x in [0,250): harmonic quad;
// [250,500): noise quad. LDS union sized for the harmonic body (16.9 KB).
// Harmonic: Y[jb+16m+n] = sum_k we[jb+16m+k]*up[16+k-n], 5 tiles x 8 MFMA.
// Noise:    Y[jb+16m+n] = sum_k nza[jb+16m+k]*ip[16+k-n], 2 tiles x 6 MFMA.
// ---------------------------------------------------------------------------
__global__ __launch_bounds__(256) void frameconv_both_mfma(
    const float* __restrict__ f0w, const double* __restrict__ base,
    const float* __restrict__ iphase, const unsigned short* __restrict__ IRb,
    const float* __restrict__ IRn,
    unsigned short* __restrict__ Yh, unsigned short* __restrict__ Yn)
{
    __shared__ __align__(16) unsigned short smem[8448];
    const int b   = blockIdx.y;
    const int tid = threadIdx.x;
    const int wv  = tid >> 6;
    const int lane = tid & 63;
    const int n = lane & 15, hi = lane >> 4;

    if (blockIdx.x < 250) {
        const int fq = blockIdx.x;
        // we(fr,x)=smem[fr*1536+x]; up0(fr,p)=smem[6144+fr*288+p]; up1 at 7296
        for (int i = tid; i < 4 * 1536; i += 256) {
            int fr = i / 1536, x = i - fr * 1536;
            unsigned short v = 0;
            if (x >= 240 && x < 1262)
                v = IRb[((size_t)b * 1000 + fq * 4 + fr) * 1024 + (x - 240)];
            smem[fr * 1536 + x] = v;
        }
        for (int i = tid; i < 4 * 288; i += 256) {
            int fr = i / 288, p = i - fr * 288;
            float v = 0.0f;
            if (p >= 17 && p <= 256)
                v = saw_sample(f0w, base, iphase, b, fq * 4 + fr, 256 - p);
            unsigned short bv = f2bf(v);
            smem[6144 + fr * 288 + p] = bv;
            if (p >= 1) smem[7296 + fr * 288 + p - 1] = bv;
            if (p == 0) smem[7296 + fr * 288 + 287] = 0;
        }
        __syncthreads();

        const unsigned short* wf = &smem[wv * 1536];
        const unsigned int* usrc = (const unsigned int*)
            ((n & 1) ? &smem[7296 + wv * 288] : &smem[6144 + wv * 288]);
        bf16x8 bfrag[8];
        #pragma unroll
        for (int s = 0; s < 8; s++) {
            int e0 = 16 + 32 * s + 8 * hi - n - (n & 1);
            int q = e0 >> 1;
            uint4 raw;
            raw.x = usrc[q]; raw.y = usrc[q + 1]; raw.z = usrc[q + 2]; raw.w = usrc[q + 3];
            bfrag[s] = __builtin_bit_cast(bf16x8, raw);
        }

        f32x4 acc[5];
        #pragma unroll
        for (int t = 0; t < 5; t++) acc[t] = (f32x4){0.f, 0.f, 0.f, 0.f};
        #pragma unroll
        for (int t = 0; t < 5; t++) {
            const int jb = t << 8;
            #pragma unroll
            for (int s = 0; s < 8; s++) {
                bf16x8 afrag = *(const bf16x8*)&wf[jb + 32 * s + 8 * hi + 16 * n];
                acc[t] = __builtin_amdgcn_mfma_f32_16x16x32_bf16(afrag, bfrag[s], acc[t], 0, 0, 0);
            }
        }

        unsigned short* yp = &Yh[((size_t)b * 1000 + fq * 4 + wv) * 1280];
        #pragma unroll
        for (int t = 0; t < 5; t++)
            #pragma unroll
            for (int j = 0; j < 4; j++)
                yp[(t << 8) + 64 * hi + 16 * j + n] = f2bf(acc[t][j]);
    } else {
        const int fq = blockIdx.x - 250;
        // nza(fr,x)=smem[fr*704+x]; ip0(fr,p)=smem[2816+fr*224+p]; ip1 at 3712
        for (int i = tid; i < 4 * 704; i += 256) {
            int fr = i / 704, x = i - fr * 704;
            unsigned short v = 0;
            if (x >= 160 && x < 400)
                v = f2bf(threefry_noise((unsigned)(b * 240000 + (fq * 4 + fr) * 240 + (x - 160))));
            smem[fr * 704 + x] = v;
        }
        for (int i = tid; i < 4 * 224; i += 256) {
            int fr = i / 224, p = i - fr * 224;
            float v = 0.0f;
            if (p >= 19 && p <= 176)
                v = IRn[((size_t)b * 1000 + fq * 4 + fr) * 158 + (176 - p)];
            unsigned short bv = f2bf(v);
            smem[2816 + fr * 224 + p] = bv;
            if (p >= 1) smem[3712 + fr * 224 + p - 1] = bv;
            if (p == 0) smem[3712 + fr * 224 + 223] = 0;
        }
        __syncthreads();

        const unsigned short* af = &smem[wv * 704];
        const unsigned int* usrc = (const unsigned int*)
            ((n & 1) ? &smem[3712 + wv * 224] : &smem[2816 + wv * 224]);
        bf16x8 bfrag[6];
        #pragma unroll
        for (int s = 0; s < 6; s++) {
            int e0 = 16 + 32 * s + 8 * hi - n - (n & 1);
            int q = e0 >> 1;
            uint4 raw;
            raw.x = usrc[q]; raw.y = usrc[q + 1]; raw.z = usrc[q + 2]; raw.w = usrc[q + 3];
            bfrag[s] = __builtin_bit_cast(bf16x8, raw);
        }

        f32x4 acc[2];
        acc[0] = (f32x4){0.f, 0.f, 0.f, 0.f};
        acc[1] = (f32x4){0.f, 0.f, 0.f, 0.f};
        #pragma unroll
        for (int t = 0; t < 2; t++) {
            const int jb = t << 8;
            #pragma unroll
            for (int s = 0; s < 6; s++) {
                bf16x8 afrag = *(const bf16x8*)&af[jb + 32 * s + 8 * hi + 16 * n];
                acc[t] = __builtin_amdgcn_mfma_f32_16x16x32_bf16(afrag, bfrag[s], acc[t], 0, 0, 0);
            }
        }

        unsigned short* yp = &Yn[((size_t)b * 1000 + fq * 4 + wv) * 400];
        #pragma unroll
        for (int t = 0; t < 2; t++)
            #pragma unroll
            for (int j = 0; j < 4; j++) {
                int idx = (t << 8) + 64 * hi + 16 * j + n;
                if (idx < 400) yp[idx] = f2bf(acc[t][j]);
            }
    }
}

// ---------------------------------------------------------------------------
// Overlap-add + 'same' slice + outputs (bf16 Y inputs)
// ---------------------------------------------------------------------------
__global__ __launch_bounds__(256) void combine_kernel(
    const unsigned short* __restrict__ Yh, const unsigned short* __restrict__ Yn,
    float* __restrict__ sig, float* __restrict__ harm, float* __restrict__ noise)
{
    int t = blockIdx.x * 256 + threadIdx.x;
    if (t >= 240000) return;
    const int b = blockIdx.y;
    float hsum = 0.0f;
    const int fhi = (t + 509) / 240;
    #pragma unroll
    for (int q = 0; q < 6; q++) {
        int f = fhi - q;
        int j = t + 509 - 240 * f;
        if (f >= 0 && f < 1000 && j < 1261)
            hsum += bf2f(Yh[((size_t)b * 1000 + f) * 1280 + j]);
    }
    float nsum = 0.0f;
    const int ghi = (t + 77) / 240;
    #pragma unroll
    for (int q = 0; q < 2; q++) {
        int f = ghi - q;
        int j = t + 77 - 240 * f;
        if (f >= 0 && f < 1000 && j < 397)
            nsum += bf2f(Yn[((size_t)b * 1000 + f) * 400 + j]);
    }
    size_t o = (size_t)b * 240000 + t;
    harm[o]  = hsum;
    noise[o] = nsum;
    sig[o]   = hsum + nsum;
}

// ---------------------------------------------------------------------------
extern "C" void kernel_launch(void* const* d_in, const int* in_sizes, int n_in,
                              void* d_out, int out_size, void* d_ws, size_t ws_size,
                              hipStream_t stream)
{
    (void)in_sizes; (void)n_in; (void)out_size; (void)ws_size;
    const float* mel    = (const float*)d_in[0];
    const float* iphase = (const float*)d_in[1];
    const float* W_in   = (const float*)d_in[2];
    const float* b_in   = (const float*)d_in[3];
    const float* W1     = (const float*)d_in[4];
    const float* b1     = (const float*)d_in[5];
    const float* W2     = (const float*)d_in[6];
    const float* b2     = (const float*)d_in[7];
    const float* W_out  = (const float*)d_in[8];
    const float* b_out  = (const float*)d_in[9];
    float* ws = (float*)d_ws;

    // workspace layout (float offsets)
    __hip_bfloat16* Chb = (__hip_bfloat16*)(ws + 0);        // [1024][512] bf16
    float*  Cn      = ws + 262144;                          // 12,640
    __hip_bfloat16* SPb = (__hip_bfloat16*)(ws + 274784);   // [8000][512] bf16
    float*  NP      = ws + 2322784;                         // 640,000
    float*  f0w     = ws + 3440640;                         // 8,000
    double* base    = (double*)(ws + 3448640);              // 8,000 dbl
    float*  BA      = ws + 7312640;                         // 2,048,000 (h1,h3)
    float*  BB      = ws + 9360640;                         // 2,048,000 (h2)
    __hip_bfloat16* BAb = (__hip_bfloat16*)(ws + 11408640); // [8000][256] bf16
    __hip_bfloat16* WTb = (__hip_bfloat16*)(ws + 12432640); // [640][256] bf16
    unsigned short* Ob  = (unsigned short*)(ws + 12514560); // [8000][640] bf16
    unsigned short* IRhb = (unsigned short*)(ws + 7312640); // [8000][1024] bf16 (aliases BA+BB, dead then)
    float*  IRn     = ws + 17634560;                        // 1,264,000
    unsigned short* YhFb = (unsigned short*)(ws + 18898560);// [8][1000][1280] bf16
    unsigned short* YnFb = (unsigned short*)(ws + 24018560);// [8][1000][400]  bf16

    float* out       = (float*)d_out;
    float* sig_out   = out;
    float* f0_out    = out + 1920000;
    float* fph_out   = out + 1928000;
    float* harm_out  = out + 1928008;
    float* noise_out = out + 3848008;

    basis_both<<<1104, 256, 0, stream>>>(Chb, Cn);

    // MLP hidden layers in fp32 (f0-precision path); 3rd layer mirrors bf16
    gemm_kernel<0><<<dim3(125, 4), 256, 0, stream>>>(mel, W_in, b_in, nullptr, BA, nullptr, 8000, 256, 80);
    gemm_kernel<1><<<dim3(125, 4), 256, 0, stream>>>(BA,  W1,   b1,   BA,      BB, nullptr, 8000, 256, 256);
    gemm_kernel<1><<<dim3(125, 4), 256, 0, stream>>>(BB,  W2,   b2,   BB,      BA, BAb,     8000, 256, 256);

    // W_out: bf16 MFMA -> Ob (bf16), then parallel transform2; exact fp32 f0 GEMV
    convert_wout<<<640, 256, 0, stream>>>(W_out, WTb);
    mfma_gemm_bf16o<256, 640><<<dim3(63, 5), 256, 0, stream>>>(
        (const unsigned short*)BAb, (const unsigned short*)WTb, Ob, 8000);
    f0_gemv<<<2000, 256, 0, stream>>>(BA, W_out, b_out, f0w, f0_out);

    transform2_kernel<<<(8000 * 592 + 255) / 256, 256, 0, stream>>>(Ob, b_out, SPb, NP);
    scan_par_kernel<<<8, 256, 0, stream>>>(f0w, iphase, base, fph_out);

    // IR_h = SPb @ Chb^T  (bf16 MFMA, bf16 out, stride 1024)
    mfma_gemm_bf16o<512, 1024><<<dim3(63, 8), 256, 0, stream>>>(
        (const unsigned short*)SPb, (const unsigned short*)Chb, IRhb, 8000);
    // IR_n fp32
    gemm_kernel<2><<<dim3(125, 3), 256, 0, stream>>>(NP, Cn, nullptr, nullptr, IRn, nullptr, 8000, 158, 80);

    // merged per-frame convs (saw / noise generated in-kernel, MFMA) + OLA
    frameconv_both_mfma<<<dim3(500, 8), 256, 0, stream>>>(
        f0w, base, iphase, IRhb, IRn, YhFb, YnFb);
    combine_kernel<<<dim3(938, 8), 256, 0, stream>>>(YhFb, YnFb, sig_out, harm_out, noise_out);
}

// Round 19
// 201.781 us; speedup vs baseline: 1.6083x; 1.0453x over previous
//
#include <hip/hip_runtime.h>
#include <hip/hip_bf16.h>
#include <math.h>

#define TWO_PI_D 6.283185307179586476925286766559
#define TWO_PI_F 6.28318530718f

typedef short bf16x8 __attribute__((ext_vector_type(8)));
typedef float f32x4 __attribute__((ext_vector_type(4)));

static __device__ inline unsigned short f2bf(float v) {
    union { __hip_bfloat16 h; unsigned short u; } cv;
    cv.h = __float2bfloat16(v);
    return cv.u;
}
static __device__ inline float bf2f(unsigned short u) {
    union { unsigned short u; __hip_bfloat16 h; } cv;
    cv.u = u;
    return __bfloat162float(cv.h);
}

// ---------------------------------------------------------------------------
// Merged setup: [0,1024) harmonic bf16-T basis; [1024,1104) noise fp32 basis;
// [1104,1744) W_out transpose->bf16.
// ---------------------------------------------------------------------------
__global__ __launch_bounds__(256) void basis_both_cw(
    __hip_bfloat16* __restrict__ Ct, float* __restrict__ Cn,
    const float* __restrict__ W, __hip_bfloat16* __restrict__ WTb)
{
    if (blockIdx.x < 1024) {
        const int n = blockIdx.x;
        for (int k = threadIdx.x; k < 512; k += 256) {
            float v = 0.0f;
            if (n < 1022) {
                float hann = 0.5f * (1.0f - __cosf(TWO_PI_F * (float)n / 1022.0f));
                float w = hann * (1.0f / 1022.0f);
                if (k == 0) v = w;
                else if (k == 511) v = (n & 1) ? w : -w;
                else {
                    int m = (k * n) % 1022;
                    float c = __cosf(TWO_PI_F * (float)m / 1022.0f);
                    v = 2.0f * w * ((k & 1) ? -c : c);
                }
            }
            Ct[(size_t)n * 512 + k] = __float2bfloat16(v);
        }
    } else if (blockIdx.x < 1104) {
        const int k = blockIdx.x - 1024;     // 0..79
        for (int n = threadIdx.x; n < 158; n += 256) {
            double hann = 0.5 * (1.0 - cos(TWO_PI_D * (double)n / 158.0));
            double w = hann / 158.0;
            double v;
            if (k == 0) v = w;
            else if (k == 79) v = (n & 1) ? w : -w;
            else {
                long m = ((long)k * (long)n) % 158;
                double c = cos(TWO_PI_D * (double)m / 158.0);
                v = 2.0 * w * ((k & 1) ? -c : c);
            }
            Cn[(size_t)k * 158 + n] = (float)v;
        }
    } else {
        const int n = blockIdx.x - 1104;     // 0..639
        const int k = threadIdx.x;           // 0..255
        float v = (n < 593) ? W[(size_t)k * 593 + n] : 0.0f;
        WTb[(size_t)n * 256 + k] = __float2bfloat16(v);
    }
}

// ---------------------------------------------------------------------------
// fp32 tiled GEMM 64x64x16 — precision path (MLP hidden layers).
// ---------------------------------------------------------------------------
__device__ inline float gelu_f(float x) {
    float x3 = x * x * x;
    float t = tanhf(0.7978845608028654f * (x + 0.044715f * x3));
    return 0.5f * x * (1.0f + t);
}

template<int MODE>
__global__ __launch_bounds__(256) void gemm_kernel(
    const float* __restrict__ A, const float* __restrict__ Bm,
    const float* __restrict__ bias, const float* __restrict__ resid,
    float* __restrict__ C, __hip_bfloat16* __restrict__ Cb, int M, int N, int K)
{
    __shared__ float As[16][68];
    __shared__ float Bs[16][68];
    const int tid = threadIdx.x;
    const int tx = tid & 15, ty = tid >> 4;
    const int m0 = blockIdx.x * 64;
    const int n0 = blockIdx.y * 64;
    const int ar  = tid >> 2;
    const int ac4 = (tid & 3) << 2;
    const int bk  = tid >> 4;
    const int bn4 = (tid & 15) << 2;
    float acc[4][4] = {};
    for (int k0 = 0; k0 < K; k0 += 16) {
        float4 av = *(const float4*)(A + (size_t)(m0 + ar) * K + k0 + ac4);
        As[ac4 + 0][ar] = av.x;
        As[ac4 + 1][ar] = av.y;
        As[ac4 + 2][ar] = av.z;
        As[ac4 + 3][ar] = av.w;
        const float* Bp = Bm + (size_t)(k0 + bk) * N + n0 + bn4;
        #pragma unroll
        for (int i = 0; i < 4; i++)
            Bs[bk][bn4 + i] = (n0 + bn4 + i < N) ? Bp[i] : 0.0f;
        __syncthreads();
        #pragma unroll
        for (int kk = 0; kk < 16; kk++) {
            float4 a4 = *(const float4*)&As[kk][ty << 2];
            float4 b4 = *(const float4*)&Bs[kk][tx << 2];
            float a[4] = {a4.x, a4.y, a4.z, a4.w};
            float b[4] = {b4.x, b4.y, b4.z, b4.w};
            #pragma unroll
            for (int i = 0; i < 4; i++)
                #pragma unroll
                for (int j = 0; j < 4; j++)
                    acc[i][j] = fmaf(a[i], b[j], acc[i][j]);
        }
        __syncthreads();
    }
    #pragma unroll
    for (int i = 0; i < 4; i++) {
        int m = m0 + (ty << 2) + i;
        #pragma unroll
        for (int j = 0; j < 4; j++) {
            int n = n0 + (tx << 2) + j;
            if (n < N) {
                float v = acc[i][j];
                if (bias) v += bias[n];
                if (MODE == 0) v = tanhf(v);
                else if (MODE == 1) v = resid[(size_t)m * N + n] + gelu_f(v);
                C[(size_t)m * N + n] = v;
                if (MODE == 1 && Cb) Cb[(size_t)m * N + n] = __float2bfloat16(v);
            }
        }
    }
}

// ---------------------------------------------------------------------------
// bf16 MFMA GEMM, bf16 output (for Ob): A [M][K], Bt [NPAD][K], C [M][NSTRIDE]
// ---------------------------------------------------------------------------
template<int K, int NSTRIDE>
__global__ __launch_bounds__(256) void mfma_gemm_bf16o(
    const unsigned short* __restrict__ A, const unsigned short* __restrict__ Bt,
    unsigned short* __restrict__ C, int M)
{
    __shared__ __align__(16) unsigned short As[128][72];
    __shared__ __align__(16) unsigned short Bs[128][72];
    const int tid = threadIdx.x;
    const int m0 = blockIdx.x * 128;
    const int n0 = blockIdx.y * 128;
    const int wid = tid >> 6;
    const int lane = tid & 63;
    const int wm = (wid >> 1) << 6;
    const int wn = (wid & 1) << 6;

    f32x4 acc[4][4];
    #pragma unroll
    for (int i = 0; i < 4; i++)
        #pragma unroll
        for (int j = 0; j < 4; j++)
            acc[i][j] = (f32x4){0.f, 0.f, 0.f, 0.f};

    for (int k0 = 0; k0 < K; k0 += 64) {
        #pragma unroll
        for (int s = 0; s < 4; s++) {
            int g = tid + (s << 8);
            int row = g >> 3;
            int kc = (g & 7) << 3;
            int ra = m0 + row; if (ra > M - 1) ra = M - 1;
            *(uint4*)&As[row][kc] = *(const uint4*)&A[(size_t)ra * K + k0 + kc];
            *(uint4*)&Bs[row][kc] = *(const uint4*)&Bt[(size_t)(n0 + row) * K + k0 + kc];
        }
        __syncthreads();
        #pragma unroll
        for (int kk = 0; kk < 64; kk += 32) {
            bf16x8 av[4], bv[4];
            const int koff = kk + ((lane >> 4) << 3);
            #pragma unroll
            for (int mt = 0; mt < 4; mt++)
                av[mt] = *(const bf16x8*)&As[wm + (mt << 4) + (lane & 15)][koff];
            #pragma unroll
            for (int nt = 0; nt < 4; nt++)
                bv[nt] = *(const bf16x8*)&Bs[wn + (nt << 4) + (lane & 15)][koff];
            #pragma unroll
            for (int mt = 0; mt < 4; mt++)
                #pragma unroll
                for (int nt = 0; nt < 4; nt++)
                    acc[mt][nt] = __builtin_amdgcn_mfma_f32_16x16x32_bf16(
                        av[mt], bv[nt], acc[mt][nt], 0, 0, 0);
        }
        __syncthreads();
    }
    const int cr0 = m0 + wm + ((lane >> 4) << 2);
    const int cc0 = n0 + wn + (lane & 15);
    #pragma unroll
    for (int mt = 0; mt < 4; mt++)
        #pragma unroll
        for (int nt = 0; nt < 4; nt++)
            #pragma unroll
            for (int j = 0; j < 4; j++) {
                int r = cr0 + (mt << 4) + j;
                if (r < M) C[(size_t)r * NSTRIDE + cc0 + (nt << 4)] = f2bf(acc[mt][nt][j]);
            }
}

// ---------------------------------------------------------------------------
// Merged IR builder: blocks [0,504): IRh = SPb @ Chb^T (bf16 MFMA, bf16 out);
// blocks [504,879): IRn = NP @ Cn (fp32). LDS union 36.9 KB.
// ---------------------------------------------------------------------------
__global__ __launch_bounds__(256) void ir_both(
    const unsigned short* __restrict__ SPb, const unsigned short* __restrict__ Chb,
    unsigned short* __restrict__ IRhb,
    const float* __restrict__ NP, const float* __restrict__ Cn,
    float* __restrict__ IRn)
{
    __shared__ __align__(16) unsigned short smem[18432];   // 36.9 KB
    const int tid = threadIdx.x;

    if (blockIdx.x < 504) {
        constexpr int K = 512, NSTRIDE = 1024, M = 8000;
        const int m0 = (blockIdx.x % 63) * 128;
        const int n0 = (blockIdx.x / 63) * 128;
        unsigned short (*As)[72] = (unsigned short(*)[72])&smem[0];
        unsigned short (*Bs)[72] = (unsigned short(*)[72])&smem[9216];
        const int wid = tid >> 6;
        const int lane = tid & 63;
        const int wm = (wid >> 1) << 6;
        const int wn = (wid & 1) << 6;

        f32x4 acc[4][4];
        #pragma unroll
        for (int i = 0; i < 4; i++)
            #pragma unroll
            for (int j = 0; j < 4; j++)
                acc[i][j] = (f32x4){0.f, 0.f, 0.f, 0.f};

        for (int k0 = 0; k0 < K; k0 += 64) {
            #pragma unroll
            for (int s = 0; s < 4; s++) {
                int g = tid + (s << 8);
                int row = g >> 3;
                int kc = (g & 7) << 3;
                int ra = m0 + row; if (ra > M - 1) ra = M - 1;
                *(uint4*)&As[row][kc] = *(const uint4*)&SPb[(size_t)ra * K + k0 + kc];
                *(uint4*)&Bs[row][kc] = *(const uint4*)&Chb[(size_t)(n0 + row) * K + k0 + kc];
            }
            __syncthreads();
            #pragma unroll
            for (int kk = 0; kk < 64; kk += 32) {
                bf16x8 av[4], bv[4];
                const int koff = kk + ((lane >> 4) << 3);
                #pragma unroll
                for (int mt = 0; mt < 4; mt++)
                    av[mt] = *(const bf16x8*)&As[wm + (mt << 4) + (lane & 15)][koff];
                #pragma unroll
                for (int nt = 0; nt < 4; nt++)
                    bv[nt] = *(const bf16x8*)&Bs[wn + (nt << 4) + (lane & 15)][koff];
                #pragma unroll
                for (int mt = 0; mt < 4; mt++)
                    #pragma unroll
                    for (int nt = 0; nt < 4; nt++)
                        acc[mt][nt] = __builtin_amdgcn_mfma_f32_16x16x32_bf16(
                            av[mt], bv[nt], acc[mt][nt], 0, 0, 0);
            }
            __syncthreads();
        }
        const int cr0 = m0 + wm + ((lane >> 4) << 2);
        const int cc0 = n0 + wn + (lane & 15);
        #pragma unroll
        for (int mt = 0; mt < 4; mt++)
            #pragma unroll
            for (int nt = 0; nt < 4; nt++)
                #pragma unroll
                for (int j = 0; j < 4; j++) {
                    int r = cr0 + (mt << 4) + j;
                    if (r < M) IRhb[(size_t)r * NSTRIDE + cc0 + (nt << 4)] = f2bf(acc[mt][nt][j]);
                }
    } else {
        constexpr int M = 8000, N = 158, K = 80;
        const int i = blockIdx.x - 504;
        const int m0 = (i % 125) * 64;
        const int n0 = (i / 125) * 64;
        float (*As)[68] = (float(*)[68])&smem[0];
        float (*Bs)[68] = (float(*)[68])((float*)&smem[0] + 16 * 68);
        const int tx = tid & 15, ty = tid >> 4;
        const int ar  = tid >> 2;
        const int ac4 = (tid & 3) << 2;
        const int bk  = tid >> 4;
        const int bn4 = (tid & 15) << 2;
        float acc[4][4] = {};
        for (int k0 = 0; k0 < K; k0 += 16) {
            float4 av = *(const float4*)(NP + (size_t)(m0 + ar) * K + k0 + ac4);
            As[ac4 + 0][ar] = av.x;
            As[ac4 + 1][ar] = av.y;
            As[ac4 + 2][ar] = av.z;
            As[ac4 + 3][ar] = av.w;
            const float* Bp = Cn + (size_t)(k0 + bk) * N + n0 + bn4;
            #pragma unroll
            for (int q = 0; q < 4; q++)
                Bs[bk][bn4 + q] = (n0 + bn4 + q < N) ? Bp[q] : 0.0f;
            __syncthreads();
            #pragma unroll
            for (int kk = 0; kk < 16; kk++) {
                float4 a4 = *(const float4*)&As[kk][ty << 2];
                float4 b4 = *(const float4*)&Bs[kk][tx << 2];
                float a[4] = {a4.x, a4.y, a4.z, a4.w};
                float b[4] = {b4.x, b4.y, b4.z, b4.w};
                #pragma unroll
                for (int p = 0; p < 4; p++)
                    #pragma unroll
                    for (int j = 0; j < 4; j++)
                        acc[p][j] = fmaf(a[p], b[j], acc[p][j]);
            }
            __syncthreads();
        }
        #pragma unroll
        for (int p = 0; p < 4; p++) {
            int m = m0 + (ty << 2) + p;
            #pragma unroll
            for (int j = 0; j < 4; j++) {
                int n = n0 + (tx << 2) + j;
                if (n < N) IRn[(size_t)m * N + n] = acc[p][j];
            }
        }
    }
}

// ---------------------------------------------------------------------------
// Merged: [0,18500) SP/NP transform from bf16 Ob; [18500,20500) exact fp32
// f0 GEMV + precise f0 transform.
// ---------------------------------------------------------------------------
__global__ __launch_bounds__(256) void transform2_f0(
    const unsigned short* __restrict__ Ob, const float* __restrict__ b_out,
    __hip_bfloat16* __restrict__ SPb, float* __restrict__ NP,
    const float* __restrict__ h3, const float* __restrict__ Wout,
    float* __restrict__ f0w, float* __restrict__ f0out)
{
    if (blockIdx.x < 18500) {
        int idx = blockIdx.x * 256 + threadIdx.x;
        if (idx >= 8000 * 592) return;
        int row = idx / 592;
        int c = idx - row * 592 + 1;
        float v = bf2f(Ob[(size_t)row * 640 + c]) + b_out[c];
        float s = 1.0f / (1.0f + __expf(-v));
        float p = 2.0f * __powf(s, 2.3025851f) + 1e-7f;
        if (c < 513) SPb[(size_t)row * 512 + (c - 1)] = __float2bfloat16(p);
        else         NP[(size_t)row * 80 + (c - 513)] = p;
    } else {
        const int row = (blockIdx.x - 18500) * 4 + (threadIdx.x >> 6);
        const int lane = threadIdx.x & 63;
        const float* a = h3 + (size_t)row * 256;
        float s = 0.0f;
        #pragma unroll
        for (int q = 0; q < 4; q++) {
            int k = lane + (q << 6);
            s = fmaf(a[k], Wout[(size_t)k * 593], s);
        }
        #pragma unroll
        for (int off = 32; off; off >>= 1) s += __shfl_down(s, off, 64);
        if (lane == 0) {
            float lg = s + b_out[0];
            float sg = 1.0f / (1.0f + expf(-lg));
            float f0 = 80.0f * powf(12.5f, sg);
            if (f0 < 80.0f) f0 = 0.0f;
            f0w[row] = f0;
            f0out[row] = f0;
        }
    }
}

// ---------------------------------------------------------------------------
// Parallel fp64 frame-level pitch scan
// ---------------------------------------------------------------------------
__device__ inline double shfl_up_d(double x, int off) {
    long long l = __double_as_longlong(x);
    int lo = (int)(l & 0xffffffffLL);
    int hi = (int)(l >> 32);
    lo = __shfl_up(lo, off, 64);
    hi = __shfl_up(hi, off, 64);
    return __longlong_as_double(((long long)hi << 32) | (unsigned int)lo);
}

__global__ __launch_bounds__(256) void scan_par_kernel(
    const float* __restrict__ f0w, const float* __restrict__ iphase,
    double* __restrict__ base, float* __restrict__ fph)
{
    __shared__ double wsum[4];
    const int b = blockIdx.x;
    const int tid = threadIdx.x;
    const int lane = tid & 63;
    const float* f0 = f0w + b * 1000;
    double s[4];
    double loc = 0.0;
    #pragma unroll
    for (int q = 0; q < 4; q++) {
        int f = tid * 4 + q;
        s[q] = loc;
        if (f < 1000) {
            double c  = (double)f0[f];
            double nx = (double)f0[(f < 999) ? (f + 1) : 999];
            loc += 120.5 * c + 119.5 * nx;
        }
    }
    double v = loc;
    #pragma unroll
    for (int off = 1; off < 64; off <<= 1) {
        double o = shfl_up_d(v, off);
        if (lane >= off) v += o;
    }
    if (lane == 63) wsum[tid >> 6] = v;
    __syncthreads();
    double wpre = 0.0;
    const int w = tid >> 6;
    for (int i = 0; i < w; i++) wpre += wsum[i];
    const double excl = wpre + v - loc;
    #pragma unroll
    for (int q = 0; q < 4; q++) {
        int f = tid * 4 + q;
        if (f < 1000) base[b * 1000 + f] = excl + s[q];
    }
    if (tid == 255) {
        double total = excl + loc;
        double u  = total * (1.0 / 24000.0);
        double ph = TWO_PI_D * u + (double)iphase[b];
        fph[b] = (float)fmod(ph, TWO_PI_D);
    }
}

// ---------------------------------------------------------------------------
// threefry2x32 (bit-exact jax.random.uniform, key (0,123), N=1,920,000)
// ---------------------------------------------------------------------------
__device__ inline unsigned rotl32(unsigned x, int d) { return (x << d) | (x >> (32 - d)); }

__device__ inline float threefry_noise(unsigned mi)
{
    const unsigned n2 = 960000u;
    unsigned i0 = (mi < n2) ? mi : (mi - n2);
    unsigned x0 = i0, x1 = i0 + n2;
    const unsigned ks0 = 0u, ks1 = 123u, ks2 = 0x1BD11BDAu ^ 0u ^ 123u;
    x0 += ks0; x1 += ks1;
#define TF_R(rot) { x0 += x1; x1 = rotl32(x1, rot); x1 ^= x0; }
    TF_R(13) TF_R(15) TF_R(26) TF_R(6)
    x0 += ks1; x1 += ks2 + 1u;
    TF_R(17) TF_R(29) TF_R(16) TF_R(24)
    x0 += ks2; x1 += ks0 + 2u;
    TF_R(13) TF_R(15) TF_R(26) TF_R(6)
    x0 += ks0; x1 += ks1 + 3u;
    TF_R(17) TF_R(29) TF_R(16) TF_R(24)
    x0 += ks1; x1 += ks2 + 4u;
    TF_R(13) TF_R(15) TF_R(26) TF_R(6)
    x0 += ks2; x1 += ks0 + 5u;
#undef TF_R
    unsigned bits = (mi < n2) ? x0 : x1;
    float uf = __uint_as_float((bits >> 9) | 0x3f800000u) - 1.0f;
    return uf * 2.0f - 1.0f;
}

// fp64 sawtooth sample
__device__ inline float saw_sample(const float* __restrict__ f0w,
                                   const double* __restrict__ base,
                                   const float* __restrict__ iphase,
                                   int b, int f, int r)
{
    double c  = (double)f0w[b * 1000 + f];
    double nx = (double)f0w[b * 1000 + ((f < 999) ? (f + 1) : 999)];
    double rr = (double)r;
    double Bc = rr * (rr + 1.0) * (1.0 / 480.0);
    double Ac = (rr + 1.0) - Bc;
    double cum = base[b * 1000 + f] + Ac * c + Bc * nx;
    double u  = cum * (1.0 / 24000.0) + (double)iphase[b] * (1.0 / TWO_PI_D);
    double fr = u - floor(u);
    return (float)(2.0 * fr - 1.0);
}

// ---------------------------------------------------------------------------
// MERGED per-frame convs as MFMA. blockIdx.x in [0,250): harmonic quad;
// [250,500): noise quad. LDS union (16.9 KB).
// ---------------------------------------------------------------------------
__global__ __launch_bounds__(256) void frameconv_both_mfma(
    const float* __restrict__ f0w, const double* __restrict__ base,
    const float* __restrict__ iphase, const unsigned short* __restrict__ IRb,
    const float* __restrict__ IRn,
    unsigned short* __restrict__ Yh, unsigned short* __restrict__ Yn)
{
    __shared__ __align__(16) unsigned short smem[8448];
    const int b   = blockIdx.y;
    const int tid = threadIdx.x;
    const int wv  = tid >> 6;
    const int lane = tid & 63;
    const int n = lane & 15, hi = lane >> 4;

    if (blockIdx.x < 250) {
        const int fq = blockIdx.x;
        for (int i = tid; i < 4 * 1536; i += 256) {
            int fr = i / 1536, x = i - fr * 1536;
            unsigned short v = 0;
            if (x >= 240 && x < 1262)
                v = IRb[((size_t)b * 1000 + fq * 4 + fr) * 1024 + (x - 240)];
            smem[fr * 1536 + x] = v;
        }
        for (int i = tid; i < 4 * 288; i += 256) {
            int fr = i / 288, p = i - fr * 288;
            float v = 0.0f;
            if (p >= 17 && p <= 256)
                v = saw_sample(f0w, base, iphase, b, fq * 4 + fr, 256 - p);
            unsigned short bv = f2bf(v);
            smem[6144 + fr * 288 + p] = bv;
            if (p >= 1) smem[7296 + fr * 288 + p - 1] = bv;
            if (p == 0) smem[7296 + fr * 288 + 287] = 0;
        }
        __syncthreads();

        const unsigned short* wf = &smem[wv * 1536];
        const unsigned int* usrc = (const unsigned int*)
            ((n & 1) ? &smem[7296 + wv * 288] : &smem[6144 + wv * 288]);
        bf16x8 bfrag[8];
        #pragma unroll
        for (int s = 0; s < 8; s++) {
            int e0 = 16 + 32 * s + 8 * hi - n - (n & 1);
            int q = e0 >> 1;
            uint4 raw;
            raw.x = usrc[q]; raw.y = usrc[q + 1]; raw.z = usrc[q + 2]; raw.w = usrc[q + 3];
            bfrag[s] = __builtin_bit_cast(bf16x8, raw);
        }

        f32x4 acc[5];
        #pragma unroll
        for (int t = 0; t < 5; t++) acc[t] = (f32x4){0.f, 0.f, 0.f, 0.f};
        #pragma unroll
        for (int t = 0; t < 5; t++) {
            const int jb = t << 8;
            #pragma unroll
            for (int s = 0; s < 8; s++) {
                bf16x8 afrag = *(const bf16x8*)&wf[jb + 32 * s + 8 * hi + 16 * n];
                acc[t] = __builtin_amdgcn_mfma_f32_16x16x32_bf16(afrag, bfrag[s], acc[t], 0, 0, 0);
            }
        }

        unsigned short* yp = &Yh[((size_t)b * 1000 + fq * 4 + wv) * 1280];
        #pragma unroll
        for (int t = 0; t < 5; t++)
            #pragma unroll
            for (int j = 0; j < 4; j++)
                yp[(t << 8) + 64 * hi + 16 * j + n] = f2bf(acc[t][j]);
    } else {
        const int fq = blockIdx.x - 250;
        for (int i = tid; i < 4 * 704; i += 256) {
            int fr = i / 704, x = i - fr * 704;
            unsigned short v = 0;
            if (x >= 160 && x < 400)
                v = f2bf(threefry_noise((unsigned)(b * 240000 + (fq * 4 + fr) * 240 + (x - 160))));
            smem[fr * 704 + x] = v;
        }
        for (int i = tid; i < 4 * 224; i += 256) {
            int fr = i / 224, p = i - fr * 224;
            float v = 0.0f;
            if (p >= 19 && p <= 176)
                v = IRn[((size_t)b * 1000 + fq * 4 + fr) * 158 + (176 - p)];
            unsigned short bv = f2bf(v);
            smem[2816 + fr * 224 + p] = bv;
            if (p >= 1) smem[3712 + fr * 224 + p - 1] = bv;
            if (p == 0) smem[3712 + fr * 224 + 223] = 0;
        }
        __syncthreads();

        const unsigned short* af = &smem[wv * 704];
        const unsigned int* usrc = (const unsigned int*)
            ((n & 1) ? &smem[3712 + wv * 224] : &smem[2816 + wv * 224]);
        bf16x8 bfrag[6];
        #pragma unroll
        for (int s = 0; s < 6; s++) {
            int e0 = 16 + 32 * s + 8 * hi - n - (n & 1);
            int q = e0 >> 1;
            uint4 raw;
            raw.x = usrc[q]; raw.y = usrc[q + 1]; raw.z = usrc[q + 2]; raw.w = usrc[q + 3];
            bfrag[s] = __builtin_bit_cast(bf16x8, raw);
        }

        f32x4 acc[2];
        acc[0] = (f32x4){0.f, 0.f, 0.f, 0.f};
        acc[1] = (f32x4){0.f, 0.f, 0.f, 0.f};
        #pragma unroll
        for (int t = 0; t < 2; t++) {
            const int jb = t << 8;
            #pragma unroll
            for (int s = 0; s < 6; s++) {
                bf16x8 afrag = *(const bf16x8*)&af[jb + 32 * s + 8 * hi + 16 * n];
                acc[t] = __builtin_amdgcn_mfma_f32_16x16x32_bf16(afrag, bfrag[s], acc[t], 0, 0, 0);
            }
        }

        unsigned short* yp = &Yn[((size_t)b * 1000 + fq * 4 + wv) * 400];
        #pragma unroll
        for (int t = 0; t < 2; t++)
            #pragma unroll
            for (int j = 0; j < 4; j++) {
                int idx = (t << 8) + 64 * hi + 16 * j + n;
                if (idx < 400) yp[idx] = f2bf(acc[t][j]);
            }
    }
}

// ---------------------------------------------------------------------------
// Overlap-add + 'same' slice + outputs (bf16 Y inputs)
// ---------------------------------------------------------------------------
__global__ __launch_bounds__(256) void combine_kernel(
    const unsigned short* __restrict__ Yh, const unsigned short* __restrict__ Yn,
    float* __restrict__ sig, float* __restrict__ harm, float* __restrict__ noise)
{
    int t = blockIdx.x * 256 + threadIdx.x;
    if (t >= 240000) return;
    const int b = blockIdx.y;
    float hsum = 0.0f;
    const int fhi = (t + 509) / 240;
    #pragma unroll
    for (int q = 0; q < 6; q++) {
        int f = fhi - q;
        int j = t + 509 - 240 * f;
        if (f >= 0 && f < 1000 && j < 1261)
            hsum += bf2f(Yh[((size_t)b * 1000 + f) * 1280 + j]);
    }
    float nsum = 0.0f;
    const int ghi = (t + 77) / 240;
    #pragma unroll
    for (int q = 0; q < 2; q++) {
        int f = ghi - q;
        int j = t + 77 - 240 * f;
        if (f >= 0 && f < 1000 && j < 397)
            nsum += bf2f(Yn[((size_t)b * 1000 + f) * 400 + j]);
    }
    size_t o = (size_t)b * 240000 + t;
    harm[o]  = hsum;
    noise[o] = nsum;
    sig[o]   = hsum + nsum;
}

// ---------------------------------------------------------------------------
extern "C" void kernel_launch(void* const* d_in, const int* in_sizes, int n_in,
                              void* d_out, int out_size, void* d_ws, size_t ws_size,
                              hipStream_t stream)
{
    (void)in_sizes; (void)n_in; (void)out_size; (void)ws_size;
    const float* mel    = (const float*)d_in[0];
    const float* iphase = (const float*)d_in[1];
    const float* W_in   = (const float*)d_in[2];
    const float* b_in   = (const float*)d_in[3];
    const float* W1     = (const float*)d_in[4];
    const float* b1     = (const float*)d_in[5];
    const float* W2     = (const float*)d_in[6];
    const float* b2     = (const float*)d_in[7];
    const float* W_out  = (const float*)d_in[8];
    const float* b_out  = (const float*)d_in[9];
    float* ws = (float*)d_ws;

    // workspace layout (float offsets)
    __hip_bfloat16* Chb = (__hip_bfloat16*)(ws + 0);        // [1024][512] bf16
    float*  Cn      = ws + 262144;                          // 12,640
    __hip_bfloat16* SPb = (__hip_bfloat16*)(ws + 274784);   // [8000][512] bf16
    float*  NP      = ws + 2322784;                         // 640,000
    float*  f0w     = ws + 3440640;                         // 8,000
    double* base    = (double*)(ws + 3448640);              // 8,000 dbl
    float*  BA      = ws + 7312640;                         // 2,048,000 (h1,h3)
    float*  BB      = ws + 9360640;                         // 2,048,000 (h2)
    __hip_bfloat16* BAb = (__hip_bfloat16*)(ws + 11408640); // [8000][256] bf16
    __hip_bfloat16* WTb = (__hip_bfloat16*)(ws + 12432640); // [640][256] bf16
    unsigned short* Ob  = (unsigned short*)(ws + 12514560); // [8000][640] bf16
    unsigned short* IRhb = (unsigned short*)(ws + 7312640); // [8000][1024] bf16 (aliases BA+BB, dead then)
    float*  IRn     = ws + 17634560;                        // 1,264,000
    unsigned short* YhFb = (unsigned short*)(ws + 18898560);// [8][1000][1280] bf16
    unsigned short* YnFb = (unsigned short*)(ws + 24018560);// [8][1000][400]  bf16

    float* out       = (float*)d_out;
    float* sig_out   = out;
    float* f0_out    = out + 1920000;
    float* fph_out   = out + 1928000;
    float* harm_out  = out + 1928008;
    float* noise_out = out + 3848008;

    basis_both_cw<<<1744, 256, 0, stream>>>(Chb, Cn, W_out, WTb);

    // MLP hidden layers in fp32 (f0-precision path); 3rd layer mirrors bf16
    gemm_kernel<0><<<dim3(125, 4), 256, 0, stream>>>(mel, W_in, b_in, nullptr, BA, nullptr, 8000, 256, 80);
    gemm_kernel<1><<<dim3(125, 4), 256, 0, stream>>>(BA,  W1,   b1,   BA,      BB, nullptr, 8000, 256, 256);
    gemm_kernel<1><<<dim3(125, 4), 256, 0, stream>>>(BB,  W2,   b2,   BB,      BA, BAb,     8000, 256, 256);

    // W_out: bf16 MFMA -> Ob (bf16)
    mfma_gemm_bf16o<256, 640><<<dim3(63, 5), 256, 0, stream>>>(
        (const unsigned short*)BAb, (const unsigned short*)WTb, Ob, 8000);

    // SP/NP transform + exact fp32 f0 (merged)
    transform2_f0<<<20500, 256, 0, stream>>>(
        Ob, b_out, SPb, NP, BA, W_out, f0w, f0_out);
    scan_par_kernel<<<8, 256, 0, stream>>>(f0w, iphase, base, fph_out);

    // IR_h (bf16 MFMA) + IR_n (fp32) merged
    ir_both<<<879, 256, 0, stream>>>(
        (const unsigned short*)SPb, (const unsigned short*)Chb, IRhb, NP, Cn, IRn);

    // merged per-frame convs (saw / noise generated in-kernel, MFMA) + OLA
    frameconv_both_mfma<<<dim3(500, 8), 256, 0, stream>>>(
        f0w, base, iphase, IRhb, IRn, YhFb, YnFb);
    combine_kernel<<<dim3(938, 8), 256, 0, stream>>>(YhFb, YnFb, sig_out, harm_out, noise_out);
}